// Round 1
// baseline (9371.532 us; speedup 1.0000x reference)
//
#include <hip/hip_runtime.h>
#include <hip/hip_bf16.h>

using bf16 = __hip_bfloat16;
typedef __attribute__((ext_vector_type(8))) short short8;
typedef __attribute__((ext_vector_type(4))) float f32x4;

#define B_ 4
#define T_ 2048
#define C_ 1024
#define H_ 16
#define D_ 64
#define FF_ 4096
#define M_TOK (B_ * T_)   // 8192

// ---------------- f32 -> bf16 convert ----------------
__global__ void cvt_f32_bf16(const float* __restrict__ in, bf16* __restrict__ out, int n) {
    int i = blockIdx.x * blockDim.x + threadIdx.x;
    if (i < n) out[i] = __float2bfloat16(in[i]);
}

// ---------------- LayerNorm: f32 in -> bf16 out ----------------
__global__ __launch_bounds__(256) void ln_kernel(const float* __restrict__ x,
                                                 const float* __restrict__ w,
                                                 const float* __restrict__ b,
                                                 bf16* __restrict__ out) {
    int row = blockIdx.x;
    const float* xr = x + (size_t)row * C_;
    int t = threadIdx.x;
    float v[4];
    float s = 0.f, s2 = 0.f;
#pragma unroll
    for (int i = 0; i < 4; i++) {
        float f = xr[t + i * 256];
        v[i] = f;
        s += f;
        s2 += f * f;
    }
#pragma unroll
    for (int off = 32; off > 0; off >>= 1) {
        s += __shfl_down(s, off);
        s2 += __shfl_down(s2, off);
    }
    __shared__ float ss[4], ss2[4];
    int wave = t >> 6, lane = t & 63;
    if (lane == 0) { ss[wave] = s; ss2[wave] = s2; }
    __syncthreads();
    s = ss[0] + ss[1] + ss[2] + ss[3];
    s2 = ss2[0] + ss2[1] + ss2[2] + ss2[3];
    float mu = s * (1.f / C_);
    float var = s2 * (1.f / C_) - mu * mu;
    float rstd = rsqrtf(var + 1e-5f);
    bf16* orow = out + (size_t)row * C_;
#pragma unroll
    for (int i = 0; i < 4; i++) {
        int c = t + i * 256;
        orow[c] = __float2bfloat16((v[i] - mu) * rstd * w[c] + b[c]);
    }
}

// ---------------- bf16 NT GEMM: C[M,N] = A[M,K] * Bw[N,K]^T ----------------
// EPI 0: store bf16
// EPI 1: out_f32 = Res_f32 + acc   (residual add)
// EPI 2: store bf16 gelu(acc)
template <int EPI>
__global__ __launch_bounds__(256) void gemm_nt(const bf16* __restrict__ A,
                                               const bf16* __restrict__ Bw,
                                               void* __restrict__ Cout,
                                               const float* __restrict__ Res,
                                               int M, int N, int K) {
    __shared__ bf16 As[128 * 72];
    __shared__ bf16 Bs[128 * 72];
    const int t = threadIdx.x;
    const int m0 = blockIdx.y * 128;
    const int n0 = blockIdx.x * 128;
    const int wave = t >> 6, lane = t & 63;
    const int wm = (wave >> 1) * 64, wn = (wave & 1) * 64;

    f32x4 acc[4][4];
#pragma unroll
    for (int mi = 0; mi < 4; mi++)
#pragma unroll
        for (int ni = 0; ni < 4; ni++) acc[mi][ni] = (f32x4){0.f, 0.f, 0.f, 0.f};

    const int lrow = lane & 15;
    const int lk = (lane >> 4) * 8;

    for (int k0 = 0; k0 < K; k0 += 64) {
#pragma unroll
        for (int i = 0; i < 4; i++) {
            int ch = t + i * 256;          // 0..1023
            int row = ch >> 3;             // 0..127
            int c8 = (ch & 7) * 8;         // 0..56
            *(short8*)(&As[row * 72 + c8]) =
                *(const short8*)(&A[(size_t)(m0 + row) * K + k0 + c8]);
            *(short8*)(&Bs[row * 72 + c8]) =
                *(const short8*)(&Bw[(size_t)(n0 + row) * K + k0 + c8]);
        }
        __syncthreads();
#pragma unroll
        for (int ks = 0; ks < 2; ks++) {
            short8 af[4], bfr[4];
#pragma unroll
            for (int mi = 0; mi < 4; mi++)
                af[mi] = *(const short8*)(&As[(wm + mi * 16 + lrow) * 72 + ks * 32 + lk]);
#pragma unroll
            for (int ni = 0; ni < 4; ni++)
                bfr[ni] = *(const short8*)(&Bs[(wn + ni * 16 + lrow) * 72 + ks * 32 + lk]);
#pragma unroll
            for (int mi = 0; mi < 4; mi++)
#pragma unroll
                for (int ni = 0; ni < 4; ni++)
                    acc[mi][ni] = __builtin_amdgcn_mfma_f32_16x16x32_bf16(
                        af[mi], bfr[ni], acc[mi][ni], 0, 0, 0);
        }
        __syncthreads();
    }

    // epilogue: D layout col=lane&15, row=(lane>>4)*4+r
    const int col = lane & 15;
    const int rbase = (lane >> 4) * 4;
#pragma unroll
    for (int mi = 0; mi < 4; mi++) {
#pragma unroll
        for (int ni = 0; ni < 4; ni++) {
            int gr = m0 + wm + mi * 16 + rbase;
            int gc = n0 + wn + ni * 16 + col;
#pragma unroll
            for (int r = 0; r < 4; r++) {
                size_t g = (size_t)(gr + r) * N + gc;
                float v = acc[mi][ni][r];
                if constexpr (EPI == 0) {
                    ((bf16*)Cout)[g] = __float2bfloat16(v);
                } else if constexpr (EPI == 1) {
                    ((float*)Cout)[g] = Res[g] + v;
                } else {
                    float ge = 0.5f * v * (1.f + erff(v * 0.70710678f));
                    ((bf16*)Cout)[g] = __float2bfloat16(ge);
                }
            }
        }
    }
}

// ---------------- causal attention, one wave per (b,h,tq) row ----------------
__global__ __launch_bounds__(256) void attn_kernel(const bf16* __restrict__ qkv,
                                                   bf16* __restrict__ y) {
    const int lane = threadIdx.x & 63;
    const int r = blockIdx.x * 4 + (threadIdx.x >> 6);  // row id over (b*H+h)*T + tq
    const int bh = r >> 11;
    const int tq = r & 2047;
    const int b = bh >> 4;
    const int h = bh & 15;

    const size_t base = ((size_t)b * T_) * (3 * C_) + (size_t)h * D_ + lane;
    const float q = __bfloat162float(qkv[base + (size_t)tq * (3 * C_)]);
    const bf16* kp = qkv + base + C_;
    const bf16* vp = qkv + base + 2 * C_;

    float m = -1e30f, l = 0.f, o = 0.f;
    const float scale = 0.125f;
    for (int s = 0; s <= tq; s++) {
        float kv = __bfloat162float(kp[(size_t)s * (3 * C_)]);
        float p = q * kv;
        p += __shfl_xor(p, 32);
        p += __shfl_xor(p, 16);
        p += __shfl_xor(p, 8);
        p += __shfl_xor(p, 4);
        p += __shfl_xor(p, 2);
        p += __shfl_xor(p, 1);
        p *= scale;
        float vv = __bfloat162float(vp[(size_t)s * (3 * C_)]);
        float mn = fmaxf(m, p);
        float al = __expf(m - mn);
        float e = __expf(p - mn);
        l = l * al + e;
        o = o * al + e * vv;
        m = mn;
    }
    y[((size_t)(b * T_ + tq)) * C_ + (size_t)h * D_ + lane] = __float2bfloat16(o / l);
}

// ---------------- launch ----------------
extern "C" void kernel_launch(void* const* d_in, const int* in_sizes, int n_in,
                              void* d_out, int out_size, void* d_ws, size_t ws_size,
                              hipStream_t stream) {
    const float* x      = (const float*)d_in[0];
    const float* ln1w   = (const float*)d_in[1];
    const float* ln1b   = (const float*)d_in[2];
    const float* ln2w   = (const float*)d_in[3];
    const float* ln2b   = (const float*)d_in[4];
    const float* w_attn = (const float*)d_in[5];  // [3C, C]
    const float* w_proj = (const float*)d_in[6];  // [C, C]
    const float* w_fc   = (const float*)d_in[7];  // [FF, C]
    const float* w_fcp  = (const float*)d_in[8];  // [C, FF]
    float* out = (float*)d_out;

    char* ws = (char*)d_ws;
    // layout (bytes):
    bf16* ln_buf = (bf16*)(ws);                              // 16 MB [0,16M)
    bf16* qkv    = (bf16*)(ws + (16u << 20));                // 48 MB in 64 MB region
    bf16* ubuf   = (bf16*)(ws + (16u << 20));                // 64 MB (reuses qkv region)
    bf16* ybuf   = (bf16*)(ws + (80u << 20));                // 16 MB
    float* x2    = (float*)(ws + (96u << 20));               // 32 MB
    bf16* wattn_h = (bf16*)(ws + (128u << 20));              // 6 MB
    bf16* wproj_h = (bf16*)(ws + (134u << 20));              // 2 MB
    bf16* wfc_h   = (bf16*)(ws + (136u << 20));              // 8 MB
    bf16* wfcp_h  = (bf16*)(ws + (144u << 20));              // 8 MB

    // 1. weight conversion
    {
        int n1 = 3 * C_ * C_, n2 = C_ * C_, n3 = FF_ * C_, n4 = C_ * FF_;
        cvt_f32_bf16<<<(n1 + 255) / 256, 256, 0, stream>>>(w_attn, wattn_h, n1);
        cvt_f32_bf16<<<(n2 + 255) / 256, 256, 0, stream>>>(w_proj, wproj_h, n2);
        cvt_f32_bf16<<<(n3 + 255) / 256, 256, 0, stream>>>(w_fc, wfc_h, n3);
        cvt_f32_bf16<<<(n4 + 255) / 256, 256, 0, stream>>>(w_fcp, wfcp_h, n4);
    }

    // 2. LN1: x -> ln_buf (bf16)
    ln_kernel<<<M_TOK, 256, 0, stream>>>(x, ln1w, ln1b, ln_buf);

    // 3. qkv = ln_buf @ w_attn^T   [8192, 3072] bf16
    gemm_nt<0><<<dim3(3 * C_ / 128, M_TOK / 128), 256, 0, stream>>>(
        ln_buf, wattn_h, qkv, nullptr, M_TOK, 3 * C_, C_);

    // 4. attention -> ybuf (bf16)
    attn_kernel<<<(B_ * H_ * T_) / 4, 256, 0, stream>>>(qkv, ybuf);

    // 5. x2 = x + ybuf @ w_proj^T   (f32)
    gemm_nt<1><<<dim3(C_ / 128, M_TOK / 128), 256, 0, stream>>>(
        ybuf, wproj_h, x2, x, M_TOK, C_, C_);

    // 6. LN2: x2 -> ln_buf
    ln_kernel<<<M_TOK, 256, 0, stream>>>(x2, ln2w, ln2b, ln_buf);

    // 7. u = gelu(ln_buf @ w_fc^T)  [8192, 4096] bf16
    gemm_nt<2><<<dim3(FF_ / 128, M_TOK / 128), 256, 0, stream>>>(
        ln_buf, wfc_h, ubuf, nullptr, M_TOK, FF_, C_);

    // 8. out = x2 + u @ w_fcp^T    (f32)
    gemm_nt<1><<<dim3(C_ / 128, M_TOK / 128), 256, 0, stream>>>(
        ubuf, wfcp_h, out, x2, M_TOK, C_, FF_);
}

// Round 2
// 595.839 us; speedup vs baseline: 15.7283x; 15.7283x over previous
//
#include <hip/hip_runtime.h>
#include <hip/hip_bf16.h>

using bf16 = __hip_bfloat16;
typedef __attribute__((ext_vector_type(8))) short short8;
typedef __attribute__((ext_vector_type(4))) float f32x4;

#define B_ 4
#define T_ 2048
#define C_ 1024
#define H_ 16
#define D_ 64
#define FF_ 4096
#define M_TOK (B_ * T_)   // 8192

// ---------------- f32 -> bf16 convert ----------------
__global__ void cvt_f32_bf16(const float* __restrict__ in, bf16* __restrict__ out, int n) {
    int i = blockIdx.x * blockDim.x + threadIdx.x;
    if (i < n) out[i] = __float2bfloat16(in[i]);
}

// ---------------- LayerNorm: f32 in -> bf16 out ----------------
__global__ __launch_bounds__(256) void ln_kernel(const float* __restrict__ x,
                                                 const float* __restrict__ w,
                                                 const float* __restrict__ b,
                                                 bf16* __restrict__ out) {
    int row = blockIdx.x;
    const float* xr = x + (size_t)row * C_;
    int t = threadIdx.x;
    float v[4];
    float s = 0.f, s2 = 0.f;
#pragma unroll
    for (int i = 0; i < 4; i++) {
        float f = xr[t + i * 256];
        v[i] = f;
        s += f;
        s2 += f * f;
    }
#pragma unroll
    for (int off = 32; off > 0; off >>= 1) {
        s += __shfl_down(s, off);
        s2 += __shfl_down(s2, off);
    }
    __shared__ float ss[4], ss2[4];
    int wave = t >> 6, lane = t & 63;
    if (lane == 0) { ss[wave] = s; ss2[wave] = s2; }
    __syncthreads();
    s = ss[0] + ss[1] + ss[2] + ss[3];
    s2 = ss2[0] + ss2[1] + ss2[2] + ss2[3];
    float mu = s * (1.f / C_);
    float var = s2 * (1.f / C_) - mu * mu;
    float rstd = rsqrtf(var + 1e-5f);
    bf16* orow = out + (size_t)row * C_;
#pragma unroll
    for (int i = 0; i < 4; i++) {
        int c = t + i * 256;
        orow[c] = __float2bfloat16((v[i] - mu) * rstd * w[c] + b[c]);
    }
}

// ---------------- bf16 NT GEMM: C[M,N] = A[M,K] * Bw[N,K]^T ----------------
template <int EPI>
__global__ __launch_bounds__(256) void gemm_nt(const bf16* __restrict__ A,
                                               const bf16* __restrict__ Bw,
                                               void* __restrict__ Cout,
                                               const float* __restrict__ Res,
                                               int M, int N, int K) {
    __shared__ bf16 As[128 * 72];
    __shared__ bf16 Bs[128 * 72];
    const int t = threadIdx.x;
    const int m0 = blockIdx.y * 128;
    const int n0 = blockIdx.x * 128;
    const int wave = t >> 6, lane = t & 63;
    const int wm = (wave >> 1) * 64, wn = (wave & 1) * 64;

    f32x4 acc[4][4];
#pragma unroll
    for (int mi = 0; mi < 4; mi++)
#pragma unroll
        for (int ni = 0; ni < 4; ni++) acc[mi][ni] = (f32x4){0.f, 0.f, 0.f, 0.f};

    const int lrow = lane & 15;
    const int lk = (lane >> 4) * 8;

    for (int k0 = 0; k0 < K; k0 += 64) {
#pragma unroll
        for (int i = 0; i < 4; i++) {
            int ch = t + i * 256;
            int row = ch >> 3;
            int c8 = (ch & 7) * 8;
            *(short8*)(&As[row * 72 + c8]) =
                *(const short8*)(&A[(size_t)(m0 + row) * K + k0 + c8]);
            *(short8*)(&Bs[row * 72 + c8]) =
                *(const short8*)(&Bw[(size_t)(n0 + row) * K + k0 + c8]);
        }
        __syncthreads();
#pragma unroll
        for (int ks = 0; ks < 2; ks++) {
            short8 af[4], bfr[4];
#pragma unroll
            for (int mi = 0; mi < 4; mi++)
                af[mi] = *(const short8*)(&As[(wm + mi * 16 + lrow) * 72 + ks * 32 + lk]);
#pragma unroll
            for (int ni = 0; ni < 4; ni++)
                bfr[ni] = *(const short8*)(&Bs[(wn + ni * 16 + lrow) * 72 + ks * 32 + lk]);
#pragma unroll
            for (int mi = 0; mi < 4; mi++)
#pragma unroll
                for (int ni = 0; ni < 4; ni++)
                    acc[mi][ni] = __builtin_amdgcn_mfma_f32_16x16x32_bf16(
                        af[mi], bfr[ni], acc[mi][ni], 0, 0, 0);
        }
        __syncthreads();
    }

    const int col = lane & 15;
    const int rbase = (lane >> 4) * 4;
#pragma unroll
    for (int mi = 0; mi < 4; mi++) {
#pragma unroll
        for (int ni = 0; ni < 4; ni++) {
            int gr = m0 + wm + mi * 16 + rbase;
            int gc = n0 + wn + ni * 16 + col;
#pragma unroll
            for (int r = 0; r < 4; r++) {
                size_t g = (size_t)(gr + r) * N + gc;
                float v = acc[mi][ni][r];
                if constexpr (EPI == 0) {
                    ((bf16*)Cout)[g] = __float2bfloat16(v);
                } else if constexpr (EPI == 1) {
                    ((float*)Cout)[g] = Res[g] + v;
                } else {
                    float ge = 0.5f * v * (1.f + erff(v * 0.70710678f));
                    ((bf16*)Cout)[g] = __float2bfloat16(ge);
                }
            }
        }
    }
}

// ---------------- MFMA flash attention ----------------
// grid: (T/64, B*H). Block = 4 waves, each wave owns 16 q rows.
__global__ __launch_bounds__(256) void flash_attn(const bf16* __restrict__ qkv,
                                                  bf16* __restrict__ y) {
    const int qt = blockIdx.x;
    const int bh = blockIdx.y;
    const int b = bh >> 4, h = bh & 15;
    const int q0 = qt * 64;
    const int t = threadIdx.x;
    const int wave = t >> 6, lane = t & 63;
    const int lrow = lane & 15;          // 16-lane group position
    const int g = lane >> 4;             // group 0..3
    const int lk = g * 8;                // k-slice base

    __shared__ short Ks[64 * 72];        // K tile row-major [kv][d], stride 72
    __shared__ short Vt[64 * 72];        // V tile transposed [d][kv-blk swizzled]
    __shared__ short Ps[64 * 72];        // P tile [q][kv], per-wave 16-row strips

    const size_t rs = 3 * C_;
    const bf16* Qg = qkv + (size_t)b * T_ * rs + h * D_;
    const bf16* Kg = Qg + C_;
    const bf16* Vg = Qg + 2 * C_;

    // Q fragments: lane holds Q[q0+wave*16+lrow][lk+j (+32*ks)]
    short8 qf[2];
    {
        const bf16* qr = Qg + (size_t)(q0 + wave * 16 + lrow) * rs;
        qf[0] = *(const short8*)(qr + lk);
        qf[1] = *(const short8*)(qr + 32 + lk);
    }

    f32x4 o[4];
#pragma unroll
    for (int ni = 0; ni < 4; ni++) o[ni] = (f32x4){0.f, 0.f, 0.f, 0.f};
    float m[4], l[4];
#pragma unroll
    for (int r = 0; r < 4; r++) { m[r] = -1e30f; l[r] = 0.f; }

    const int srow = t >> 3;           // 0..31
    const int sc8 = (t & 7) * 8;       // 0..56
    const int sk = t & 7;              // == (sc8+j)>>3

    const float scale = 0.125f;

    for (int kt = 0; kt <= qt; kt++) {
        const int s0 = kt * 64;
        // ---- stage K (row-major) and V (transposed+swizzled) ----
#pragma unroll
        for (int p = 0; p < 2; p++) {
            int r = srow + p * 32;
            const bf16* krow = Kg + (size_t)(s0 + r) * rs + sc8;
            *(short8*)(&Ks[r * 72 + sc8]) = *(const short8*)krow;
            const bf16* vrow = Vg + (size_t)(s0 + r) * rs + sc8;
            short8 v8 = *(const short8*)vrow;
            int blk = (r >> 3) ^ sk;
            short* vd = &Vt[(blk << 3) + (r & 7)];
#pragma unroll
            for (int j = 0; j < 8; j++)
                vd[(sc8 + j) * 72] = v8[j];
        }
        __syncthreads();

        // ---- S = Q K^T (16x64 per wave) ----
        f32x4 s[4];
#pragma unroll
        for (int ni = 0; ni < 4; ni++) s[ni] = (f32x4){0.f, 0.f, 0.f, 0.f};
#pragma unroll
        for (int ks = 0; ks < 2; ks++) {
#pragma unroll
            for (int ni = 0; ni < 4; ni++) {
                short8 kf = *(const short8*)(&Ks[(ni * 16 + lrow) * 72 + ks * 32 + lk]);
                s[ni] = __builtin_amdgcn_mfma_f32_16x16x32_bf16(qf[ks], kf, s[ni], 0, 0, 0);
            }
        }

        // ---- scale + causal mask (only diagonal tile) ----
        if (kt == qt) {
#pragma unroll
            for (int ni = 0; ni < 4; ni++)
#pragma unroll
                for (int r = 0; r < 4; r++) {
                    int qrl = wave * 16 + g * 4 + r;
                    int kvl = ni * 16 + lrow;
                    s[ni][r] = (kvl > qrl) ? -1e30f : s[ni][r] * scale;
                }
        } else {
#pragma unroll
            for (int ni = 0; ni < 4; ni++)
#pragma unroll
                for (int r = 0; r < 4; r++) s[ni][r] *= scale;
        }

        // ---- online softmax (rows live in 16-lane groups) ----
        float pm[4];
#pragma unroll
        for (int r = 0; r < 4; r++) {
            pm[r] = fmaxf(fmaxf(s[0][r], s[1][r]), fmaxf(s[2][r], s[3][r]));
#pragma unroll
            for (int off = 1; off < 16; off <<= 1)
                pm[r] = fmaxf(pm[r], __shfl_xor(pm[r], off));
        }
        float alpha[4], rowsum[4];
#pragma unroll
        for (int r = 0; r < 4; r++) {
            float mn = fmaxf(m[r], pm[r]);
            alpha[r] = __expf(m[r] - mn);
            m[r] = mn;
            rowsum[r] = 0.f;
        }
#pragma unroll
        for (int ni = 0; ni < 4; ni++) {
#pragma unroll
            for (int r = 0; r < 4; r++) {
                float p = __expf(s[ni][r] - m[r]);
                rowsum[r] += p;
                bf16 pb = __float2bfloat16(p);
                Ps[(wave * 16 + g * 4 + r) * 72 + ni * 16 + lrow] = *(short*)&pb;
            }
        }
#pragma unroll
        for (int r = 0; r < 4; r++) {
#pragma unroll
            for (int off = 1; off < 16; off <<= 1)
                rowsum[r] += __shfl_xor(rowsum[r], off);
            l[r] = l[r] * alpha[r] + rowsum[r];
        }
#pragma unroll
        for (int ni = 0; ni < 4; ni++)
#pragma unroll
            for (int r = 0; r < 4; r++) o[ni][r] *= alpha[r];

        // ---- PV: O += P * V  (P strip is wave-private, no barrier) ----
#pragma unroll
        for (int ks2 = 0; ks2 < 2; ks2++) {
            short8 pf = *(const short8*)(&Ps[(wave * 16 + lrow) * 72 + ks2 * 32 + lk]);
#pragma unroll
            for (int ni = 0; ni < 4; ni++) {
                short8 vf = *(const short8*)(
                    &Vt[(ni * 16 + lrow) * 72 +
                        (((ks2 * 4 + g) ^ (ni * 2 + (lrow >> 3))) << 3)]);
                o[ni] = __builtin_amdgcn_mfma_f32_16x16x32_bf16(pf, vf, o[ni], 0, 0, 0);
            }
        }
        __syncthreads();
    }

    // ---- write O / l ----
    float inv[4];
#pragma unroll
    for (int r = 0; r < 4; r++) inv[r] = 1.f / l[r];
#pragma unroll
    for (int ni = 0; ni < 4; ni++)
#pragma unroll
        for (int r = 0; r < 4; r++) {
            int qrow = q0 + wave * 16 + g * 4 + r;
            int d = ni * 16 + lrow;
            y[((size_t)(b * T_ + qrow)) * C_ + h * D_ + d] =
                __float2bfloat16(o[ni][r] * inv[r]);
        }
}

// ---------------- launch ----------------
extern "C" void kernel_launch(void* const* d_in, const int* in_sizes, int n_in,
                              void* d_out, int out_size, void* d_ws, size_t ws_size,
                              hipStream_t stream) {
    const float* x      = (const float*)d_in[0];
    const float* ln1w   = (const float*)d_in[1];
    const float* ln1b   = (const float*)d_in[2];
    const float* ln2w   = (const float*)d_in[3];
    const float* ln2b   = (const float*)d_in[4];
    const float* w_attn = (const float*)d_in[5];
    const float* w_proj = (const float*)d_in[6];
    const float* w_fc   = (const float*)d_in[7];
    const float* w_fcp  = (const float*)d_in[8];
    float* out = (float*)d_out;

    char* ws = (char*)d_ws;
    bf16* ln_buf = (bf16*)(ws);
    bf16* qkv    = (bf16*)(ws + (16u << 20));
    bf16* ubuf   = (bf16*)(ws + (16u << 20));
    bf16* ybuf   = (bf16*)(ws + (80u << 20));
    float* x2    = (float*)(ws + (96u << 20));
    bf16* wattn_h = (bf16*)(ws + (128u << 20));
    bf16* wproj_h = (bf16*)(ws + (134u << 20));
    bf16* wfc_h   = (bf16*)(ws + (136u << 20));
    bf16* wfcp_h  = (bf16*)(ws + (144u << 20));

    {
        int n1 = 3 * C_ * C_, n2 = C_ * C_, n3 = FF_ * C_, n4 = C_ * FF_;
        cvt_f32_bf16<<<(n1 + 255) / 256, 256, 0, stream>>>(w_attn, wattn_h, n1);
        cvt_f32_bf16<<<(n2 + 255) / 256, 256, 0, stream>>>(w_proj, wproj_h, n2);
        cvt_f32_bf16<<<(n3 + 255) / 256, 256, 0, stream>>>(w_fc, wfc_h, n3);
        cvt_f32_bf16<<<(n4 + 255) / 256, 256, 0, stream>>>(w_fcp, wfcp_h, n4);
    }

    ln_kernel<<<M_TOK, 256, 0, stream>>>(x, ln1w, ln1b, ln_buf);

    gemm_nt<0><<<dim3(3 * C_ / 128, M_TOK / 128), 256, 0, stream>>>(
        ln_buf, wattn_h, qkv, nullptr, M_TOK, 3 * C_, C_);

    flash_attn<<<dim3(T_ / 64, B_ * H_), 256, 0, stream>>>(qkv, ybuf);

    gemm_nt<1><<<dim3(C_ / 128, M_TOK / 128), 256, 0, stream>>>(
        ybuf, wproj_h, x2, x, M_TOK, C_, C_);

    ln_kernel<<<M_TOK, 256, 0, stream>>>(x2, ln2w, ln2b, ln_buf);

    gemm_nt<2><<<dim3(FF_ / 128, M_TOK / 128), 256, 0, stream>>>(
        ln_buf, wfc_h, ubuf, nullptr, M_TOK, FF_, C_);

    gemm_nt<1><<<dim3(C_ / 128, M_TOK / 128), 256, 0, stream>>>(
        ubuf, wfcp_h, out, x2, M_TOK, C_, FF_);
}

// Round 3
// 572.227 us; speedup vs baseline: 16.3773x; 1.0413x over previous
//
#include <hip/hip_runtime.h>
#include <hip/hip_bf16.h>

using bf16 = __hip_bfloat16;
typedef __attribute__((ext_vector_type(8))) short short8;
typedef __attribute__((ext_vector_type(4))) float f32x4;

#define B_ 4
#define T_ 2048
#define C_ 1024
#define H_ 16
#define FF_ 4096
#define M_TOK (B_ * T_)   // 8192

// ---------------- async global->LDS 16B ----------------
__device__ __forceinline__ void gload16(const void* g, void* l) {
    __builtin_amdgcn_global_load_lds(
        (const __attribute__((address_space(1))) void*)g,
        (__attribute__((address_space(3))) void*)l, 16, 0, 0);
}

// ---------------- DPP 16-lane rotate reduce ----------------
template <int CTRL>
__device__ __forceinline__ float dpp_rotf(float x) {
    return __int_as_float(__builtin_amdgcn_update_dpp(
        0, __float_as_int(x), CTRL, 0xf, 0xf, true));
}
__device__ __forceinline__ float red16_max(float v) {
    v = fmaxf(v, dpp_rotf<0x128>(v));   // row_ror:8
    v = fmaxf(v, dpp_rotf<0x124>(v));   // row_ror:4
    v = fmaxf(v, dpp_rotf<0x122>(v));   // row_ror:2
    v = fmaxf(v, dpp_rotf<0x121>(v));   // row_ror:1
    return v;
}
__device__ __forceinline__ float red16_sum(float v) {
    v += dpp_rotf<0x128>(v);
    v += dpp_rotf<0x124>(v);
    v += dpp_rotf<0x122>(v);
    v += dpp_rotf<0x121>(v);
    return v;
}

// ---------------- f32 -> bf16 convert ----------------
__global__ void cvt_f32_bf16(const float* __restrict__ in, bf16* __restrict__ out, int n) {
    int i = blockIdx.x * blockDim.x + threadIdx.x;
    if (i < n) out[i] = __float2bfloat16(in[i]);
}

// ---------------- LayerNorm: f32 in -> bf16 out ----------------
__global__ __launch_bounds__(256) void ln_kernel(const float* __restrict__ x,
                                                 const float* __restrict__ w,
                                                 const float* __restrict__ b,
                                                 bf16* __restrict__ out) {
    int row = blockIdx.x;
    const float* xr = x + (size_t)row * C_;
    int t = threadIdx.x;
    float v[4];
    float s = 0.f, s2 = 0.f;
#pragma unroll
    for (int i = 0; i < 4; i++) {
        float f = xr[t + i * 256];
        v[i] = f;
        s += f;
        s2 += f * f;
    }
#pragma unroll
    for (int off = 32; off > 0; off >>= 1) {
        s += __shfl_down(s, off);
        s2 += __shfl_down(s2, off);
    }
    __shared__ float ss[4], ss2[4];
    int wave = t >> 6, lane = t & 63;
    if (lane == 0) { ss[wave] = s; ss2[wave] = s2; }
    __syncthreads();
    s = ss[0] + ss[1] + ss[2] + ss[3];
    s2 = ss2[0] + ss2[1] + ss2[2] + ss2[3];
    float mu = s * (1.f / C_);
    float var = s2 * (1.f / C_) - mu * mu;
    float rstd = rsqrtf(var + 1e-5f);
    bf16* orow = out + (size_t)row * C_;
#pragma unroll
    for (int i = 0; i < 4; i++) {
        int c = t + i * 256;
        orow[c] = __float2bfloat16((v[i] - mu) * rstd * w[c] + b[c]);
    }
}

// ---------------- bf16 NT GEMM (m97 structure): C[M,N] = A[M,K] * Bw[N,K]^T ----------------
// EPI 0: store bf16   EPI 1: f32 out = Res + acc   EPI 2: bf16 gelu(acc)
template <int EPI>
__global__ __launch_bounds__(256) void gemm_nt(const bf16* __restrict__ A,
                                               const bf16* __restrict__ Bw,
                                               void* __restrict__ Cout,
                                               const float* __restrict__ Res,
                                               int M, int N, int K) {
    __shared__ alignas(16) bf16 As[128 * 64];
    __shared__ alignas(16) bf16 Bs[128 * 64];
    const int t = threadIdx.x;
    const int m0 = blockIdx.y * 128;
    const int n0 = blockIdx.x * 128;
    const int wave = t >> 6, lane = t & 63;
    const int wm = (wave >> 1) * 64, wn = (wave & 1) * 64;
    const int lrow = lane & 15;
    const int lk = (lane >> 4) * 8;
    const int srow = t >> 3;        // 0..31
    const int scol = (t & 7) * 8;   // 0..56

    f32x4 acc[4][4];
#pragma unroll
    for (int mi = 0; mi < 4; mi++)
#pragma unroll
        for (int ni = 0; ni < 4; ni++) acc[mi][ni] = (f32x4){0.f, 0.f, 0.f, 0.f};

    for (int k0 = 0; k0 < K; k0 += 64) {
#pragma unroll
        for (int i = 0; i < 4; i++) {
            int row = i * 32 + srow;
            gload16(A + (size_t)(m0 + row) * K + k0 + scol, &As[row * 64 + scol]);
        }
#pragma unroll
        for (int i = 0; i < 4; i++) {
            int row = i * 32 + srow;
            gload16(Bw + (size_t)(n0 + row) * K + k0 + scol, &Bs[row * 64 + scol]);
        }
        __syncthreads();
#pragma unroll
        for (int ks = 0; ks < 2; ks++) {
            short8 af[4], bfr[4];
#pragma unroll
            for (int mi = 0; mi < 4; mi++)
                af[mi] = *(const short8*)(&As[(wm + mi * 16 + lrow) * 64 + ks * 32 + lk]);
#pragma unroll
            for (int ni = 0; ni < 4; ni++)
                bfr[ni] = *(const short8*)(&Bs[(wn + ni * 16 + lrow) * 64 + ks * 32 + lk]);
#pragma unroll
            for (int mi = 0; mi < 4; mi++)
#pragma unroll
                for (int ni = 0; ni < 4; ni++)
                    acc[mi][ni] = __builtin_amdgcn_mfma_f32_16x16x32_bf16(
                        af[mi], bfr[ni], acc[mi][ni], 0, 0, 0);
        }
        __syncthreads();
    }

    const int col = lane & 15;
    const int rbase = (lane >> 4) * 4;
#pragma unroll
    for (int mi = 0; mi < 4; mi++) {
#pragma unroll
        for (int ni = 0; ni < 4; ni++) {
            int gr = m0 + wm + mi * 16 + rbase;
            int gc = n0 + wn + ni * 16 + col;
#pragma unroll
            for (int r = 0; r < 4; r++) {
                size_t gidx = (size_t)(gr + r) * N + gc;
                float v = acc[mi][ni][r];
                if constexpr (EPI == 0) {
                    ((bf16*)Cout)[gidx] = __float2bfloat16(v);
                } else if constexpr (EPI == 1) {
                    ((float*)Cout)[gidx] = Res[gidx] + v;
                } else {
                    float ge = 0.5f * v * (1.f + erff(v * 0.70710678f));
                    ((bf16*)Cout)[gidx] = __float2bfloat16(ge);
                }
            }
        }
    }
}

// ---------------- MFMA flash attention ----------------
// qk: [B*T, 2C] rows = (Q | K) bf16;  vt: [C, B*T] = V^T per head-dim row.
// grid: (T/128, B*H). Block = 4 waves, each wave owns 32 q rows.
__global__ __launch_bounds__(256) void flash_attn(const bf16* __restrict__ qk,
                                                  const bf16* __restrict__ vt,
                                                  bf16* __restrict__ y) {
    const int qtb = (gridDim.x - 1) - blockIdx.x;   // heavy blocks first
    const int bh = blockIdx.y;
    const int b = bh >> 4, h = bh & 15;
    const int q0 = qtb * 128;
    const int t = threadIdx.x;
    const int wave = t >> 6, lane = t & 63;
    const int lrow = lane & 15, g = lane >> 4, lk = g * 8;

    __shared__ alignas(16) short Ks[64 * 72];
    __shared__ alignas(16) short Vs[64 * 72];
    __shared__ alignas(16) short Ps[128 * 72];

    const size_t rs = 2 * C_;   // 2048
    const bf16* Qg = qk + (size_t)b * T_ * rs + h * 64;
    const bf16* Kg = Qg + C_;
    const bf16* Vg = vt + (size_t)(h * 64) * M_TOK + b * T_;

    short8 qf[2][2];
#pragma unroll
    for (int mi = 0; mi < 2; mi++) {
        const bf16* qr = Qg + (size_t)(q0 + wave * 32 + mi * 16 + lrow) * rs;
        qf[mi][0] = *(const short8*)(qr + lk);
        qf[mi][1] = *(const short8*)(qr + 32 + lk);
    }

    f32x4 o[2][4];
    float m[2][4], l[2][4];
#pragma unroll
    for (int mi = 0; mi < 2; mi++) {
#pragma unroll
        for (int ni = 0; ni < 4; ni++) o[mi][ni] = (f32x4){0.f, 0.f, 0.f, 0.f};
#pragma unroll
        for (int r = 0; r < 4; r++) { m[mi][r] = -1e30f; l[mi][r] = 0.f; }
    }

    const int srow = t >> 3;        // 0..31
    const int sc8 = (t & 7) * 8;    // 0..56
    const float scale = 0.125f;
    const int nkt = 2 * qtb + 2;

    for (int kt = 0; kt < nkt; kt++) {
        const int s0 = kt * 64;
#pragma unroll
        for (int p = 0; p < 2; p++) {
            int r = srow + p * 32;
            *(short8*)(&Ks[r * 72 + sc8]) = *(const short8*)(Kg + (size_t)(s0 + r) * rs + sc8);
            *(short8*)(&Vs[r * 72 + sc8]) = *(const short8*)(Vg + (size_t)r * M_TOK + s0 + sc8);
        }
        __syncthreads();

        // ---- S = Q K^T : 32x64 per wave ----
        f32x4 s[2][4];
#pragma unroll
        for (int mi = 0; mi < 2; mi++)
#pragma unroll
            for (int ni = 0; ni < 4; ni++) s[mi][ni] = (f32x4){0.f, 0.f, 0.f, 0.f};
#pragma unroll
        for (int ks = 0; ks < 2; ks++) {
#pragma unroll
            for (int ni = 0; ni < 4; ni++) {
                short8 kf = *(const short8*)(&Ks[(ni * 16 + lrow) * 72 + ks * 32 + lk]);
#pragma unroll
                for (int mi = 0; mi < 2; mi++)
                    s[mi][ni] = __builtin_amdgcn_mfma_f32_16x16x32_bf16(
                        qf[mi][ks], kf, s[mi][ni], 0, 0, 0);
            }
        }

        // ---- scale + causal mask (only last two kv tiles of this block) ----
        if (kt >= nkt - 2) {
#pragma unroll
            for (int mi = 0; mi < 2; mi++)
#pragma unroll
                for (int ni = 0; ni < 4; ni++)
#pragma unroll
                    for (int r = 0; r < 4; r++) {
                        int qg = q0 + wave * 32 + mi * 16 + g * 4 + r;
                        int kvg = s0 + ni * 16 + lrow;
                        s[mi][ni][r] = (kvg > qg) ? -1e30f : s[mi][ni][r] * scale;
                    }
        } else {
#pragma unroll
            for (int mi = 0; mi < 2; mi++)
#pragma unroll
                for (int ni = 0; ni < 4; ni++)
#pragma unroll
                    for (int r = 0; r < 4; r++) s[mi][ni][r] *= scale;
        }

        // ---- online softmax (DPP 16-lane reductions) ----
#pragma unroll
        for (int mi = 0; mi < 2; mi++) {
            float alpha[4];
#pragma unroll
            for (int r = 0; r < 4; r++) {
                float v = fmaxf(fmaxf(s[mi][0][r], s[mi][1][r]),
                                fmaxf(s[mi][2][r], s[mi][3][r]));
                v = red16_max(v);
                float mn = fmaxf(m[mi][r], v);
                alpha[r] = __expf(m[mi][r] - mn);
                m[mi][r] = mn;
            }
            float rowsum[4] = {0.f, 0.f, 0.f, 0.f};
#pragma unroll
            for (int ni = 0; ni < 4; ni++) {
#pragma unroll
                for (int r = 0; r < 4; r++) {
                    float p = __expf(s[mi][ni][r] - m[mi][r]);
                    rowsum[r] += p;
                    bf16 pb = __float2bfloat16(p);
                    Ps[(wave * 32 + mi * 16 + g * 4 + r) * 72 + ni * 16 + lrow] = *(short*)&pb;
                }
            }
#pragma unroll
            for (int r = 0; r < 4; r++) {
                float tot = red16_sum(rowsum[r]);
                l[mi][r] = l[mi][r] * alpha[r] + tot;
            }
#pragma unroll
            for (int ni = 0; ni < 4; ni++)
#pragma unroll
                for (int r = 0; r < 4; r++) o[mi][ni][r] *= alpha[r];
        }

        // ---- PV: O += P * V^T-frag (wave-private P strip, no barrier) ----
#pragma unroll
        for (int ks2 = 0; ks2 < 2; ks2++) {
            short8 pf[2];
#pragma unroll
            for (int mi = 0; mi < 2; mi++)
                pf[mi] = *(const short8*)(&Ps[(wave * 32 + mi * 16 + lrow) * 72 + ks2 * 32 + lk]);
#pragma unroll
            for (int ni = 0; ni < 4; ni++) {
                short8 vf = *(const short8*)(&Vs[(ni * 16 + lrow) * 72 + ks2 * 32 + lk]);
#pragma unroll
                for (int mi = 0; mi < 2; mi++)
                    o[mi][ni] = __builtin_amdgcn_mfma_f32_16x16x32_bf16(
                        pf[mi], vf, o[mi][ni], 0, 0, 0);
            }
        }
        __syncthreads();
    }

    // ---- write O / l ----
#pragma unroll
    for (int mi = 0; mi < 2; mi++) {
        float inv[4];
#pragma unroll
        for (int r = 0; r < 4; r++) inv[r] = 1.f / l[mi][r];
#pragma unroll
        for (int ni = 0; ni < 4; ni++)
#pragma unroll
            for (int r = 0; r < 4; r++) {
                int qrow = q0 + wave * 32 + mi * 16 + g * 4 + r;
                y[((size_t)(b * T_ + qrow)) * C_ + h * 64 + ni * 16 + lrow] =
                    __float2bfloat16(o[mi][ni][r] * inv[r]);
            }
    }
}

// ---------------- launch ----------------
extern "C" void kernel_launch(void* const* d_in, const int* in_sizes, int n_in,
                              void* d_out, int out_size, void* d_ws, size_t ws_size,
                              hipStream_t stream) {
    const float* x      = (const float*)d_in[0];
    const float* ln1w   = (const float*)d_in[1];
    const float* ln1b   = (const float*)d_in[2];
    const float* ln2w   = (const float*)d_in[3];
    const float* ln2b   = (const float*)d_in[4];
    const float* w_attn = (const float*)d_in[5];  // [3C, C]
    const float* w_proj = (const float*)d_in[6];  // [C, C]
    const float* w_fc   = (const float*)d_in[7];  // [FF, C]
    const float* w_fcp  = (const float*)d_in[8];  // [C, FF]
    float* out = (float*)d_out;

    char* ws = (char*)d_ws;
    bf16* ln_buf  = (bf16*)(ws);                   // [0,16M)
    bf16* qk_buf  = (bf16*)(ws + (16u << 20));     // [16,48M)  [8192][2048]
    bf16* vt_buf  = (bf16*)(ws + (48u << 20));     // [48,64M)  [1024][8192]
    bf16* ybuf    = (bf16*)(ws + (64u << 20));     // [64,80M)
    bf16* ubuf    = (bf16*)(ws + (16u << 20));     // [16,80M) reuse after attn
    float* x2     = (float*)(ws + (80u << 20));    // [80,112M)
    bf16* wattn_h = (bf16*)(ws + (112u << 20));    // 6 MB
    bf16* wproj_h = (bf16*)(ws + (118u << 20));    // 2 MB
    bf16* wfc_h   = (bf16*)(ws + (120u << 20));    // 8 MB
    bf16* wfcp_h  = (bf16*)(ws + (128u << 20));    // 8 MB

    {
        int n1 = 3 * C_ * C_, n2 = C_ * C_, n3 = FF_ * C_, n4 = C_ * FF_;
        cvt_f32_bf16<<<(n1 + 255) / 256, 256, 0, stream>>>(w_attn, wattn_h, n1);
        cvt_f32_bf16<<<(n2 + 255) / 256, 256, 0, stream>>>(w_proj, wproj_h, n2);
        cvt_f32_bf16<<<(n3 + 255) / 256, 256, 0, stream>>>(w_fc, wfc_h, n3);
        cvt_f32_bf16<<<(n4 + 255) / 256, 256, 0, stream>>>(w_fcp, wfcp_h, n4);
    }

    // LN1
    ln_kernel<<<M_TOK, 256, 0, stream>>>(x, ln1w, ln1b, ln_buf);

    // qk = ln_buf @ w_attn[0:2C]^T   [8192, 2048] bf16
    gemm_nt<0><<<dim3(2 * C_ / 128, M_TOK / 128), 256, 0, stream>>>(
        ln_buf, wattn_h, qk_buf, nullptr, M_TOK, 2 * C_, C_);

    // vt = w_attn[2C:3C] @ ln_buf^T  [1024, 8192] bf16   (V^T directly)
    gemm_nt<0><<<dim3(M_TOK / 128, C_ / 128), 256, 0, stream>>>(
        wattn_h + (size_t)2 * C_ * C_, ln_buf, vt_buf, nullptr, C_, M_TOK, C_);

    // attention -> ybuf
    flash_attn<<<dim3(T_ / 128, B_ * H_), 256, 0, stream>>>(qk_buf, vt_buf, ybuf);

    // x2 = x + ybuf @ w_proj^T (f32)
    gemm_nt<1><<<dim3(C_ / 128, M_TOK / 128), 256, 0, stream>>>(
        ybuf, wproj_h, x2, x, M_TOK, C_, C_);

    // LN2
    ln_kernel<<<M_TOK, 256, 0, stream>>>(x2, ln2w, ln2b, ln_buf);

    // u = gelu(ln_buf @ w_fc^T)  [8192, 4096] bf16
    gemm_nt<2><<<dim3(FF_ / 128, M_TOK / 128), 256, 0, stream>>>(
        ln_buf, wfc_h, ubuf, nullptr, M_TOK, FF_, C_);

    // out = x2 + u @ w_fcp^T (f32)
    gemm_nt<1><<<dim3(C_ / 128, M_TOK / 128), 256, 0, stream>>>(
        ubuf, wfcp_h, out, x2, M_TOK, C_, FF_);
}

// Round 4
// 445.819 us; speedup vs baseline: 21.0209x; 1.2835x over previous
//
#include <hip/hip_runtime.h>
#include <hip/hip_bf16.h>

using bf16 = __hip_bfloat16;
typedef __attribute__((ext_vector_type(8))) short short8;
typedef __attribute__((ext_vector_type(4))) float f32x4;

#define B_ 4
#define T_ 2048
#define C_ 1024
#define H_ 16
#define FF_ 4096
#define M_TOK (B_ * T_)   // 8192

#define BARRIER() asm volatile("s_barrier" ::: "memory")
#define WAITLGKM0() asm volatile("s_waitcnt lgkmcnt(0)" ::: "memory")
#define WAITLGKM8() asm volatile("s_waitcnt lgkmcnt(8)" ::: "memory")
#define WAITVM4() asm volatile("s_waitcnt vmcnt(4)" ::: "memory")
#define WAITVM0() asm volatile("s_waitcnt vmcnt(0)" ::: "memory")

// ---------------- async global->LDS 16B ----------------
__device__ __forceinline__ void gload16(const void* g, void* l) {
    __builtin_amdgcn_global_load_lds(
        (const __attribute__((address_space(1))) void*)g,
        (__attribute__((address_space(3))) void*)l, 16, 0, 0);
}

// ---------------- DPP 16-lane rotate reduce ----------------
template <int CTRL>
__device__ __forceinline__ float dpp_rotf(float x) {
    return __int_as_float(__builtin_amdgcn_update_dpp(
        0, __float_as_int(x), CTRL, 0xf, 0xf, true));
}
__device__ __forceinline__ float red16_max(float v) {
    v = fmaxf(v, dpp_rotf<0x128>(v));
    v = fmaxf(v, dpp_rotf<0x124>(v));
    v = fmaxf(v, dpp_rotf<0x122>(v));
    v = fmaxf(v, dpp_rotf<0x121>(v));
    return v;
}
__device__ __forceinline__ float red16_sum(float v) {
    v += dpp_rotf<0x128>(v);
    v += dpp_rotf<0x124>(v);
    v += dpp_rotf<0x122>(v);
    v += dpp_rotf<0x121>(v);
    return v;
}

// ---------------- f32 -> bf16 convert ----------------
__global__ void cvt_f32_bf16(const float* __restrict__ in, bf16* __restrict__ out, int n) {
    int i = blockIdx.x * blockDim.x + threadIdx.x;
    if (i < n) out[i] = __float2bfloat16(in[i]);
}

// ---------------- LayerNorm: f32 in -> bf16 out ----------------
__global__ __launch_bounds__(256) void ln_kernel(const float* __restrict__ x,
                                                 const float* __restrict__ w,
                                                 const float* __restrict__ b,
                                                 bf16* __restrict__ out) {
    int row = blockIdx.x;
    const float* xr = x + (size_t)row * C_;
    int t = threadIdx.x;
    float v[4];
    float s = 0.f, s2 = 0.f;
#pragma unroll
    for (int i = 0; i < 4; i++) {
        float f = xr[t + i * 256];
        v[i] = f;
        s += f;
        s2 += f * f;
    }
#pragma unroll
    for (int off = 32; off > 0; off >>= 1) {
        s += __shfl_down(s, off);
        s2 += __shfl_down(s2, off);
    }
    __shared__ float ss[4], ss2[4];
    int wave = t >> 6, lane = t & 63;
    if (lane == 0) { ss[wave] = s; ss2[wave] = s2; }
    __syncthreads();
    s = ss[0] + ss[1] + ss[2] + ss[3];
    s2 = ss2[0] + ss2[1] + ss2[2] + ss2[3];
    float mu = s * (1.f / C_);
    float var = s2 * (1.f / C_) - mu * mu;
    float rstd = rsqrtf(var + 1e-5f);
    bf16* orow = out + (size_t)row * C_;
#pragma unroll
    for (int i = 0; i < 4; i++) {
        int c = t + i * 256;
        orow[c] = __float2bfloat16((v[i] - mu) * rstd * w[c] + b[c]);
    }
}

// ---------------- 128x128 NT GEMM (m97 structure) ----------------
// EPI 0: store bf16   EPI 1: f32 out = Res + acc   EPI 2: bf16 gelu(acc)
template <int EPI>
__global__ __launch_bounds__(256) void gemm_nt(const bf16* __restrict__ A,
                                               const bf16* __restrict__ Bw,
                                               void* __restrict__ Cout,
                                               const float* __restrict__ Res,
                                               int M, int N, int K) {
    __shared__ alignas(16) bf16 As[128 * 64];
    __shared__ alignas(16) bf16 Bs[128 * 64];
    const int t = threadIdx.x;
    const int m0 = blockIdx.y * 128;
    const int n0 = blockIdx.x * 128;
    const int wave = t >> 6, lane = t & 63;
    const int wm = (wave >> 1) * 64, wn = (wave & 1) * 64;
    const int lrow = lane & 15;
    const int lk = (lane >> 4) * 8;
    const int srow = t >> 3;
    const int scol = (t & 7) * 8;

    f32x4 acc[4][4];
#pragma unroll
    for (int mi = 0; mi < 4; mi++)
#pragma unroll
        for (int ni = 0; ni < 4; ni++) acc[mi][ni] = (f32x4){0.f, 0.f, 0.f, 0.f};

    for (int k0 = 0; k0 < K; k0 += 64) {
#pragma unroll
        for (int i = 0; i < 4; i++) {
            int row = i * 32 + srow;
            gload16(A + (size_t)(m0 + row) * K + k0 + scol, &As[row * 64 + scol]);
        }
#pragma unroll
        for (int i = 0; i < 4; i++) {
            int row = i * 32 + srow;
            gload16(Bw + (size_t)(n0 + row) * K + k0 + scol, &Bs[row * 64 + scol]);
        }
        __syncthreads();
#pragma unroll
        for (int ks = 0; ks < 2; ks++) {
            short8 af[4], bfr[4];
#pragma unroll
            for (int mi = 0; mi < 4; mi++)
                af[mi] = *(const short8*)(&As[(wm + mi * 16 + lrow) * 64 + ks * 32 + lk]);
#pragma unroll
            for (int ni = 0; ni < 4; ni++)
                bfr[ni] = *(const short8*)(&Bs[(wn + ni * 16 + lrow) * 64 + ks * 32 + lk]);
#pragma unroll
            for (int mi = 0; mi < 4; mi++)
#pragma unroll
                for (int ni = 0; ni < 4; ni++)
                    acc[mi][ni] = __builtin_amdgcn_mfma_f32_16x16x32_bf16(
                        af[mi], bfr[ni], acc[mi][ni], 0, 0, 0);
        }
        __syncthreads();
    }

    const int col = lane & 15;
    const int rbase = (lane >> 4) * 4;
#pragma unroll
    for (int mi = 0; mi < 4; mi++) {
#pragma unroll
        for (int ni = 0; ni < 4; ni++) {
            int gr = m0 + wm + mi * 16 + rbase;
            int gc = n0 + wn + ni * 16 + col;
#pragma unroll
            for (int r = 0; r < 4; r++) {
                size_t gidx = (size_t)(gr + r) * N + gc;
                float v = acc[mi][ni][r];
                if constexpr (EPI == 0) {
                    ((bf16*)Cout)[gidx] = __float2bfloat16(v);
                } else if constexpr (EPI == 1) {
                    ((float*)Cout)[gidx] = Res[gidx] + v;
                } else {
                    float ge = 0.5f * v * (1.f + erff(v * 0.70710678f));
                    ((bf16*)Cout)[gidx] = __float2bfloat16(ge);
                }
            }
        }
    }
}

// ---------------- 256x256 8-phase NT GEMM (T2+T3+T4+T5) ----------------
// 512 threads = 8 waves (2Mx4N). LDS 128 KiB: SA/SB double-buffered.
// XOR swizzle: LDS[row][c] = G[row][c ^ ((row&7)<<4 bytes)]; both-sides.
#define HALF256 (128 * 64)
template <int EPI>
__global__ __launch_bounds__(512, 2) void gemm256(const bf16* __restrict__ Ag,
                                                  const bf16* __restrict__ Bg,
                                                  void* __restrict__ Cout,
                                                  int M, int N, int K) {
    __shared__ short SA[2][256 * 64];
    __shared__ short SB[2][256 * 64];

    const int nbx = N >> 8;
    const int nwg = nbx * (M >> 8);
    const int bid = blockIdx.x;
    const int cpx = nwg >> 3;
    const int swzb = (bid & 7) * cpx + (bid >> 3);   // XCD swizzle (nwg%8==0)
    const int m0 = (swzb / nbx) * 256;
    const int n0 = (swzb % nbx) * 256;

    const int t = threadIdx.x;
    const int wid = t >> 6, lane = t & 63;
    const int wm = wid >> 2, wn = wid & 3;
    const int lrow = lane & 15, lg = lane >> 4;
    const int swzr = (lane & 7) * 8;          // read-side XOR in shorts (row&7 == lane&7)
    const int sr = lane >> 3;                 // staging row within 8-group
    const int ssc = ((lane & 7) ^ sr) * 8;    // pre-swizzled source col (shorts)

    f32x4 acc[8][4];
#pragma unroll
    for (int mi = 0; mi < 8; mi++)
#pragma unroll
        for (int ni = 0; ni < 4; ni++) acc[mi][ni] = (f32x4){0.f, 0.f, 0.f, 0.f};
    short8 bfr[4][2];

    const int T = K >> 6;
    const int niter = T >> 1;

    // stage one half-tile (128 rows x 64 shorts): 2 gloads/thread, linear LDS dest
#define STAGE256(ldsbase, g, grow0, k0)                                          \
    {                                                                            \
        _Pragma("unroll") for (int s_ = 0; s_ < 2; s_++) {                       \
            int row_ = s_ * 64 + wid * 8 + sr;                                   \
            gload16(g + (size_t)((grow0) + row_) * K + (k0) + ssc,               \
                    (ldsbase) + row_ * 64 + (lane & 7) * 8);                     \
        }                                                                        \
    }

#define DSREADS256(q, buf)                                                       \
    if ((q) == 0) {                                                              \
        _Pragma("unroll") for (int ni = 0; ni < 4; ni++)                         \
        _Pragma("unroll") for (int ks = 0; ks < 2; ks++)                         \
            bfr[ni][ks] = *(const short8*)(&SB[buf][(wn * 64 + ni * 16 + lrow) * 64 + \
                                                    ((ks * 32 + lg * 8) ^ swzr)]);    \
    }                                                                            \
    _Pragma("unroll") for (int mi2 = 0; mi2 < 2; mi2++)                          \
    _Pragma("unroll") for (int ks = 0; ks < 2; ks++)                             \
        af[mi2 * 2 + ks] = *(const short8*)(&SA[buf][(wm * 128 + (2 * (q) + mi2) * 16 + lrow) * 64 + \
                                                     ((ks * 32 + lg * 8) ^ swzr)]);

#define MFMAS256(q)                                                              \
    __builtin_amdgcn_s_setprio(1);                                               \
    _Pragma("unroll") for (int ks = 0; ks < 2; ks++)                             \
    _Pragma("unroll") for (int ni = 0; ni < 4; ni++)                             \
    _Pragma("unroll") for (int mi2 = 0; mi2 < 2; mi2++)                          \
        acc[2 * (q) + mi2][ni] = __builtin_amdgcn_mfma_f32_16x16x32_bf16(        \
            af[mi2 * 2 + ks], bfr[ni][ks], acc[2 * (q) + mi2][ni], 0, 0, 0);     \
    __builtin_amdgcn_s_setprio(0);

    // ---- prologue: A0,B0 full + B1 ----
    STAGE256(&SA[0][0], Ag, m0, 0);
    STAGE256(&SA[0][HALF256], Ag, m0 + 128, 0);
    STAGE256(&SB[0][0], Bg, n0, 0);
    STAGE256(&SB[0][HALF256], Bg, n0 + 128, 0);
    STAGE256(&SB[1][0], Bg, n0, 64);
    STAGE256(&SB[1][HALF256], Bg, n0 + 128, 64);
    WAITVM4();
    BARRIER();

    for (int iter = 0; iter < niter; iter++) {
        const int tt = 2 * iter;
        const int ka = (tt + 1) * 64, kb = (tt + 2) * 64, kc = (tt + 3) * 64;
        const bool s2 = (tt + 2 < T), s3 = (tt + 3 < T);
        const bool last = (iter == niter - 1);
        short8 af[4];

        // ph1: quad0 of tile tt (buf0); stage A(t+1)h0 -> SA[1]
        DSREADS256(0, 0);
        STAGE256(&SA[1][0], Ag, m0, ka);
        WAITLGKM8();
        BARRIER(); WAITLGKM0(); MFMAS256(0); BARRIER();
        // ph2
        DSREADS256(1, 0);
        STAGE256(&SA[1][HALF256], Ag, m0 + 128, ka);
        BARRIER(); WAITLGKM0(); MFMAS256(1); BARRIER();
        // ph3
        DSREADS256(2, 0);
        if (s2) STAGE256(&SB[0][0], Bg, n0, kb);
        BARRIER(); WAITLGKM0(); MFMAS256(2); BARRIER();
        // ph4
        DSREADS256(3, 0);
        if (s2) STAGE256(&SB[0][HALF256], Bg, n0 + 128, kb);
        BARRIER(); WAITLGKM0(); MFMAS256(3);
        if (last) { WAITVM0(); } else { WAITVM4(); }
        BARRIER();
        // ph5: quad0 of tile tt+1 (buf1); stage A(t+2)h0 -> SA[0]
        DSREADS256(0, 1);
        if (s2) STAGE256(&SA[0][0], Ag, m0, kb);
        WAITLGKM8();
        BARRIER(); WAITLGKM0(); MFMAS256(0); BARRIER();
        // ph6
        DSREADS256(1, 1);
        if (s2) STAGE256(&SA[0][HALF256], Ag, m0 + 128, kb);
        BARRIER(); WAITLGKM0(); MFMAS256(1); BARRIER();
        // ph7
        DSREADS256(2, 1);
        if (s3) STAGE256(&SB[1][0], Bg, n0, kc);
        BARRIER(); WAITLGKM0(); MFMAS256(2); BARRIER();
        // ph8
        DSREADS256(3, 1);
        if (s3) STAGE256(&SB[1][HALF256], Bg, n0 + 128, kc);
        BARRIER(); WAITLGKM0(); MFMAS256(3);
        if (!last) WAITVM4();
        BARRIER();
    }

    // ---- epilogue ----
#pragma unroll
    for (int mi = 0; mi < 8; mi++) {
#pragma unroll
        for (int ni = 0; ni < 4; ni++) {
            int gr = m0 + wm * 128 + mi * 16 + lg * 4;
            int gc = n0 + wn * 64 + ni * 16 + lrow;
#pragma unroll
            for (int r = 0; r < 4; r++) {
                size_t gi = (size_t)(gr + r) * N + gc;
                float v = acc[mi][ni][r];
                if constexpr (EPI == 0) {
                    ((bf16*)Cout)[gi] = __float2bfloat16(v);
                } else {
                    float ge = 0.5f * v * (1.f + erff(v * 0.70710678f));
                    ((bf16*)Cout)[gi] = __float2bfloat16(ge);
                }
            }
        }
    }
}

// ---------------- MFMA flash attention (work-paired, balanced) ----------------
// grid: (8, B*H). Block handles q-tiles {15-pi, pi} (128 rows each, 4 waves x 32).
__global__ __launch_bounds__(256) void flash_attn(const bf16* __restrict__ qk,
                                                  const bf16* __restrict__ vt,
                                                  bf16* __restrict__ y) {
    const int pi = blockIdx.x;
    const int bh = blockIdx.y;
    const int b = bh >> 4, h = bh & 15;
    const int t = threadIdx.x;
    const int wave = t >> 6, lane = t & 63;
    const int lrow = lane & 15, g = lane >> 4, lk = g * 8;

    __shared__ alignas(16) short Ks[64 * 72];
    __shared__ alignas(16) short Vs[64 * 72];
    __shared__ alignas(16) short Ps[128 * 72];

    const size_t rs = 2 * C_;
    const bf16* Qg = qk + (size_t)b * T_ * rs + h * 64;
    const bf16* Kg = Qg + C_;
    const bf16* Vg = vt + (size_t)(h * 64) * M_TOK + b * T_;

    const int srow = t >> 3;
    const int sc8 = (t & 7) * 8;
    const float scale = 0.125f;

    for (int sel = 0; sel < 2; sel++) {
        const int qtb = sel ? pi : 15 - pi;   // heavy first; pair sums to constant work
        const int q0 = qtb * 128;
        const int nkt = 2 * qtb + 2;

        short8 qf[2][2];
#pragma unroll
        for (int mi = 0; mi < 2; mi++) {
            const bf16* qr = Qg + (size_t)(q0 + wave * 32 + mi * 16 + lrow) * rs;
            qf[mi][0] = *(const short8*)(qr + lk);
            qf[mi][1] = *(const short8*)(qr + 32 + lk);
        }

        f32x4 o[2][4];
        float m[2][4], l[2][4];
#pragma unroll
        for (int mi = 0; mi < 2; mi++) {
#pragma unroll
            for (int ni = 0; ni < 4; ni++) o[mi][ni] = (f32x4){0.f, 0.f, 0.f, 0.f};
#pragma unroll
            for (int r = 0; r < 4; r++) { m[mi][r] = -1e30f; l[mi][r] = 0.f; }
        }

        for (int kt = 0; kt < nkt; kt++) {
            const int s0 = kt * 64;
#pragma unroll
            for (int p = 0; p < 2; p++) {
                int r = srow + p * 32;
                *(short8*)(&Ks[r * 72 + sc8]) = *(const short8*)(Kg + (size_t)(s0 + r) * rs + sc8);
                *(short8*)(&Vs[r * 72 + sc8]) = *(const short8*)(Vg + (size_t)r * M_TOK + s0 + sc8);
            }
            __syncthreads();

            f32x4 s[2][4];
#pragma unroll
            for (int mi = 0; mi < 2; mi++)
#pragma unroll
                for (int ni = 0; ni < 4; ni++) s[mi][ni] = (f32x4){0.f, 0.f, 0.f, 0.f};
#pragma unroll
            for (int ks = 0; ks < 2; ks++) {
#pragma unroll
                for (int ni = 0; ni < 4; ni++) {
                    short8 kf = *(const short8*)(&Ks[(ni * 16 + lrow) * 72 + ks * 32 + lk]);
#pragma unroll
                    for (int mi = 0; mi < 2; mi++)
                        s[mi][ni] = __builtin_amdgcn_mfma_f32_16x16x32_bf16(
                            qf[mi][ks], kf, s[mi][ni], 0, 0, 0);
                }
            }

            if (kt >= nkt - 2) {
#pragma unroll
                for (int mi = 0; mi < 2; mi++)
#pragma unroll
                    for (int ni = 0; ni < 4; ni++)
#pragma unroll
                        for (int r = 0; r < 4; r++) {
                            int qg = q0 + wave * 32 + mi * 16 + g * 4 + r;
                            int kvg = s0 + ni * 16 + lrow;
                            s[mi][ni][r] = (kvg > qg) ? -1e30f : s[mi][ni][r] * scale;
                        }
            } else {
#pragma unroll
                for (int mi = 0; mi < 2; mi++)
#pragma unroll
                    for (int ni = 0; ni < 4; ni++)
#pragma unroll
                        for (int r = 0; r < 4; r++) s[mi][ni][r] *= scale;
            }

#pragma unroll
            for (int mi = 0; mi < 2; mi++) {
                float alpha[4];
#pragma unroll
                for (int r = 0; r < 4; r++) {
                    float v = fmaxf(fmaxf(s[mi][0][r], s[mi][1][r]),
                                    fmaxf(s[mi][2][r], s[mi][3][r]));
                    v = red16_max(v);
                    float mn = fmaxf(m[mi][r], v);
                    alpha[r] = __expf(m[mi][r] - mn);
                    m[mi][r] = mn;
                }
                float rowsum[4] = {0.f, 0.f, 0.f, 0.f};
#pragma unroll
                for (int ni = 0; ni < 4; ni++) {
#pragma unroll
                    for (int r = 0; r < 4; r++) {
                        float p = __expf(s[mi][ni][r] - m[mi][r]);
                        rowsum[r] += p;
                        bf16 pb = __float2bfloat16(p);
                        Ps[(wave * 32 + mi * 16 + g * 4 + r) * 72 + ni * 16 + lrow] = *(short*)&pb;
                    }
                }
#pragma unroll
                for (int r = 0; r < 4; r++) {
                    float tot = red16_sum(rowsum[r]);
                    l[mi][r] = l[mi][r] * alpha[r] + tot;
                }
#pragma unroll
                for (int ni = 0; ni < 4; ni++)
#pragma unroll
                    for (int r = 0; r < 4; r++) o[mi][ni][r] *= alpha[r];
            }

#pragma unroll
            for (int ks2 = 0; ks2 < 2; ks2++) {
                short8 pf[2];
#pragma unroll
                for (int mi = 0; mi < 2; mi++)
                    pf[mi] = *(const short8*)(&Ps[(wave * 32 + mi * 16 + lrow) * 72 + ks2 * 32 + lk]);
#pragma unroll
                for (int ni = 0; ni < 4; ni++) {
                    short8 vf = *(const short8*)(&Vs[(ni * 16 + lrow) * 72 + ks2 * 32 + lk]);
#pragma unroll
                    for (int mi = 0; mi < 2; mi++)
                        o[mi][ni] = __builtin_amdgcn_mfma_f32_16x16x32_bf16(
                            pf[mi], vf, o[mi][ni], 0, 0, 0);
                }
            }
            __syncthreads();
        }

#pragma unroll
        for (int mi = 0; mi < 2; mi++) {
            float inv[4];
#pragma unroll
            for (int r = 0; r < 4; r++) inv[r] = 1.f / l[mi][r];
#pragma unroll
            for (int ni = 0; ni < 4; ni++)
#pragma unroll
                for (int r = 0; r < 4; r++) {
                    int qrow = q0 + wave * 32 + mi * 16 + g * 4 + r;
                    y[((size_t)(b * T_ + qrow)) * C_ + h * 64 + ni * 16 + lrow] =
                        __float2bfloat16(o[mi][ni][r] * inv[r]);
                }
        }
    }
}

// ---------------- launch ----------------
extern "C" void kernel_launch(void* const* d_in, const int* in_sizes, int n_in,
                              void* d_out, int out_size, void* d_ws, size_t ws_size,
                              hipStream_t stream) {
    const float* x      = (const float*)d_in[0];
    const float* ln1w   = (const float*)d_in[1];
    const float* ln1b   = (const float*)d_in[2];
    const float* ln2w   = (const float*)d_in[3];
    const float* ln2b   = (const float*)d_in[4];
    const float* w_attn = (const float*)d_in[5];
    const float* w_proj = (const float*)d_in[6];
    const float* w_fc   = (const float*)d_in[7];
    const float* w_fcp  = (const float*)d_in[8];
    float* out = (float*)d_out;

    char* ws = (char*)d_ws;
    bf16* ln_buf  = (bf16*)(ws);
    bf16* qk_buf  = (bf16*)(ws + (16u << 20));
    bf16* vt_buf  = (bf16*)(ws + (48u << 20));
    bf16* ybuf    = (bf16*)(ws + (64u << 20));
    bf16* ubuf    = (bf16*)(ws + (16u << 20));
    float* x2     = (float*)(ws + (80u << 20));
    bf16* wattn_h = (bf16*)(ws + (112u << 20));
    bf16* wproj_h = (bf16*)(ws + (118u << 20));
    bf16* wfc_h   = (bf16*)(ws + (120u << 20));
    bf16* wfcp_h  = (bf16*)(ws + (128u << 20));

    {
        int n1 = 3 * C_ * C_, n2 = C_ * C_, n3 = FF_ * C_, n4 = C_ * FF_;
        cvt_f32_bf16<<<(n1 + 255) / 256, 256, 0, stream>>>(w_attn, wattn_h, n1);
        cvt_f32_bf16<<<(n2 + 255) / 256, 256, 0, stream>>>(w_proj, wproj_h, n2);
        cvt_f32_bf16<<<(n3 + 255) / 256, 256, 0, stream>>>(w_fc, wfc_h, n3);
        cvt_f32_bf16<<<(n4 + 255) / 256, 256, 0, stream>>>(w_fcp, wfcp_h, n4);
    }

    // LN1
    ln_kernel<<<M_TOK, 256, 0, stream>>>(x, ln1w, ln1b, ln_buf);

    // qk = ln_buf @ w_attn[0:2C]^T   [8192, 2048]  (256^2 8-phase)
    gemm256<0><<<dim3((M_TOK / 256) * (2 * C_ / 256)), 512, 0, stream>>>(
        ln_buf, wattn_h, qk_buf, M_TOK, 2 * C_, C_);

    // vt = w_attn[2C:3C] @ ln_buf^T  [1024, 8192]  (128^2)
    gemm_nt<0><<<dim3(M_TOK / 128, C_ / 128), 256, 0, stream>>>(
        wattn_h + (size_t)2 * C_ * C_, ln_buf, vt_buf, nullptr, C_, M_TOK, C_);

    // attention -> ybuf (balanced pairs)
    flash_attn<<<dim3(8, B_ * H_), 256, 0, stream>>>(qk_buf, vt_buf, ybuf);

    // x2 = x + ybuf @ w_proj^T (f32)  (128^2)
    gemm_nt<1><<<dim3(C_ / 128, M_TOK / 128), 256, 0, stream>>>(
        ybuf, wproj_h, x2, x, M_TOK, C_, C_);

    // LN2
    ln_kernel<<<M_TOK, 256, 0, stream>>>(x2, ln2w, ln2b, ln_buf);

    // u = gelu(ln_buf @ w_fc^T)  [8192, 4096]  (256^2 8-phase)
    gemm256<2><<<dim3((M_TOK / 256) * (FF_ / 256)), 512, 0, stream>>>(
        ln_buf, wfc_h, ubuf, M_TOK, FF_, C_);

    // out = x2 + u @ w_fcp^T (f32)  (128^2)
    gemm_nt<1><<<dim3(C_ / 128, M_TOK / 128), 256, 0, stream>>>(
        ubuf, wfcp_h, out, x2, M_TOK, C_, FF_);
}

// Round 5
// 436.744 us; speedup vs baseline: 21.4577x; 1.0208x over previous
//
#include <hip/hip_runtime.h>
#include <hip/hip_bf16.h>

using bf16 = __hip_bfloat16;
typedef __attribute__((ext_vector_type(8))) short short8;
typedef __attribute__((ext_vector_type(4))) short sh4;
typedef __attribute__((ext_vector_type(4))) float f32x4;

#define B_ 4
#define T_ 2048
#define C_ 1024
#define H_ 16
#define FF_ 4096
#define M_TOK (B_ * T_)   // 8192

#define BARRIER() asm volatile("s_barrier" ::: "memory")
#define WAITLGKM0() asm volatile("s_waitcnt lgkmcnt(0)" ::: "memory")
#define WAITLGKM8() asm volatile("s_waitcnt lgkmcnt(8)" ::: "memory")
#define WAITVM4() asm volatile("s_waitcnt vmcnt(4)" ::: "memory")
#define WAITVM0() asm volatile("s_waitcnt vmcnt(0)" ::: "memory")

// ---------------- async global->LDS 16B ----------------
__device__ __forceinline__ void gload16(const void* g, void* l) {
    __builtin_amdgcn_global_load_lds(
        (const __attribute__((address_space(1))) void*)g,
        (__attribute__((address_space(3))) void*)l, 16, 0, 0);
}

// 2^x in one instruction
__device__ __forceinline__ float fexp2(float x) {
    float r;
    asm("v_exp_f32 %0, %1" : "=v"(r) : "v"(x));
    return r;
}

// ---------------- DPP 16-lane rotate reduce ----------------
template <int CTRL>
__device__ __forceinline__ float dpp_rotf(float x) {
    return __int_as_float(__builtin_amdgcn_update_dpp(
        0, __float_as_int(x), CTRL, 0xf, 0xf, true));
}
__device__ __forceinline__ float red16_max(float v) {
    v = fmaxf(v, dpp_rotf<0x128>(v));
    v = fmaxf(v, dpp_rotf<0x124>(v));
    v = fmaxf(v, dpp_rotf<0x122>(v));
    v = fmaxf(v, dpp_rotf<0x121>(v));
    return v;
}
__device__ __forceinline__ float red16_sum(float v) {
    v += dpp_rotf<0x128>(v);
    v += dpp_rotf<0x124>(v);
    v += dpp_rotf<0x122>(v);
    v += dpp_rotf<0x121>(v);
    return v;
}

// ---------------- f32 -> bf16 convert, 4/thread ----------------
__global__ void cvt_f32_bf16_v4(const float* __restrict__ in, bf16* __restrict__ out, int n4) {
    int i = blockIdx.x * blockDim.x + threadIdx.x;
    if (i < n4) {
        float4 v = ((const float4*)in)[i];
        sh4 o;
        bf16 b0 = __float2bfloat16(v.x), b1 = __float2bfloat16(v.y),
             b2 = __float2bfloat16(v.z), b3 = __float2bfloat16(v.w);
        o[0] = *(short*)&b0; o[1] = *(short*)&b1;
        o[2] = *(short*)&b2; o[3] = *(short*)&b3;
        ((sh4*)out)[i] = o;
    }
}

// ---------------- LayerNorm: f32 in -> bf16 out (float4) ----------------
__global__ __launch_bounds__(256) void ln_kernel(const float* __restrict__ x,
                                                 const float* __restrict__ w,
                                                 const float* __restrict__ b,
                                                 bf16* __restrict__ out) {
    int row = blockIdx.x;
    const float* xr = x + (size_t)row * C_;
    int t = threadIdx.x;
    float4 v = ((const float4*)xr)[t];
    float s = v.x + v.y + v.z + v.w;
    float s2 = v.x * v.x + v.y * v.y + v.z * v.z + v.w * v.w;
#pragma unroll
    for (int off = 32; off > 0; off >>= 1) {
        s += __shfl_down(s, off);
        s2 += __shfl_down(s2, off);
    }
    __shared__ float ss[4], ss2[4];
    int wave = t >> 6, lane = t & 63;
    if (lane == 0) { ss[wave] = s; ss2[wave] = s2; }
    __syncthreads();
    s = ss[0] + ss[1] + ss[2] + ss[3];
    s2 = ss2[0] + ss2[1] + ss2[2] + ss2[3];
    float mu = s * (1.f / C_);
    float var = s2 * (1.f / C_) - mu * mu;
    float rstd = rsqrtf(var + 1e-5f);
    float4 wv = ((const float4*)w)[t];
    float4 bv = ((const float4*)b)[t];
    sh4 o;
    bf16 b0 = __float2bfloat16((v.x - mu) * rstd * wv.x + bv.x);
    bf16 b1 = __float2bfloat16((v.y - mu) * rstd * wv.y + bv.y);
    bf16 b2 = __float2bfloat16((v.z - mu) * rstd * wv.z + bv.z);
    bf16 b3 = __float2bfloat16((v.w - mu) * rstd * wv.w + bv.w);
    o[0] = *(short*)&b0; o[1] = *(short*)&b1;
    o[2] = *(short*)&b2; o[3] = *(short*)&b3;
    ((sh4*)(out + (size_t)row * C_))[t] = o;
}

// ---------------- 128x128 NT GEMM (m97 structure) ----------------
// EPI 0: store bf16   EPI 1: f32 out = Res + acc   EPI 2: bf16 gelu(acc)
template <int EPI>
__global__ __launch_bounds__(256) void gemm_nt(const bf16* __restrict__ A,
                                               const bf16* __restrict__ Bw,
                                               void* __restrict__ Cout,
                                               const float* __restrict__ Res,
                                               int M, int N, int K) {
    __shared__ alignas(16) bf16 As[128 * 64];
    __shared__ alignas(16) bf16 Bs[128 * 64];
    const int t = threadIdx.x;
    const int m0 = blockIdx.y * 128;
    const int n0 = blockIdx.x * 128;
    const int wave = t >> 6, lane = t & 63;
    const int wm = (wave >> 1) * 64, wn = (wave & 1) * 64;
    const int lrow = lane & 15;
    const int lk = (lane >> 4) * 8;
    const int srow = t >> 3;
    const int scol = (t & 7) * 8;

    f32x4 acc[4][4];
#pragma unroll
    for (int mi = 0; mi < 4; mi++)
#pragma unroll
        for (int ni = 0; ni < 4; ni++) acc[mi][ni] = (f32x4){0.f, 0.f, 0.f, 0.f};

    for (int k0 = 0; k0 < K; k0 += 64) {
#pragma unroll
        for (int i = 0; i < 4; i++) {
            int row = i * 32 + srow;
            gload16(A + (size_t)(m0 + row) * K + k0 + scol, &As[row * 64 + scol]);
        }
#pragma unroll
        for (int i = 0; i < 4; i++) {
            int row = i * 32 + srow;
            gload16(Bw + (size_t)(n0 + row) * K + k0 + scol, &Bs[row * 64 + scol]);
        }
        __syncthreads();
#pragma unroll
        for (int ks = 0; ks < 2; ks++) {
            short8 af[4], bfr[4];
#pragma unroll
            for (int mi = 0; mi < 4; mi++)
                af[mi] = *(const short8*)(&As[(wm + mi * 16 + lrow) * 64 + ks * 32 + lk]);
#pragma unroll
            for (int ni = 0; ni < 4; ni++)
                bfr[ni] = *(const short8*)(&Bs[(wn + ni * 16 + lrow) * 64 + ks * 32 + lk]);
#pragma unroll
            for (int mi = 0; mi < 4; mi++)
#pragma unroll
                for (int ni = 0; ni < 4; ni++)
                    acc[mi][ni] = __builtin_amdgcn_mfma_f32_16x16x32_bf16(
                        af[mi], bfr[ni], acc[mi][ni], 0, 0, 0);
        }
        __syncthreads();
    }

    const int col = lane & 15;
    const int rbase = (lane >> 4) * 4;
#pragma unroll
    for (int mi = 0; mi < 4; mi++) {
#pragma unroll
        for (int ni = 0; ni < 4; ni++) {
            int gr = m0 + wm + mi * 16 + rbase;
            int gc = n0 + wn + ni * 16 + col;
#pragma unroll
            for (int r = 0; r < 4; r++) {
                size_t gidx = (size_t)(gr + r) * N + gc;
                float v = acc[mi][ni][r];
                if constexpr (EPI == 0) {
                    ((bf16*)Cout)[gidx] = __float2bfloat16(v);
                } else if constexpr (EPI == 1) {
                    ((float*)Cout)[gidx] = Res[gidx] + v;
                } else {
                    float ge = 0.5f * v * (1.f + erff(v * 0.70710678f));
                    ((bf16*)Cout)[gidx] = __float2bfloat16(ge);
                }
            }
        }
    }
}

// ---------------- 256x256 8-phase NT GEMM (T2+T3+T4+T5) ----------------
#define HALF256 (128 * 64)
template <int EPI>
__global__ __launch_bounds__(512, 2) void gemm256(const bf16* __restrict__ Ag,
                                                  const bf16* __restrict__ Bg,
                                                  void* __restrict__ Cout,
                                                  const float* __restrict__ Res,
                                                  int M, int N, int K) {
    __shared__ short SA[2][256 * 64];
    __shared__ short SB[2][256 * 64];

    const int nbx = N >> 8;
    const int nwg = nbx * (M >> 8);
    const int bid = blockIdx.x;
    const int cpx = nwg >> 3;
    const int swzb = (bid & 7) * cpx + (bid >> 3);
    const int m0 = (swzb / nbx) * 256;
    const int n0 = (swzb % nbx) * 256;

    const int t = threadIdx.x;
    const int wid = t >> 6, lane = t & 63;
    const int wm = wid >> 2, wn = wid & 3;
    const int lrow = lane & 15, lg = lane >> 4;
    const int swzr = (lane & 7) * 8;
    const int sr = lane >> 3;
    const int ssc = ((lane & 7) ^ sr) * 8;

    f32x4 acc[8][4];
#pragma unroll
    for (int mi = 0; mi < 8; mi++)
#pragma unroll
        for (int ni = 0; ni < 4; ni++) acc[mi][ni] = (f32x4){0.f, 0.f, 0.f, 0.f};
    short8 bfr[4][2];

    const int T = K >> 6;
    const int niter = T >> 1;

#define STAGE256(ldsbase, g, grow0, k0)                                          \
    {                                                                            \
        _Pragma("unroll") for (int s_ = 0; s_ < 2; s_++) {                       \
            int row_ = s_ * 64 + wid * 8 + sr;                                   \
            gload16(g + (size_t)((grow0) + row_) * K + (k0) + ssc,               \
                    (ldsbase) + row_ * 64 + (lane & 7) * 8);                     \
        }                                                                        \
    }

#define DSREADS256(q, buf)                                                       \
    if ((q) == 0) {                                                              \
        _Pragma("unroll") for (int ni = 0; ni < 4; ni++)                         \
        _Pragma("unroll") for (int ks = 0; ks < 2; ks++)                         \
            bfr[ni][ks] = *(const short8*)(&SB[buf][(wn * 64 + ni * 16 + lrow) * 64 + \
                                                    ((ks * 32 + lg * 8) ^ swzr)]);    \
    }                                                                            \
    _Pragma("unroll") for (int mi2 = 0; mi2 < 2; mi2++)                          \
    _Pragma("unroll") for (int ks = 0; ks < 2; ks++)                             \
        af[mi2 * 2 + ks] = *(const short8*)(&SA[buf][(wm * 128 + (2 * (q) + mi2) * 16 + lrow) * 64 + \
                                                     ((ks * 32 + lg * 8) ^ swzr)]);

#define MFMAS256(q)                                                              \
    __builtin_amdgcn_s_setprio(1);                                               \
    _Pragma("unroll") for (int ks = 0; ks < 2; ks++)                             \
    _Pragma("unroll") for (int ni = 0; ni < 4; ni++)                             \
    _Pragma("unroll") for (int mi2 = 0; mi2 < 2; mi2++)                          \
        acc[2 * (q) + mi2][ni] = __builtin_amdgcn_mfma_f32_16x16x32_bf16(        \
            af[mi2 * 2 + ks], bfr[ni][ks], acc[2 * (q) + mi2][ni], 0, 0, 0);     \
    __builtin_amdgcn_s_setprio(0);

    STAGE256(&SA[0][0], Ag, m0, 0);
    STAGE256(&SA[0][HALF256], Ag, m0 + 128, 0);
    STAGE256(&SB[0][0], Bg, n0, 0);
    STAGE256(&SB[0][HALF256], Bg, n0 + 128, 0);
    STAGE256(&SB[1][0], Bg, n0, 64);
    STAGE256(&SB[1][HALF256], Bg, n0 + 128, 64);
    WAITVM4();
    BARRIER();

    for (int iter = 0; iter < niter; iter++) {
        const int tt = 2 * iter;
        const int ka = (tt + 1) * 64, kb = (tt + 2) * 64, kc = (tt + 3) * 64;
        const bool s2 = (tt + 2 < T), s3 = (tt + 3 < T);
        const bool last = (iter == niter - 1);
        short8 af[4];

        DSREADS256(0, 0);
        STAGE256(&SA[1][0], Ag, m0, ka);
        WAITLGKM8();
        BARRIER(); WAITLGKM0(); MFMAS256(0); BARRIER();
        DSREADS256(1, 0);
        STAGE256(&SA[1][HALF256], Ag, m0 + 128, ka);
        BARRIER(); WAITLGKM0(); MFMAS256(1); BARRIER();
        DSREADS256(2, 0);
        if (s2) STAGE256(&SB[0][0], Bg, n0, kb);
        BARRIER(); WAITLGKM0(); MFMAS256(2); BARRIER();
        DSREADS256(3, 0);
        if (s2) STAGE256(&SB[0][HALF256], Bg, n0 + 128, kb);
        BARRIER(); WAITLGKM0(); MFMAS256(3);
        if (last) { WAITVM0(); } else { WAITVM4(); }
        BARRIER();
        DSREADS256(0, 1);
        if (s2) STAGE256(&SA[0][0], Ag, m0, kb);
        WAITLGKM8();
        BARRIER(); WAITLGKM0(); MFMAS256(0); BARRIER();
        DSREADS256(1, 1);
        if (s2) STAGE256(&SA[0][HALF256], Ag, m0 + 128, kb);
        BARRIER(); WAITLGKM0(); MFMAS256(1); BARRIER();
        DSREADS256(2, 1);
        if (s3) STAGE256(&SB[1][0], Bg, n0, kc);
        BARRIER(); WAITLGKM0(); MFMAS256(2); BARRIER();
        DSREADS256(3, 1);
        if (s3) STAGE256(&SB[1][HALF256], Bg, n0 + 128, kc);
        BARRIER(); WAITLGKM0(); MFMAS256(3);
        if (!last) WAITVM4();
        BARRIER();
    }

#pragma unroll
    for (int mi = 0; mi < 8; mi++) {
#pragma unroll
        for (int ni = 0; ni < 4; ni++) {
            int gr = m0 + wm * 128 + mi * 16 + lg * 4;
            int gc = n0 + wn * 64 + ni * 16 + lrow;
#pragma unroll
            for (int r = 0; r < 4; r++) {
                size_t gi = (size_t)(gr + r) * N + gc;
                float v = acc[mi][ni][r];
                if constexpr (EPI == 0) {
                    ((bf16*)Cout)[gi] = __float2bfloat16(v);
                } else if constexpr (EPI == 1) {
                    ((float*)Cout)[gi] = Res[gi] + v;
                } else {
                    float ge = 0.5f * v * (1.f + erff(v * 0.70710678f));
                    ((bf16*)Cout)[gi] = __float2bfloat16(ge);
                }
            }
        }
    }
}

// ---------------- MFMA flash attention (paired, exp2, defer-max, async stage) ----------------
// grid: (8, B*H). Block handles q-tiles {15-pi, pi} (128 rows each, 4 waves x 32).
__global__ __launch_bounds__(256) void flash_attn(const bf16* __restrict__ qk,
                                                  const bf16* __restrict__ vt,
                                                  bf16* __restrict__ y) {
    const int pi = blockIdx.x;
    const int bh = blockIdx.y;
    const int b = bh >> 4, h = bh & 15;
    const int t = threadIdx.x;
    const int wave = t >> 6, lane = t & 63;
    const int lrow = lane & 15, g = lane >> 4, lk = g * 8;

    __shared__ alignas(16) short Ks[64 * 72];
    __shared__ alignas(16) short Vs[64 * 72];
    __shared__ alignas(16) short Ps[128 * 72];

    const size_t rs = 2 * C_;
    const bf16* Qg = qk + (size_t)b * T_ * rs + h * 64;
    const bf16* Kg = Qg + C_;
    const bf16* Vg = vt + (size_t)(h * 64) * M_TOK + b * T_;

    const int srow = t >> 3;
    const int sc8 = (t & 7) * 8;
    const float scale2 = 0.125f * 1.44269504089f;   // exp2 domain

    for (int sel = 0; sel < 2; sel++) {
        const int qtb = sel ? pi : 15 - pi;
        const int q0 = qtb * 128;
        const int nkt = 2 * qtb + 2;

        short8 qf[2][2];
#pragma unroll
        for (int mi = 0; mi < 2; mi++) {
            const bf16* qr = Qg + (size_t)(q0 + wave * 32 + mi * 16 + lrow) * rs;
            qf[mi][0] = *(const short8*)(qr + lk);
            qf[mi][1] = *(const short8*)(qr + 32 + lk);
        }

        f32x4 o[2][4];
        float m[2][4], l[2][4];
#pragma unroll
        for (int mi = 0; mi < 2; mi++) {
#pragma unroll
            for (int ni = 0; ni < 4; ni++) o[mi][ni] = (f32x4){0.f, 0.f, 0.f, 0.f};
#pragma unroll
            for (int r = 0; r < 4; r++) { m[mi][r] = -1e30f; l[mi][r] = 0.f; }
        }

        // prefetch tile 0 into regs
        short8 kr[2], vr[2];
#pragma unroll
        for (int p = 0; p < 2; p++) {
            int r = srow + p * 32;
            kr[p] = *(const short8*)(Kg + (size_t)r * rs + sc8);
            vr[p] = *(const short8*)(Vg + (size_t)r * M_TOK + sc8);
        }

        for (int kt = 0; kt < nkt; kt++) {
            const int s0 = kt * 64;
            // write staged regs to LDS
#pragma unroll
            for (int p = 0; p < 2; p++) {
                int r = srow + p * 32;
                *(short8*)(&Ks[r * 72 + sc8]) = kr[p];
                *(short8*)(&Vs[r * 72 + sc8]) = vr[p];
            }
            __syncthreads();
            // prefetch next tile (latency hides under compute)
            if (kt + 1 < nkt) {
                const int s0n = (kt + 1) * 64;
#pragma unroll
                for (int p = 0; p < 2; p++) {
                    int r = srow + p * 32;
                    kr[p] = *(const short8*)(Kg + (size_t)(s0n + r) * rs + sc8);
                    vr[p] = *(const short8*)(Vg + (size_t)r * M_TOK + s0n + sc8);
                }
            }

            // ---- S = Q K^T : 32x64 per wave ----
            f32x4 s[2][4];
#pragma unroll
            for (int mi = 0; mi < 2; mi++)
#pragma unroll
                for (int ni = 0; ni < 4; ni++) s[mi][ni] = (f32x4){0.f, 0.f, 0.f, 0.f};
#pragma unroll
            for (int ks = 0; ks < 2; ks++) {
#pragma unroll
                for (int ni = 0; ni < 4; ni++) {
                    short8 kf = *(const short8*)(&Ks[(ni * 16 + lrow) * 72 + ks * 32 + lk]);
#pragma unroll
                    for (int mi = 0; mi < 2; mi++)
                        s[mi][ni] = __builtin_amdgcn_mfma_f32_16x16x32_bf16(
                            qf[mi][ks], kf, s[mi][ni], 0, 0, 0);
                }
            }

            if (kt >= nkt - 2) {
#pragma unroll
                for (int mi = 0; mi < 2; mi++)
#pragma unroll
                    for (int ni = 0; ni < 4; ni++)
#pragma unroll
                        for (int r = 0; r < 4; r++) {
                            int qg = q0 + wave * 32 + mi * 16 + g * 4 + r;
                            int kvg = s0 + ni * 16 + lrow;
                            s[mi][ni][r] = (kvg > qg) ? -1e30f : s[mi][ni][r] * scale2;
                        }
            } else {
#pragma unroll
                for (int mi = 0; mi < 2; mi++)
#pragma unroll
                    for (int ni = 0; ni < 4; ni++)
#pragma unroll
                        for (int r = 0; r < 4; r++) s[mi][ni][r] *= scale2;
            }

#pragma unroll
            for (int mi = 0; mi < 2; mi++) {
                float pm[4];
#pragma unroll
                for (int r = 0; r < 4; r++) {
                    float v = fmaxf(fmaxf(s[mi][0][r], s[mi][1][r]),
                                    fmaxf(s[mi][2][r], s[mi][3][r]));
                    pm[r] = red16_max(v);
                }
                int ok = (pm[0] <= m[mi][0] + 8.f) && (pm[1] <= m[mi][1] + 8.f) &&
                         (pm[2] <= m[mi][2] + 8.f) && (pm[3] <= m[mi][3] + 8.f);
                if (!__all(ok)) {
                    float alpha[4];
#pragma unroll
                    for (int r = 0; r < 4; r++) {
                        float mn = fmaxf(m[mi][r], pm[r]);
                        alpha[r] = fexp2(m[mi][r] - mn);
                        m[mi][r] = mn;
                        l[mi][r] *= alpha[r];
                    }
#pragma unroll
                    for (int ni = 0; ni < 4; ni++)
#pragma unroll
                        for (int r = 0; r < 4; r++) o[mi][ni][r] *= alpha[r];
                }
                float rowsum[4] = {0.f, 0.f, 0.f, 0.f};
#pragma unroll
                for (int ni = 0; ni < 4; ni++) {
#pragma unroll
                    for (int r = 0; r < 4; r++) {
                        float p = fexp2(s[mi][ni][r] - m[mi][r]);
                        rowsum[r] += p;
                        bf16 pb = __float2bfloat16(p);
                        Ps[(wave * 32 + mi * 16 + g * 4 + r) * 72 + ni * 16 + lrow] = *(short*)&pb;
                    }
                }
#pragma unroll
                for (int r = 0; r < 4; r++)
                    l[mi][r] += red16_sum(rowsum[r]);
            }

            // ---- PV ----
#pragma unroll
            for (int ks2 = 0; ks2 < 2; ks2++) {
                short8 pf[2];
#pragma unroll
                for (int mi = 0; mi < 2; mi++)
                    pf[mi] = *(const short8*)(&Ps[(wave * 32 + mi * 16 + lrow) * 72 + ks2 * 32 + lk]);
#pragma unroll
                for (int ni = 0; ni < 4; ni++) {
                    short8 vf = *(const short8*)(&Vs[(ni * 16 + lrow) * 72 + ks2 * 32 + lk]);
#pragma unroll
                    for (int mi = 0; mi < 2; mi++)
                        o[mi][ni] = __builtin_amdgcn_mfma_f32_16x16x32_bf16(
                            pf[mi], vf, o[mi][ni], 0, 0, 0);
                }
            }
            __syncthreads();
        }

#pragma unroll
        for (int mi = 0; mi < 2; mi++) {
            float inv[4];
#pragma unroll
            for (int r = 0; r < 4; r++) inv[r] = 1.f / l[mi][r];
#pragma unroll
            for (int ni = 0; ni < 4; ni++)
#pragma unroll
                for (int r = 0; r < 4; r++) {
                    int qrow = q0 + wave * 32 + mi * 16 + g * 4 + r;
                    y[((size_t)(b * T_ + qrow)) * C_ + h * 64 + ni * 16 + lrow] =
                        __float2bfloat16(o[mi][ni][r] * inv[r]);
                }
        }
    }
}

// ---------------- launch ----------------
extern "C" void kernel_launch(void* const* d_in, const int* in_sizes, int n_in,
                              void* d_out, int out_size, void* d_ws, size_t ws_size,
                              hipStream_t stream) {
    const float* x      = (const float*)d_in[0];
    const float* ln1w   = (const float*)d_in[1];
    const float* ln1b   = (const float*)d_in[2];
    const float* ln2w   = (const float*)d_in[3];
    const float* ln2b   = (const float*)d_in[4];
    const float* w_attn = (const float*)d_in[5];
    const float* w_proj = (const float*)d_in[6];
    const float* w_fc   = (const float*)d_in[7];
    const float* w_fcp  = (const float*)d_in[8];
    float* out = (float*)d_out;

    char* ws = (char*)d_ws;
    bf16* ln_buf  = (bf16*)(ws);
    bf16* qk_buf  = (bf16*)(ws + (16u << 20));
    bf16* vt_buf  = (bf16*)(ws + (48u << 20));
    bf16* ybuf    = (bf16*)(ws + (64u << 20));
    bf16* ubuf    = (bf16*)(ws + (16u << 20));
    float* x2     = (float*)(ws + (80u << 20));
    bf16* wattn_h = (bf16*)(ws + (112u << 20));
    bf16* wproj_h = (bf16*)(ws + (118u << 20));
    bf16* wfc_h   = (bf16*)(ws + (120u << 20));
    bf16* wfcp_h  = (bf16*)(ws + (128u << 20));

    {
        int n1 = 3 * C_ * C_ / 4, n2 = C_ * C_ / 4, n3 = FF_ * C_ / 4, n4 = C_ * FF_ / 4;
        cvt_f32_bf16_v4<<<(n1 + 255) / 256, 256, 0, stream>>>(w_attn, wattn_h, n1);
        cvt_f32_bf16_v4<<<(n2 + 255) / 256, 256, 0, stream>>>(w_proj, wproj_h, n2);
        cvt_f32_bf16_v4<<<(n3 + 255) / 256, 256, 0, stream>>>(w_fc, wfc_h, n3);
        cvt_f32_bf16_v4<<<(n4 + 255) / 256, 256, 0, stream>>>(w_fcp, wfcp_h, n4);
    }

    // LN1
    ln_kernel<<<M_TOK, 256, 0, stream>>>(x, ln1w, ln1b, ln_buf);

    // qk = ln_buf @ w_attn[0:2C]^T   (256^2 8-phase)
    gemm256<0><<<dim3((M_TOK / 256) * (2 * C_ / 256)), 512, 0, stream>>>(
        ln_buf, wattn_h, qk_buf, nullptr, M_TOK, 2 * C_, C_);

    // vt = w_attn[2C:3C] @ ln_buf^T  [1024, 8192]  (128^2)
    gemm_nt<0><<<dim3(M_TOK / 128, C_ / 128), 256, 0, stream>>>(
        wattn_h + (size_t)2 * C_ * C_, ln_buf, vt_buf, nullptr, C_, M_TOK, C_);

    // attention
    flash_attn<<<dim3(8, B_ * H_), 256, 0, stream>>>(qk_buf, vt_buf, ybuf);

    // x2 = x + ybuf @ w_proj^T (f32)  (128^2)
    gemm_nt<1><<<dim3(C_ / 128, M_TOK / 128), 256, 0, stream>>>(
        ybuf, wproj_h, x2, x, M_TOK, C_, C_);

    // LN2
    ln_kernel<<<M_TOK, 256, 0, stream>>>(x2, ln2w, ln2b, ln_buf);

    // u = gelu(ln_buf @ w_fc^T)  (256^2 8-phase)
    gemm256<2><<<dim3((M_TOK / 256) * (FF_ / 256)), 512, 0, stream>>>(
        ln_buf, wfc_h, ubuf, nullptr, M_TOK, FF_, C_);

    // out = x2 + u @ w_fcp^T (f32)  (128^2)
    gemm_nt<1><<<dim3(C_ / 128, M_TOK / 128), 256, 0, stream>>>(
        ubuf, wfcp_h, out, x2, M_TOK, C_, FF_);
}

// Round 7
// 427.148 us; speedup vs baseline: 21.9398x; 1.0225x over previous
//
#include <hip/hip_runtime.h>
#include <hip/hip_bf16.h>

using bf16 = __hip_bfloat16;
typedef __attribute__((ext_vector_type(8))) short short8;
typedef __attribute__((ext_vector_type(4))) short sh4;
typedef __attribute__((ext_vector_type(4))) float f32x4;

#define B_ 4
#define T_ 2048
#define C_ 1024
#define H_ 16
#define FF_ 4096
#define M_TOK (B_ * T_)   // 8192

#define BARRIER() asm volatile("s_barrier" ::: "memory")
#define WAITLGKM0() asm volatile("s_waitcnt lgkmcnt(0)" ::: "memory")
#define WAITLGKM8() asm volatile("s_waitcnt lgkmcnt(8)" ::: "memory")
#define WAITVM4() asm volatile("s_waitcnt vmcnt(4)" ::: "memory")
#define WAITVM0() asm volatile("s_waitcnt vmcnt(0)" ::: "memory")

// ---------------- async global->LDS 16B ----------------
__device__ __forceinline__ void gload16(const void* g, void* l) {
    __builtin_amdgcn_global_load_lds(
        (const __attribute__((address_space(1))) void*)g,
        (__attribute__((address_space(3))) void*)l, 16, 0, 0);
}

// 2^x in one instruction
__device__ __forceinline__ float fexp2(float x) {
    float r;
    asm("v_exp_f32 %0, %1" : "=v"(r) : "v"(x));
    return r;
}

__device__ __forceinline__ float bf16bits2f(short s) {
    return __uint_as_float(((unsigned)(unsigned short)s) << 16);
}

// ---------------- DPP 16-lane rotate reduce ----------------
template <int CTRL>
__device__ __forceinline__ float dpp_rotf(float x) {
    return __int_as_float(__builtin_amdgcn_update_dpp(
        0, __float_as_int(x), CTRL, 0xf, 0xf, true));
}
__device__ __forceinline__ float red16_max(float v) {
    v = fmaxf(v, dpp_rotf<0x128>(v));
    v = fmaxf(v, dpp_rotf<0x124>(v));
    v = fmaxf(v, dpp_rotf<0x122>(v));
    v = fmaxf(v, dpp_rotf<0x121>(v));
    return v;
}
__device__ __forceinline__ float red16_sum(float v) {
    v += dpp_rotf<0x128>(v);
    v += dpp_rotf<0x124>(v);
    v += dpp_rotf<0x122>(v);
    v += dpp_rotf<0x121>(v);
    return v;
}

// ---------------- f32 -> bf16 convert, 4/thread ----------------
__global__ void cvt_f32_bf16_v4(const float* __restrict__ in, bf16* __restrict__ out, int n4) {
    int i = blockIdx.x * blockDim.x + threadIdx.x;
    if (i < n4) {
        float4 v = ((const float4*)in)[i];
        sh4 o;
        bf16 b0 = __float2bfloat16(v.x), b1 = __float2bfloat16(v.y),
             b2 = __float2bfloat16(v.z), b3 = __float2bfloat16(v.w);
        o[0] = *(short*)&b0; o[1] = *(short*)&b1;
        o[2] = *(short*)&b2; o[3] = *(short*)&b3;
        ((sh4*)out)[i] = o;
    }
}

// ---------------- LayerNorm: TIN in -> bf16 out ----------------
template <typename TIN>
__global__ __launch_bounds__(256) void ln_kernel(const TIN* __restrict__ x,
                                                 const float* __restrict__ w,
                                                 const float* __restrict__ b,
                                                 bf16* __restrict__ out) {
    int row = blockIdx.x;
    int t = threadIdx.x;
    float4 v;
    if constexpr (sizeof(TIN) == 4) {
        v = ((const float4*)(x + (size_t)row * C_))[t];
    } else {
        sh4 h = ((const sh4*)(x + (size_t)row * C_))[t];
        v.x = bf16bits2f(h[0]);
        v.y = bf16bits2f(h[1]);
        v.z = bf16bits2f(h[2]);
        v.w = bf16bits2f(h[3]);
    }
    float s = v.x + v.y + v.z + v.w;
    float s2 = v.x * v.x + v.y * v.y + v.z * v.z + v.w * v.w;
#pragma unroll
    for (int off = 32; off > 0; off >>= 1) {
        s += __shfl_down(s, off);
        s2 += __shfl_down(s2, off);
    }
    __shared__ float ss[4], ss2[4];
    int wave = t >> 6, lane = t & 63;
    if (lane == 0) { ss[wave] = s; ss2[wave] = s2; }
    __syncthreads();
    s = ss[0] + ss[1] + ss[2] + ss[3];
    s2 = ss2[0] + ss2[1] + ss2[2] + ss2[3];
    float mu = s * (1.f / C_);
    float var = s2 * (1.f / C_) - mu * mu;
    float rstd = rsqrtf(var + 1e-5f);
    float4 wv = ((const float4*)w)[t];
    float4 bv = ((const float4*)b)[t];
    sh4 o;
    bf16 b0 = __float2bfloat16((v.x - mu) * rstd * wv.x + bv.x);
    bf16 b1 = __float2bfloat16((v.y - mu) * rstd * wv.y + bv.y);
    bf16 b2 = __float2bfloat16((v.z - mu) * rstd * wv.z + bv.z);
    bf16 b3 = __float2bfloat16((v.w - mu) * rstd * wv.w + bv.w);
    o[0] = *(short*)&b0; o[1] = *(short*)&b1;
    o[2] = *(short*)&b2; o[3] = *(short*)&b3;
    ((sh4*)(out + (size_t)row * C_))[t] = o;
}

// ---------------- 128x128 NT GEMM (m97 structure) ----------------
// EPI 0: bf16 out = acc
// EPI 3: bf16 out = f32 Res + acc
// EPI 4: f32 out = bf16 Res + acc
// SWZ 0: linear   SWZ 1: XCD chunk-M (large A)   SWZ 2: XCD chunk-N (large B)
template <int EPI, int SWZ>
__global__ __launch_bounds__(256) void gemm_nt(const bf16* __restrict__ A,
                                               const bf16* __restrict__ Bw,
                                               void* __restrict__ Cout,
                                               const void* __restrict__ Res,
                                               int M, int N, int K) {
    __shared__ alignas(16) bf16 As[128 * 64];
    __shared__ alignas(16) bf16 Bs[128 * 64];
    const int t = threadIdx.x;
    int bx = blockIdx.x, by = blockIdx.y;
    if constexpr (SWZ != 0) {
        const int nbx = gridDim.x, nby = gridDim.y;
        const int nwg = nbx * nby;
        const int id = by * nbx + bx;
        const int cpx = nwg >> 3;
        const int swz = (id & 7) * cpx + (id >> 3);
        if constexpr (SWZ == 1) { by = swz / nbx; bx = swz % nbx; }
        else                    { bx = swz / nby; by = swz % nby; }
    }
    const int m0 = by * 128;
    const int n0 = bx * 128;
    const int wave = t >> 6, lane = t & 63;
    const int wm = (wave >> 1) * 64, wn = (wave & 1) * 64;
    const int lrow = lane & 15;
    const int lk = (lane >> 4) * 8;
    const int srow = t >> 3;
    const int scol = (t & 7) * 8;

    f32x4 acc[4][4];
#pragma unroll
    for (int mi = 0; mi < 4; mi++)
#pragma unroll
        for (int ni = 0; ni < 4; ni++) acc[mi][ni] = (f32x4){0.f, 0.f, 0.f, 0.f};

    for (int k0 = 0; k0 < K; k0 += 64) {
#pragma unroll
        for (int i = 0; i < 4; i++) {
            int row = i * 32 + srow;
            gload16(A + (size_t)(m0 + row) * K + k0 + scol, &As[row * 64 + scol]);
        }
#pragma unroll
        for (int i = 0; i < 4; i++) {
            int row = i * 32 + srow;
            gload16(Bw + (size_t)(n0 + row) * K + k0 + scol, &Bs[row * 64 + scol]);
        }
        __syncthreads();
#pragma unroll
        for (int ks = 0; ks < 2; ks++) {
            short8 af[4], bfr[4];
#pragma unroll
            for (int mi = 0; mi < 4; mi++)
                af[mi] = *(const short8*)(&As[(wm + mi * 16 + lrow) * 64 + ks * 32 + lk]);
#pragma unroll
            for (int ni = 0; ni < 4; ni++)
                bfr[ni] = *(const short8*)(&Bs[(wn + ni * 16 + lrow) * 64 + ks * 32 + lk]);
#pragma unroll
            for (int mi = 0; mi < 4; mi++)
#pragma unroll
                for (int ni = 0; ni < 4; ni++)
                    acc[mi][ni] = __builtin_amdgcn_mfma_f32_16x16x32_bf16(
                        af[mi], bfr[ni], acc[mi][ni], 0, 0, 0);
        }
        __syncthreads();
    }

    const int col = lane & 15;
    const int rbase = (lane >> 4) * 4;
#pragma unroll
    for (int mi = 0; mi < 4; mi++) {
#pragma unroll
        for (int ni = 0; ni < 4; ni++) {
            int gr = m0 + wm + mi * 16 + rbase;
            int gc = n0 + wn + ni * 16 + col;
#pragma unroll
            for (int r = 0; r < 4; r++) {
                size_t gidx = (size_t)(gr + r) * N + gc;
                float v = acc[mi][ni][r];
                if constexpr (EPI == 0) {
                    ((bf16*)Cout)[gidx] = __float2bfloat16(v);
                } else if constexpr (EPI == 3) {
                    float res = ((const float*)Res)[gidx];
                    ((bf16*)Cout)[gidx] = __float2bfloat16(res + v);
                } else {
                    float res = __bfloat162float(((const bf16*)Res)[gidx]);
                    ((float*)Cout)[gidx] = res + v;
                }
            }
        }
    }
}

// ---------------- 256x256 8-phase NT GEMM (T2+T3+T4+T5) ----------------
#define HALF256 (128 * 64)
template <int EPI>
__global__ __launch_bounds__(512, 2) void gemm256(const bf16* __restrict__ Ag,
                                                  const bf16* __restrict__ Bg,
                                                  void* __restrict__ Cout,
                                                  int M, int N, int K) {
    __shared__ short SA[2][256 * 64];
    __shared__ short SB[2][256 * 64];

    const int nbx = N >> 8;
    const int nwg = nbx * (M >> 8);
    const int bid = blockIdx.x;
    const int cpx = nwg >> 3;
    const int swzb = (bid & 7) * cpx + (bid >> 3);
    const int m0 = (swzb / nbx) * 256;
    const int n0 = (swzb % nbx) * 256;

    const int t = threadIdx.x;
    const int wid = t >> 6, lane = t & 63;
    const int wm = wid >> 2, wn = wid & 3;
    const int lrow = lane & 15, lg = lane >> 4;
    const int swzr = (lane & 7) * 8;
    const int sr = lane >> 3;
    const int ssc = ((lane & 7) ^ sr) * 8;

    f32x4 acc[8][4];
#pragma unroll
    for (int mi = 0; mi < 8; mi++)
#pragma unroll
        for (int ni = 0; ni < 4; ni++) acc[mi][ni] = (f32x4){0.f, 0.f, 0.f, 0.f};
    short8 bfr[4][2];

    const int T = K >> 6;
    const int niter = T >> 1;

#define STAGE256(ldsbase, g, grow0, k0)                                          \
    {                                                                            \
        _Pragma("unroll") for (int s_ = 0; s_ < 2; s_++) {                       \
            int row_ = s_ * 64 + wid * 8 + sr;                                   \
            gload16(g + (size_t)((grow0) + row_) * K + (k0) + ssc,               \
                    (ldsbase) + row_ * 64 + (lane & 7) * 8);                     \
        }                                                                        \
    }

#define DSREADS256(q, buf)                                                       \
    if ((q) == 0) {                                                              \
        _Pragma("unroll") for (int ni = 0; ni < 4; ni++)                         \
        _Pragma("unroll") for (int ks = 0; ks < 2; ks++)                         \
            bfr[ni][ks] = *(const short8*)(&SB[buf][(wn * 64 + ni * 16 + lrow) * 64 + \
                                                    ((ks * 32 + lg * 8) ^ swzr)]);    \
    }                                                                            \
    _Pragma("unroll") for (int mi2 = 0; mi2 < 2; mi2++)                          \
    _Pragma("unroll") for (int ks = 0; ks < 2; ks++)                             \
        af[mi2 * 2 + ks] = *(const short8*)(&SA[buf][(wm * 128 + (2 * (q) + mi2) * 16 + lrow) * 64 + \
                                                     ((ks * 32 + lg * 8) ^ swzr)]);

#define MFMAS256(q)                                                              \
    __builtin_amdgcn_s_setprio(1);                                               \
    _Pragma("unroll") for (int ks = 0; ks < 2; ks++)                             \
    _Pragma("unroll") for (int ni = 0; ni < 4; ni++)                             \
    _Pragma("unroll") for (int mi2 = 0; mi2 < 2; mi2++)                          \
        acc[2 * (q) + mi2][ni] = __builtin_amdgcn_mfma_f32_16x16x32_bf16(        \
            af[mi2 * 2 + ks], bfr[ni][ks], acc[2 * (q) + mi2][ni], 0, 0, 0);     \
    __builtin_amdgcn_s_setprio(0);

    STAGE256(&SA[0][0], Ag, m0, 0);
    STAGE256(&SA[0][HALF256], Ag, m0 + 128, 0);
    STAGE256(&SB[0][0], Bg, n0, 0);
    STAGE256(&SB[0][HALF256], Bg, n0 + 128, 0);
    STAGE256(&SB[1][0], Bg, n0, 64);
    STAGE256(&SB[1][HALF256], Bg, n0 + 128, 64);
    WAITVM4();
    BARRIER();

    for (int iter = 0; iter < niter; iter++) {
        const int tt = 2 * iter;
        const int ka = (tt + 1) * 64, kb = (tt + 2) * 64, kc = (tt + 3) * 64;
        const bool s2 = (tt + 2 < T), s3 = (tt + 3 < T);
        const bool last = (iter == niter - 1);
        short8 af[4];

        DSREADS256(0, 0);
        STAGE256(&SA[1][0], Ag, m0, ka);
        WAITLGKM8();
        BARRIER(); WAITLGKM0(); MFMAS256(0); BARRIER();
        DSREADS256(1, 0);
        STAGE256(&SA[1][HALF256], Ag, m0 + 128, ka);
        BARRIER(); WAITLGKM0(); MFMAS256(1); BARRIER();
        DSREADS256(2, 0);
        if (s2) STAGE256(&SB[0][0], Bg, n0, kb);
        BARRIER(); WAITLGKM0(); MFMAS256(2); BARRIER();
        DSREADS256(3, 0);
        if (s2) STAGE256(&SB[0][HALF256], Bg, n0 + 128, kb);
        BARRIER(); WAITLGKM0(); MFMAS256(3);
        if (last) { WAITVM0(); } else { WAITVM4(); }
        BARRIER();
        DSREADS256(0, 1);
        if (s2) STAGE256(&SA[0][0], Ag, m0, kb);
        WAITLGKM8();
        BARRIER(); WAITLGKM0(); MFMAS256(0); BARRIER();
        DSREADS256(1, 1);
        if (s2) STAGE256(&SA[0][HALF256], Ag, m0 + 128, kb);
        BARRIER(); WAITLGKM0(); MFMAS256(1); BARRIER();
        DSREADS256(2, 1);
        if (s3) STAGE256(&SB[1][0], Bg, n0, kc);
        BARRIER(); WAITLGKM0(); MFMAS256(2); BARRIER();
        DSREADS256(3, 1);
        if (s3) STAGE256(&SB[1][HALF256], Bg, n0 + 128, kc);
        BARRIER(); WAITLGKM0(); MFMAS256(3);
        if (!last) WAITVM4();
        BARRIER();
    }

#pragma unroll
    for (int mi = 0; mi < 8; mi++) {
#pragma unroll
        for (int ni = 0; ni < 4; ni++) {
            int gr = m0 + wm * 128 + mi * 16 + lg * 4;
            int gc = n0 + wn * 64 + ni * 16 + lrow;
#pragma unroll
            for (int r = 0; r < 4; r++) {
                size_t gi = (size_t)(gr + r) * N + gc;
                float v = acc[mi][ni][r];
                if constexpr (EPI == 0) {
                    ((bf16*)Cout)[gi] = __float2bfloat16(v);
                } else {
                    float ge = 0.5f * v * (1.f + erff(v * 0.70710678f));
                    ((bf16*)Cout)[gi] = __float2bfloat16(ge);
                }
            }
        }
    }
}

// ---------------- MFMA flash attention (paired, exp2, defer-max, async stage, setprio) ----------------
__global__ __launch_bounds__(256) void flash_attn(const bf16* __restrict__ qk,
                                                  const bf16* __restrict__ vt,
                                                  bf16* __restrict__ y) {
    const int pi = blockIdx.x;
    const int bh = blockIdx.y;
    const int b = bh >> 4, h = bh & 15;
    const int t = threadIdx.x;
    const int wave = t >> 6, lane = t & 63;
    const int lrow = lane & 15, g = lane >> 4, lk = g * 8;

    __shared__ alignas(16) short Ks[64 * 72];
    __shared__ alignas(16) short Vs[64 * 72];
    __shared__ alignas(16) short Ps[128 * 72];

    const size_t rs = 2 * C_;
    const bf16* Qg = qk + (size_t)b * T_ * rs + h * 64;
    const bf16* Kg = Qg + C_;
    const bf16* Vg = vt + (size_t)(h * 64) * M_TOK + b * T_;

    const int srow = t >> 3;
    const int sc8 = (t & 7) * 8;
    const float scale2 = 0.125f * 1.44269504089f;

    for (int sel = 0; sel < 2; sel++) {
        const int qtb = sel ? pi : 15 - pi;
        const int q0 = qtb * 128;
        const int nkt = 2 * qtb + 2;

        short8 qf[2][2];
#pragma unroll
        for (int mi = 0; mi < 2; mi++) {
            const bf16* qr = Qg + (size_t)(q0 + wave * 32 + mi * 16 + lrow) * rs;
            qf[mi][0] = *(const short8*)(qr + lk);
            qf[mi][1] = *(const short8*)(qr + 32 + lk);
        }

        f32x4 o[2][4];
        float m[2][4], l[2][4];
#pragma unroll
        for (int mi = 0; mi < 2; mi++) {
#pragma unroll
            for (int ni = 0; ni < 4; ni++) o[mi][ni] = (f32x4){0.f, 0.f, 0.f, 0.f};
#pragma unroll
            for (int r = 0; r < 4; r++) { m[mi][r] = -1e30f; l[mi][r] = 0.f; }
        }

        short8 kr[2], vr[2];
#pragma unroll
        for (int p = 0; p < 2; p++) {
            int r = srow + p * 32;
            kr[p] = *(const short8*)(Kg + (size_t)r * rs + sc8);
            vr[p] = *(const short8*)(Vg + (size_t)r * M_TOK + sc8);
        }

        for (int kt = 0; kt < nkt; kt++) {
            const int s0 = kt * 64;
#pragma unroll
            for (int p = 0; p < 2; p++) {
                int r = srow + p * 32;
                *(short8*)(&Ks[r * 72 + sc8]) = kr[p];
                *(short8*)(&Vs[r * 72 + sc8]) = vr[p];
            }
            __syncthreads();
            if (kt + 1 < nkt) {
                const int s0n = (kt + 1) * 64;
#pragma unroll
                for (int p = 0; p < 2; p++) {
                    int r = srow + p * 32;
                    kr[p] = *(const short8*)(Kg + (size_t)(s0n + r) * rs + sc8);
                    vr[p] = *(const short8*)(Vg + (size_t)r * M_TOK + s0n + sc8);
                }
            }

            f32x4 s[2][4];
#pragma unroll
            for (int mi = 0; mi < 2; mi++)
#pragma unroll
                for (int ni = 0; ni < 4; ni++) s[mi][ni] = (f32x4){0.f, 0.f, 0.f, 0.f};
            __builtin_amdgcn_s_setprio(1);
#pragma unroll
            for (int ks = 0; ks < 2; ks++) {
#pragma unroll
                for (int ni = 0; ni < 4; ni++) {
                    short8 kf = *(const short8*)(&Ks[(ni * 16 + lrow) * 72 + ks * 32 + lk]);
#pragma unroll
                    for (int mi = 0; mi < 2; mi++)
                        s[mi][ni] = __builtin_amdgcn_mfma_f32_16x16x32_bf16(
                            qf[mi][ks], kf, s[mi][ni], 0, 0, 0);
                }
            }
            __builtin_amdgcn_s_setprio(0);

            if (kt >= nkt - 2) {
#pragma unroll
                for (int mi = 0; mi < 2; mi++)
#pragma unroll
                    for (int ni = 0; ni < 4; ni++)
#pragma unroll
                        for (int r = 0; r < 4; r++) {
                            int qg = q0 + wave * 32 + mi * 16 + g * 4 + r;
                            int kvg = s0 + ni * 16 + lrow;
                            s[mi][ni][r] = (kvg > qg) ? -1e30f : s[mi][ni][r] * scale2;
                        }
            } else {
#pragma unroll
                for (int mi = 0; mi < 2; mi++)
#pragma unroll
                    for (int ni = 0; ni < 4; ni++)
#pragma unroll
                        for (int r = 0; r < 4; r++) s[mi][ni][r] *= scale2;
            }

#pragma unroll
            for (int mi = 0; mi < 2; mi++) {
                float pm[4];
#pragma unroll
                for (int r = 0; r < 4; r++) {
                    float v = fmaxf(fmaxf(s[mi][0][r], s[mi][1][r]),
                                    fmaxf(s[mi][2][r], s[mi][3][r]));
                    pm[r] = red16_max(v);
                }
                int ok = (pm[0] <= m[mi][0] + 8.f) && (pm[1] <= m[mi][1] + 8.f) &&
                         (pm[2] <= m[mi][2] + 8.f) && (pm[3] <= m[mi][3] + 8.f);
                if (!__all(ok)) {
                    float alpha[4];
#pragma unroll
                    for (int r = 0; r < 4; r++) {
                        float mn = fmaxf(m[mi][r], pm[r]);
                        alpha[r] = fexp2(m[mi][r] - mn);
                        m[mi][r] = mn;
                        l[mi][r] *= alpha[r];
                    }
#pragma unroll
                    for (int ni = 0; ni < 4; ni++)
#pragma unroll
                        for (int r = 0; r < 4; r++) o[mi][ni][r] *= alpha[r];
                }
                float rowsum[4] = {0.f, 0.f, 0.f, 0.f};
#pragma unroll
                for (int ni = 0; ni < 4; ni++) {
#pragma unroll
                    for (int r = 0; r < 4; r++) {
                        float p = fexp2(s[mi][ni][r] - m[mi][r]);
                        rowsum[r] += p;
                        bf16 pb = __float2bfloat16(p);
                        Ps[(wave * 32 + mi * 16 + g * 4 + r) * 72 + ni * 16 + lrow] = *(short*)&pb;
                    }
                }
#pragma unroll
                for (int r = 0; r < 4; r++)
                    l[mi][r] += red16_sum(rowsum[r]);
            }

            __builtin_amdgcn_s_setprio(1);
#pragma unroll
            for (int ks2 = 0; ks2 < 2; ks2++) {
                short8 pf[2];
#pragma unroll
                for (int mi = 0; mi < 2; mi++)
                    pf[mi] = *(const short8*)(&Ps[(wave * 32 + mi * 16 + lrow) * 72 + ks2 * 32 + lk]);
#pragma unroll
                for (int ni = 0; ni < 4; ni++) {
                    short8 vf = *(const short8*)(&Vs[(ni * 16 + lrow) * 72 + ks2 * 32 + lk]);
#pragma unroll
                    for (int mi = 0; mi < 2; mi++)
                        o[mi][ni] = __builtin_amdgcn_mfma_f32_16x16x32_bf16(
                            pf[mi], vf, o[mi][ni], 0, 0, 0);
                }
            }
            __builtin_amdgcn_s_setprio(0);
            __syncthreads();
        }

#pragma unroll
        for (int mi = 0; mi < 2; mi++) {
            float inv[4];
#pragma unroll
            for (int r = 0; r < 4; r++) inv[r] = 1.f / l[mi][r];
#pragma unroll
            for (int ni = 0; ni < 4; ni++)
#pragma unroll
                for (int r = 0; r < 4; r++) {
                    int qrow = q0 + wave * 32 + mi * 16 + g * 4 + r;
                    y[((size_t)(b * T_ + qrow)) * C_ + h * 64 + ni * 16 + lrow] =
                        __float2bfloat16(o[mi][ni][r] * inv[r]);
                }
        }
    }
}

// ---------------- launch ----------------
extern "C" void kernel_launch(void* const* d_in, const int* in_sizes, int n_in,
                              void* d_out, int out_size, void* d_ws, size_t ws_size,
                              hipStream_t stream) {
    const float* x      = (const float*)d_in[0];
    const float* ln1w   = (const float*)d_in[1];
    const float* ln1b   = (const float*)d_in[2];
    const float* ln2w   = (const float*)d_in[3];
    const float* ln2b   = (const float*)d_in[4];
    const float* w_attn = (const float*)d_in[5];
    const float* w_proj = (const float*)d_in[6];
    const float* w_fc   = (const float*)d_in[7];
    const float* w_fcp  = (const float*)d_in[8];
    float* out = (float*)d_out;

    char* ws = (char*)d_ws;
    bf16* ln_buf  = (bf16*)(ws);                   // [0,16M)
    bf16* qk_buf  = (bf16*)(ws + (16u << 20));     // [16,48M)
    bf16* vt_buf  = (bf16*)(ws + (48u << 20));     // [48,64M)
    bf16* ybuf    = (bf16*)(ws + (64u << 20));     // [64,80M)
    bf16* ubuf    = (bf16*)(ws + (16u << 20));     // [16,80M) reuse after attn
    bf16* x2b     = (bf16*)(ws + (80u << 20));     // [80,96M) bf16 residual state
    bf16* wattn_h = (bf16*)(ws + (112u << 20));
    bf16* wproj_h = (bf16*)(ws + (118u << 20));
    bf16* wfc_h   = (bf16*)(ws + (120u << 20));
    bf16* wfcp_h  = (bf16*)(ws + (128u << 20));

    {
        int n1 = 3 * C_ * C_ / 4, n2 = C_ * C_ / 4, n3 = FF_ * C_ / 4, n4 = C_ * FF_ / 4;
        cvt_f32_bf16_v4<<<(n1 + 255) / 256, 256, 0, stream>>>(w_attn, wattn_h, n1);
        cvt_f32_bf16_v4<<<(n2 + 255) / 256, 256, 0, stream>>>(w_proj, wproj_h, n2);
        cvt_f32_bf16_v4<<<(n3 + 255) / 256, 256, 0, stream>>>(w_fc, wfc_h, n3);
        cvt_f32_bf16_v4<<<(n4 + 255) / 256, 256, 0, stream>>>(w_fcp, wfcp_h, n4);
    }

    // LN1 (f32 in)
    ln_kernel<float><<<M_TOK, 256, 0, stream>>>(x, ln1w, ln1b, ln_buf);

    // qk = ln_buf @ w_attn[0:2C]^T  (256^2 8-phase)
    gemm256<0><<<dim3((M_TOK / 256) * (2 * C_ / 256)), 512, 0, stream>>>(
        ln_buf, wattn_h, qk_buf, M_TOK, 2 * C_, C_);

    // vt = w_v @ ln_buf^T  [1024, 8192]  (128^2, chunk-N: large B)
    gemm_nt<0, 2><<<dim3(M_TOK / 128, C_ / 128), 256, 0, stream>>>(
        wattn_h + (size_t)2 * C_ * C_, ln_buf, vt_buf, nullptr, C_, M_TOK, C_);

    // attention
    flash_attn<<<dim3(8, B_ * H_), 256, 0, stream>>>(qk_buf, vt_buf, ybuf);

    // x2b = bf16(x + ybuf @ w_proj^T)  (128^2, chunk-M: large A)
    gemm_nt<3, 1><<<dim3(C_ / 128, M_TOK / 128), 256, 0, stream>>>(
        ybuf, wproj_h, x2b, x, M_TOK, C_, C_);

    // LN2 (bf16 in)
    ln_kernel<bf16><<<M_TOK, 256, 0, stream>>>(x2b, ln2w, ln2b, ln_buf);

    // u = gelu(ln_buf @ w_fc^T)  (256^2 8-phase)
    gemm256<2><<<dim3((M_TOK / 256) * (FF_ / 256)), 512, 0, stream>>>(
        ln_buf, wfc_h, ubuf, M_TOK, FF_, C_);

    // out = f32(x2b) + u @ w_fcp^T  (128^2, chunk-M: large A)
    gemm_nt<4, 1><<<dim3(C_ / 128, M_TOK / 128), 256, 0, stream>>>(
        ubuf, wfcp_h, out, x2b, M_TOK, C_, FF_);
}

// Round 8
// 390.257 us; speedup vs baseline: 24.0138x; 1.0945x over previous
//
#include <hip/hip_runtime.h>
#include <hip/hip_bf16.h>

using bf16 = __hip_bfloat16;
typedef __attribute__((ext_vector_type(8))) short short8;
typedef __attribute__((ext_vector_type(4))) short sh4;
typedef __attribute__((ext_vector_type(4))) float f32x4;

#define B_ 4
#define T_ 2048
#define C_ 1024
#define H_ 16
#define FF_ 4096
#define M_TOK (B_ * T_)   // 8192

#define BARRIER() asm volatile("s_barrier" ::: "memory")
#define WAITLGKM0() asm volatile("s_waitcnt lgkmcnt(0)" ::: "memory")
#define WAITLGKM8() asm volatile("s_waitcnt lgkmcnt(8)" ::: "memory")
#define WAITVM4() asm volatile("s_waitcnt vmcnt(4)" ::: "memory")
#define WAITVM2() asm volatile("s_waitcnt vmcnt(2)" ::: "memory")
#define WAITVM0() asm volatile("s_waitcnt vmcnt(0)" ::: "memory")

// ---------------- async global->LDS 16B ----------------
__device__ __forceinline__ void gload16(const void* g, void* l) {
    __builtin_amdgcn_global_load_lds(
        (const __attribute__((address_space(1))) void*)g,
        (__attribute__((address_space(3))) void*)l, 16, 0, 0);
}

// 2^x in one instruction
__device__ __forceinline__ float fexp2(float x) {
    float r;
    asm("v_exp_f32 %0, %1" : "=v"(r) : "v"(x));
    return r;
}

__device__ __forceinline__ float bf16bits2f(short s) {
    return __uint_as_float(((unsigned)(unsigned short)s) << 16);
}

// ---------------- DPP 16-lane rotate reduce ----------------
template <int CTRL>
__device__ __forceinline__ float dpp_rotf(float x) {
    return __int_as_float(__builtin_amdgcn_update_dpp(
        0, __float_as_int(x), CTRL, 0xf, 0xf, true));
}
__device__ __forceinline__ float red16_max(float v) {
    v = fmaxf(v, dpp_rotf<0x128>(v));
    v = fmaxf(v, dpp_rotf<0x124>(v));
    v = fmaxf(v, dpp_rotf<0x122>(v));
    v = fmaxf(v, dpp_rotf<0x121>(v));
    return v;
}
__device__ __forceinline__ float red16_sum(float v) {
    v += dpp_rotf<0x128>(v);
    v += dpp_rotf<0x124>(v);
    v += dpp_rotf<0x122>(v);
    v += dpp_rotf<0x121>(v);
    return v;
}

// ---------------- f32 -> bf16 convert, 4/thread ----------------
__global__ void cvt_f32_bf16_v4(const float* __restrict__ in, bf16* __restrict__ out, int n4) {
    int i = blockIdx.x * blockDim.x + threadIdx.x;
    if (i < n4) {
        float4 v = ((const float4*)in)[i];
        sh4 o;
        bf16 b0 = __float2bfloat16(v.x), b1 = __float2bfloat16(v.y),
             b2 = __float2bfloat16(v.z), b3 = __float2bfloat16(v.w);
        o[0] = *(short*)&b0; o[1] = *(short*)&b1;
        o[2] = *(short*)&b2; o[3] = *(short*)&b3;
        ((sh4*)out)[i] = o;
    }
}

// ---------------- LayerNorm: TIN in -> bf16 out ----------------
template <typename TIN>
__global__ __launch_bounds__(256) void ln_kernel(const TIN* __restrict__ x,
                                                 const float* __restrict__ w,
                                                 const float* __restrict__ b,
                                                 bf16* __restrict__ out) {
    int row = blockIdx.x;
    int t = threadIdx.x;
    float4 v;
    if constexpr (sizeof(TIN) == 4) {
        v = ((const float4*)(x + (size_t)row * C_))[t];
    } else {
        sh4 h = ((const sh4*)(x + (size_t)row * C_))[t];
        v.x = bf16bits2f(h[0]);
        v.y = bf16bits2f(h[1]);
        v.z = bf16bits2f(h[2]);
        v.w = bf16bits2f(h[3]);
    }
    float s = v.x + v.y + v.z + v.w;
    float s2 = v.x * v.x + v.y * v.y + v.z * v.z + v.w * v.w;
#pragma unroll
    for (int off = 32; off > 0; off >>= 1) {
        s += __shfl_down(s, off);
        s2 += __shfl_down(s2, off);
    }
    __shared__ float ss[4], ss2[4];
    int wave = t >> 6, lane = t & 63;
    if (lane == 0) { ss[wave] = s; ss2[wave] = s2; }
    __syncthreads();
    s = ss[0] + ss[1] + ss[2] + ss[3];
    s2 = ss2[0] + ss2[1] + ss2[2] + ss2[3];
    float mu = s * (1.f / C_);
    float var = s2 * (1.f / C_) - mu * mu;
    float rstd = rsqrtf(var + 1e-5f);
    float4 wv = ((const float4*)w)[t];
    float4 bv = ((const float4*)b)[t];
    sh4 o;
    bf16 b0 = __float2bfloat16((v.x - mu) * rstd * wv.x + bv.x);
    bf16 b1 = __float2bfloat16((v.y - mu) * rstd * wv.y + bv.y);
    bf16 b2 = __float2bfloat16((v.z - mu) * rstd * wv.z + bv.z);
    bf16 b3 = __float2bfloat16((v.w - mu) * rstd * wv.w + bv.w);
    o[0] = *(short*)&b0; o[1] = *(short*)&b1;
    o[2] = *(short*)&b2; o[3] = *(short*)&b3;
    ((sh4*)(out + (size_t)row * C_))[t] = o;
}

// ======== shared staging macro: 128 rows x 64 shorts, linear LDS dest,
// ======== pre-swizzled global source (both-sides st swizzle) ========
#define STG(ldsbase, g, grow0, k0)                                               \
    {                                                                            \
        _Pragma("unroll") for (int s_ = 0; s_ < 2; s_++) {                       \
            int row_ = s_ * 64 + wid * 8 + sr;                                   \
            gload16(g + (size_t)((grow0) + row_) * K + (k0) + ssc,               \
                    (ldsbase) + row_ * 64 + (lane & 7) * 8);                     \
        }                                                                        \
    }

// ---------------- 256x256 8-phase NT GEMM (T2+T3+T4+T5) ----------------
#define HALF256 (128 * 64)
template <int EPI>
__global__ __launch_bounds__(512, 2) void gemm256(const bf16* __restrict__ Ag,
                                                  const bf16* __restrict__ Bg,
                                                  void* __restrict__ Cout,
                                                  int M, int N, int K) {
    __shared__ short SA[2][256 * 64];
    __shared__ short SB[2][256 * 64];

    const int nbx = N >> 8;
    const int nwg = nbx * (M >> 8);
    const int bid = blockIdx.x;
    const int cpx = nwg >> 3;
    const int swzb = (bid & 7) * cpx + (bid >> 3);
    const int m0 = (swzb / nbx) * 256;
    const int n0 = (swzb % nbx) * 256;

    const int t = threadIdx.x;
    const int wid = t >> 6, lane = t & 63;
    const int wm = wid >> 2, wn = wid & 3;
    const int lrow = lane & 15, lg = lane >> 4;
    const int swzr = (lane & 7) * 8;
    const int sr = lane >> 3;
    const int ssc = ((lane & 7) ^ sr) * 8;

    f32x4 acc[8][4];
#pragma unroll
    for (int mi = 0; mi < 8; mi++)
#pragma unroll
        for (int ni = 0; ni < 4; ni++) acc[mi][ni] = (f32x4){0.f, 0.f, 0.f, 0.f};
    short8 bfr[4][2];

    const int T = K >> 6;
    const int niter = T >> 1;

#define DSREADS256(q, buf)                                                       \
    if ((q) == 0) {                                                              \
        _Pragma("unroll") for (int ni = 0; ni < 4; ni++)                         \
        _Pragma("unroll") for (int ks = 0; ks < 2; ks++)                         \
            bfr[ni][ks] = *(const short8*)(&SB[buf][(wn * 64 + ni * 16 + lrow) * 64 + \
                                                    ((ks * 32 + lg * 8) ^ swzr)]);    \
    }                                                                            \
    _Pragma("unroll") for (int mi2 = 0; mi2 < 2; mi2++)                          \
    _Pragma("unroll") for (int ks = 0; ks < 2; ks++)                             \
        af[mi2 * 2 + ks] = *(const short8*)(&SA[buf][(wm * 128 + (2 * (q) + mi2) * 16 + lrow) * 64 + \
                                                     ((ks * 32 + lg * 8) ^ swzr)]);

#define MFMAS256(q)                                                              \
    __builtin_amdgcn_s_setprio(1);                                               \
    _Pragma("unroll") for (int ks = 0; ks < 2; ks++)                             \
    _Pragma("unroll") for (int ni = 0; ni < 4; ni++)                             \
    _Pragma("unroll") for (int mi2 = 0; mi2 < 2; mi2++)                          \
        acc[2 * (q) + mi2][ni] = __builtin_amdgcn_mfma_f32_16x16x32_bf16(        \
            af[mi2 * 2 + ks], bfr[ni][ks], acc[2 * (q) + mi2][ni], 0, 0, 0);     \
    __builtin_amdgcn_s_setprio(0);

    STG(&SA[0][0], Ag, m0, 0);
    STG(&SA[0][HALF256], Ag, m0 + 128, 0);
    STG(&SB[0][0], Bg, n0, 0);
    STG(&SB[0][HALF256], Bg, n0 + 128, 0);
    STG(&SB[1][0], Bg, n0, 64);
    STG(&SB[1][HALF256], Bg, n0 + 128, 64);
    WAITVM4();
    BARRIER();

    for (int iter = 0; iter < niter; iter++) {
        const int tt = 2 * iter;
        const int ka = (tt + 1) * 64, kb = (tt + 2) * 64, kc = (tt + 3) * 64;
        const bool s2 = (tt + 2 < T), s3 = (tt + 3 < T);
        const bool last = (iter == niter - 1);
        short8 af[4];

        DSREADS256(0, 0);
        STG(&SA[1][0], Ag, m0, ka);
        WAITLGKM8();
        BARRIER(); WAITLGKM0(); MFMAS256(0); BARRIER();
        DSREADS256(1, 0);
        STG(&SA[1][HALF256], Ag, m0 + 128, ka);
        BARRIER(); WAITLGKM0(); MFMAS256(1); BARRIER();
        DSREADS256(2, 0);
        if (s2) STG(&SB[0][0], Bg, n0, kb);
        BARRIER(); WAITLGKM0(); MFMAS256(2); BARRIER();
        DSREADS256(3, 0);
        if (s2) STG(&SB[0][HALF256], Bg, n0 + 128, kb);
        BARRIER(); WAITLGKM0(); MFMAS256(3);
        if (last) { WAITVM0(); } else { WAITVM4(); }
        BARRIER();
        DSREADS256(0, 1);
        if (s2) STG(&SA[0][0], Ag, m0, kb);
        WAITLGKM8();
        BARRIER(); WAITLGKM0(); MFMAS256(0); BARRIER();
        DSREADS256(1, 1);
        if (s2) STG(&SA[0][HALF256], Ag, m0 + 128, kb);
        BARRIER(); WAITLGKM0(); MFMAS256(1); BARRIER();
        DSREADS256(2, 1);
        if (s3) STG(&SB[1][0], Bg, n0, kc);
        BARRIER(); WAITLGKM0(); MFMAS256(2); BARRIER();
        DSREADS256(3, 1);
        if (s3) STG(&SB[1][HALF256], Bg, n0 + 128, kc);
        BARRIER(); WAITLGKM0(); MFMAS256(3);
        if (!last) WAITVM4();
        BARRIER();
    }

#pragma unroll
    for (int mi = 0; mi < 8; mi++) {
#pragma unroll
        for (int ni = 0; ni < 4; ni++) {
            int gr = m0 + wm * 128 + mi * 16 + lg * 4;
            int gc = n0 + wn * 64 + ni * 16 + lrow;
#pragma unroll
            for (int r = 0; r < 4; r++) {
                size_t gi = (size_t)(gr + r) * N + gc;
                float v = acc[mi][ni][r];
                if constexpr (EPI == 0) {
                    ((bf16*)Cout)[gi] = __float2bfloat16(v);
                } else {
                    float ge = 0.5f * v * (1.f + erff(v * 0.70710678f));
                    ((bf16*)Cout)[gi] = __float2bfloat16(ge);
                }
            }
        }
    }
}

// ---------------- 256x128 8-phase NT GEMM (for N=1024-class shapes) ----------------
// 512 threads = 8 waves (4M x 2N), wave tile 64x64. SA 64KB + SB 32KB dbuf = 96KB.
// Stage cadence: A(t+1) @ph1, B(t+2) @ph2, A(t+2) @ph3, B(t+3) @ph4; vmcnt(2).
// EPI 0: bf16 out = acc   EPI 3: bf16 out = f32 Res + acc   EPI 4: f32 out = bf16 Res + acc
template <int EPI>
__global__ __launch_bounds__(512, 2) void gemm256x128(const bf16* __restrict__ Ag,
                                                      const bf16* __restrict__ Bg,
                                                      void* __restrict__ Cout,
                                                      const void* __restrict__ Res,
                                                      int M, int N, int K) {
    __shared__ short SA[2][256 * 64];
    __shared__ short SB[2][128 * 64];

    const int nbx = N >> 7;
    const int nwg = nbx * (M >> 8);
    const int bid = blockIdx.x;
    const int cpx = nwg >> 3;
    const int swzb = (bid & 7) * cpx + (bid >> 3);   // XCD chunk (nwg%8==0)
    const int m0 = (swzb / nbx) * 256;
    const int n0 = (swzb % nbx) * 128;

    const int t = threadIdx.x;
    const int wid = t >> 6, lane = t & 63;
    const int wm = wid >> 1, wn = wid & 1;
    const int lrow = lane & 15, lg = lane >> 4;
    const int swzr = (lane & 7) * 8;
    const int sr = lane >> 3;
    const int ssc = ((lane & 7) ^ sr) * 8;

    f32x4 acc[4][4];
#pragma unroll
    for (int mi = 0; mi < 4; mi++)
#pragma unroll
        for (int ni = 0; ni < 4; ni++) acc[mi][ni] = (f32x4){0.f, 0.f, 0.f, 0.f};
    short8 bfr[4][2];

    const int T = K >> 6;
    const int niter = T >> 1;

#define DSRX(p, buf)                                                             \
    if ((p) == 0) {                                                              \
        _Pragma("unroll") for (int ni = 0; ni < 4; ni++)                         \
        _Pragma("unroll") for (int ks = 0; ks < 2; ks++)                         \
            bfr[ni][ks] = *(const short8*)(&SB[buf][(wn * 64 + ni * 16 + lrow) * 64 + \
                                                    ((ks * 32 + lg * 8) ^ swzr)]);    \
    }                                                                            \
    _Pragma("unroll") for (int mi2 = 0; mi2 < 2; mi2++)                          \
    _Pragma("unroll") for (int ks = 0; ks < 2; ks++)                             \
        af[mi2 * 2 + ks] = *(const short8*)(&SA[buf][(wm * 64 + (2 * (p) + mi2) * 16 + lrow) * 64 + \
                                                     ((ks * 32 + lg * 8) ^ swzr)]);

#define MFX(p)                                                                   \
    __builtin_amdgcn_s_setprio(1);                                               \
    _Pragma("unroll") for (int ks = 0; ks < 2; ks++)                             \
    _Pragma("unroll") for (int ni = 0; ni < 4; ni++)                             \
    _Pragma("unroll") for (int mi2 = 0; mi2 < 2; mi2++)                          \
        acc[2 * (p) + mi2][ni] = __builtin_amdgcn_mfma_f32_16x16x32_bf16(        \
            af[mi2 * 2 + ks], bfr[ni][ks], acc[2 * (p) + mi2][ni], 0, 0, 0);     \
    __builtin_amdgcn_s_setprio(0);

    // prologue: A0 (2 halves), B0, B1  -> 8 gloads; need A0+B0 -> vmcnt(2)
    STG(&SA[0][0], Ag, m0, 0);
    STG(&SA[0][HALF256], Ag, m0 + 128, 0);
    STG(&SB[0][0], Bg, n0, 0);
    STG(&SB[1][0], Bg, n0, 64);
    WAITVM2();
    BARRIER();

    for (int iter = 0; iter < niter; iter++) {
        const int tt = 2 * iter;
        const int ka = (tt + 1) * 64, kb = (tt + 2) * 64, kc = (tt + 3) * 64;
        const bool s2 = (tt + 2 < T), s3 = (tt + 3 < T);
        const bool last = (iter == niter - 1);
        short8 af[4];

        // ph1: tile tt (buf0) p0; stage A(t+1) -> SA[1]
        DSRX(0, 0);
        STG(&SA[1][0], Ag, m0, ka);
        STG(&SA[1][HALF256], Ag, m0 + 128, ka);
        WAITLGKM8();
        BARRIER(); WAITLGKM0(); MFX(0); BARRIER();
        // ph2: tile tt p1; stage B(t+2) -> SB[0]
        DSRX(1, 0);
        if (s2) STG(&SB[0][0], Bg, n0, kb);
        BARRIER(); WAITLGKM0(); MFX(1);
        if (last) { WAITVM0(); } else { WAITVM2(); }   // drain B(t+1)+A(t+1)
        BARRIER();
        // ph3: tile tt+1 (buf1) p0; stage A(t+2) -> SA[0]
        DSRX(0, 1);
        if (s2) {
            STG(&SA[0][0], Ag, m0, kb);
            STG(&SA[0][HALF256], Ag, m0 + 128, kb);
        }
        WAITLGKM8();
        BARRIER(); WAITLGKM0(); MFX(0); BARRIER();
        // ph4: tile tt+1 p1; stage B(t+3) -> SB[1]
        DSRX(1, 1);
        if (s3) STG(&SB[1][0], Bg, n0, kc);
        BARRIER(); WAITLGKM0(); MFX(1);
        if (last) { WAITVM0(); } else { WAITVM2(); }   // drain B(t+2)+A(t+2)
        BARRIER();
    }

    // epilogue
#pragma unroll
    for (int mi = 0; mi < 4; mi++) {
#pragma unroll
        for (int ni = 0; ni < 4; ni++) {
            int gr = m0 + wm * 64 + mi * 16 + lg * 4;
            int gc = n0 + wn * 64 + ni * 16 + lrow;
#pragma unroll
            for (int r = 0; r < 4; r++) {
                size_t gi = (size_t)(gr + r) * N + gc;
                float v = acc[mi][ni][r];
                if constexpr (EPI == 0) {
                    ((bf16*)Cout)[gi] = __float2bfloat16(v);
                } else if constexpr (EPI == 3) {
                    float res = ((const float*)Res)[gi];
                    ((bf16*)Cout)[gi] = __float2bfloat16(res + v);
                } else {
                    float res = __bfloat162float(((const bf16*)Res)[gi]);
                    ((float*)Cout)[gi] = res + v;
                }
            }
        }
    }
}

// ---------------- MFMA flash attention (paired, exp2, defer-max, async stage, setprio) ----------------
__global__ __launch_bounds__(256) void flash_attn(const bf16* __restrict__ qk,
                                                  const bf16* __restrict__ vt,
                                                  bf16* __restrict__ y) {
    const int pi = blockIdx.x;
    const int bh = blockIdx.y;
    const int b = bh >> 4, h = bh & 15;
    const int t = threadIdx.x;
    const int wave = t >> 6, lane = t & 63;
    const int lrow = lane & 15, g = lane >> 4, lk = g * 8;

    __shared__ alignas(16) short Ks[64 * 72];
    __shared__ alignas(16) short Vs[64 * 72];
    __shared__ alignas(16) short Ps[128 * 72];

    const size_t rs = 2 * C_;
    const bf16* Qg = qk + (size_t)b * T_ * rs + h * 64;
    const bf16* Kg = Qg + C_;
    const bf16* Vg = vt + (size_t)(h * 64) * M_TOK + b * T_;

    const int srow = t >> 3;
    const int sc8 = (t & 7) * 8;
    const float scale2 = 0.125f * 1.44269504089f;

    for (int sel = 0; sel < 2; sel++) {
        const int qtb = sel ? pi : 15 - pi;
        const int q0 = qtb * 128;
        const int nkt = 2 * qtb + 2;

        short8 qf[2][2];
#pragma unroll
        for (int mi = 0; mi < 2; mi++) {
            const bf16* qr = Qg + (size_t)(q0 + wave * 32 + mi * 16 + lrow) * rs;
            qf[mi][0] = *(const short8*)(qr + lk);
            qf[mi][1] = *(const short8*)(qr + 32 + lk);
        }

        f32x4 o[2][4];
        float m[2][4], l[2][4];
#pragma unroll
        for (int mi = 0; mi < 2; mi++) {
#pragma unroll
            for (int ni = 0; ni < 4; ni++) o[mi][ni] = (f32x4){0.f, 0.f, 0.f, 0.f};
#pragma unroll
            for (int r = 0; r < 4; r++) { m[mi][r] = -1e30f; l[mi][r] = 0.f; }
        }

        short8 kr[2], vr[2];
#pragma unroll
        for (int p = 0; p < 2; p++) {
            int r = srow + p * 32;
            kr[p] = *(const short8*)(Kg + (size_t)r * rs + sc8);
            vr[p] = *(const short8*)(Vg + (size_t)r * M_TOK + sc8);
        }

        for (int kt = 0; kt < nkt; kt++) {
            const int s0 = kt * 64;
#pragma unroll
            for (int p = 0; p < 2; p++) {
                int r = srow + p * 32;
                *(short8*)(&Ks[r * 72 + sc8]) = kr[p];
                *(short8*)(&Vs[r * 72 + sc8]) = vr[p];
            }
            __syncthreads();
            if (kt + 1 < nkt) {
                const int s0n = (kt + 1) * 64;
#pragma unroll
                for (int p = 0; p < 2; p++) {
                    int r = srow + p * 32;
                    kr[p] = *(const short8*)(Kg + (size_t)(s0n + r) * rs + sc8);
                    vr[p] = *(const short8*)(Vg + (size_t)r * M_TOK + s0n + sc8);
                }
            }

            f32x4 s[2][4];
#pragma unroll
            for (int mi = 0; mi < 2; mi++)
#pragma unroll
                for (int ni = 0; ni < 4; ni++) s[mi][ni] = (f32x4){0.f, 0.f, 0.f, 0.f};
            __builtin_amdgcn_s_setprio(1);
#pragma unroll
            for (int ks = 0; ks < 2; ks++) {
#pragma unroll
                for (int ni = 0; ni < 4; ni++) {
                    short8 kf = *(const short8*)(&Ks[(ni * 16 + lrow) * 72 + ks * 32 + lk]);
#pragma unroll
                    for (int mi = 0; mi < 2; mi++)
                        s[mi][ni] = __builtin_amdgcn_mfma_f32_16x16x32_bf16(
                            qf[mi][ks], kf, s[mi][ni], 0, 0, 0);
                }
            }
            __builtin_amdgcn_s_setprio(0);

            if (kt >= nkt - 2) {
#pragma unroll
                for (int mi = 0; mi < 2; mi++)
#pragma unroll
                    for (int ni = 0; ni < 4; ni++)
#pragma unroll
                        for (int r = 0; r < 4; r++) {
                            int qg = q0 + wave * 32 + mi * 16 + g * 4 + r;
                            int kvg = s0 + ni * 16 + lrow;
                            s[mi][ni][r] = (kvg > qg) ? -1e30f : s[mi][ni][r] * scale2;
                        }
            } else {
#pragma unroll
                for (int mi = 0; mi < 2; mi++)
#pragma unroll
                    for (int ni = 0; ni < 4; ni++)
#pragma unroll
                        for (int r = 0; r < 4; r++) s[mi][ni][r] *= scale2;
            }

#pragma unroll
            for (int mi = 0; mi < 2; mi++) {
                float pm[4];
#pragma unroll
                for (int r = 0; r < 4; r++) {
                    float v = fmaxf(fmaxf(s[mi][0][r], s[mi][1][r]),
                                    fmaxf(s[mi][2][r], s[mi][3][r]));
                    pm[r] = red16_max(v);
                }
                int ok = (pm[0] <= m[mi][0] + 8.f) && (pm[1] <= m[mi][1] + 8.f) &&
                         (pm[2] <= m[mi][2] + 8.f) && (pm[3] <= m[mi][3] + 8.f);
                if (!__all(ok)) {
                    float alpha[4];
#pragma unroll
                    for (int r = 0; r < 4; r++) {
                        float mn = fmaxf(m[mi][r], pm[r]);
                        alpha[r] = fexp2(m[mi][r] - mn);
                        m[mi][r] = mn;
                        l[mi][r] *= alpha[r];
                    }
#pragma unroll
                    for (int ni = 0; ni < 4; ni++)
#pragma unroll
                        for (int r = 0; r < 4; r++) o[mi][ni][r] *= alpha[r];
                }
                float rowsum[4] = {0.f, 0.f, 0.f, 0.f};
#pragma unroll
                for (int ni = 0; ni < 4; ni++) {
#pragma unroll
                    for (int r = 0; r < 4; r++) {
                        float p = fexp2(s[mi][ni][r] - m[mi][r]);
                        rowsum[r] += p;
                        bf16 pb = __float2bfloat16(p);
                        Ps[(wave * 32 + mi * 16 + g * 4 + r) * 72 + ni * 16 + lrow] = *(short*)&pb;
                    }
                }
#pragma unroll
                for (int r = 0; r < 4; r++)
                    l[mi][r] += red16_sum(rowsum[r]);
            }

            __builtin_amdgcn_s_setprio(1);
#pragma unroll
            for (int ks2 = 0; ks2 < 2; ks2++) {
                short8 pf[2];
#pragma unroll
                for (int mi = 0; mi < 2; mi++)
                    pf[mi] = *(const short8*)(&Ps[(wave * 32 + mi * 16 + lrow) * 72 + ks2 * 32 + lk]);
#pragma unroll
                for (int ni = 0; ni < 4; ni++) {
                    short8 vf = *(const short8*)(&Vs[(ni * 16 + lrow) * 72 + ks2 * 32 + lk]);
#pragma unroll
                    for (int mi = 0; mi < 2; mi++)
                        o[mi][ni] = __builtin_amdgcn_mfma_f32_16x16x32_bf16(
                            pf[mi], vf, o[mi][ni], 0, 0, 0);
                }
            }
            __builtin_amdgcn_s_setprio(0);
            __syncthreads();
        }

#pragma unroll
        for (int mi = 0; mi < 2; mi++) {
            float inv[4];
#pragma unroll
            for (int r = 0; r < 4; r++) inv[r] = 1.f / l[mi][r];
#pragma unroll
            for (int ni = 0; ni < 4; ni++)
#pragma unroll
                for (int r = 0; r < 4; r++) {
                    int qrow = q0 + wave * 32 + mi * 16 + g * 4 + r;
                    y[((size_t)(b * T_ + qrow)) * C_ + h * 64 + ni * 16 + lrow] =
                        __float2bfloat16(o[mi][ni][r] * inv[r]);
                }
        }
    }
}

// ---------------- launch ----------------
extern "C" void kernel_launch(void* const* d_in, const int* in_sizes, int n_in,
                              void* d_out, int out_size, void* d_ws, size_t ws_size,
                              hipStream_t stream) {
    const float* x      = (const float*)d_in[0];
    const float* ln1w   = (const float*)d_in[1];
    const float* ln1b   = (const float*)d_in[2];
    const float* ln2w   = (const float*)d_in[3];
    const float* ln2b   = (const float*)d_in[4];
    const float* w_attn = (const float*)d_in[5];
    const float* w_proj = (const float*)d_in[6];
    const float* w_fc   = (const float*)d_in[7];
    const float* w_fcp  = (const float*)d_in[8];
    float* out = (float*)d_out;

    char* ws = (char*)d_ws;
    bf16* ln_buf  = (bf16*)(ws);                   // [0,16M)
    bf16* qk_buf  = (bf16*)(ws + (16u << 20));     // [16,48M)
    bf16* vt_buf  = (bf16*)(ws + (48u << 20));     // [48,64M)
    bf16* ybuf    = (bf16*)(ws + (64u << 20));     // [64,80M)
    bf16* ubuf    = (bf16*)(ws + (16u << 20));     // [16,80M) reuse after attn
    bf16* x2b     = (bf16*)(ws + (80u << 20));     // [80,96M) bf16 residual state
    bf16* wattn_h = (bf16*)(ws + (112u << 20));
    bf16* wproj_h = (bf16*)(ws + (118u << 20));
    bf16* wfc_h   = (bf16*)(ws + (120u << 20));
    bf16* wfcp_h  = (bf16*)(ws + (128u << 20));

    {
        int n1 = 3 * C_ * C_ / 4, n2 = C_ * C_ / 4, n3 = FF_ * C_ / 4, n4 = C_ * FF_ / 4;
        cvt_f32_bf16_v4<<<(n1 + 255) / 256, 256, 0, stream>>>(w_attn, wattn_h, n1);
        cvt_f32_bf16_v4<<<(n2 + 255) / 256, 256, 0, stream>>>(w_proj, wproj_h, n2);
        cvt_f32_bf16_v4<<<(n3 + 255) / 256, 256, 0, stream>>>(w_fc, wfc_h, n3);
        cvt_f32_bf16_v4<<<(n4 + 255) / 256, 256, 0, stream>>>(w_fcp, wfcp_h, n4);
    }

    // LN1 (f32 in)
    ln_kernel<float><<<M_TOK, 256, 0, stream>>>(x, ln1w, ln1b, ln_buf);

    // qk = ln_buf @ w_attn[0:2C]^T  (256^2 8-phase)
    gemm256<0><<<dim3((M_TOK / 256) * (2 * C_ / 256)), 512, 0, stream>>>(
        ln_buf, wattn_h, qk_buf, M_TOK, 2 * C_, C_);

    // vt = w_v @ ln_buf^T  [1024, 8192]  (256x128 8-phase, 256 wgs)
    gemm256x128<0><<<dim3((C_ / 256) * (M_TOK / 128)), 512, 0, stream>>>(
        wattn_h + (size_t)2 * C_ * C_, ln_buf, vt_buf, nullptr, C_, M_TOK, C_);

    // attention
    flash_attn<<<dim3(8, B_ * H_), 256, 0, stream>>>(qk_buf, vt_buf, ybuf);

    // x2b = bf16(x + ybuf @ w_proj^T)  (256x128 8-phase, 256 wgs)
    gemm256x128<3><<<dim3((M_TOK / 256) * (C_ / 128)), 512, 0, stream>>>(
        ybuf, wproj_h, x2b, x, M_TOK, C_, C_);

    // LN2 (bf16 in)
    ln_kernel<bf16><<<M_TOK, 256, 0, stream>>>(x2b, ln2w, ln2b, ln_buf);

    // u = gelu(ln_buf @ w_fc^T)  (256^2 8-phase)
    gemm256<2><<<dim3((M_TOK / 256) * (FF_ / 256)), 512, 0, stream>>>(
        ln_buf, wfc_h, ubuf, M_TOK, FF_, C_);

    // out = f32(x2b) + u @ w_fcp^T  (256x128 8-phase, 256 wgs)
    gemm256x128<4><<<dim3((M_TOK / 256) * (C_ / 128)), 512, 0, stream>>>(
        ubuf, wfcp_h, out, x2b, M_TOK, C_, FF_);
}

// Round 9
// 382.229 us; speedup vs baseline: 24.5181x; 1.0210x over previous
//
#include <hip/hip_runtime.h>
#include <hip/hip_bf16.h>

using bf16 = __hip_bfloat16;
typedef __attribute__((ext_vector_type(8))) short short8;
typedef __attribute__((ext_vector_type(4))) short sh4;
typedef __attribute__((ext_vector_type(4))) float f32x4;

#define B_ 4
#define T_ 2048
#define C_ 1024
#define H_ 16
#define FF_ 4096
#define M_TOK (B_ * T_)   // 8192
#define SCALE2 0.1803368801111f   // 0.125 * log2(e)

#define BARRIER() asm volatile("s_barrier" ::: "memory")
#define WAITLGKM0() asm volatile("s_waitcnt lgkmcnt(0)" ::: "memory")
#define WAITLGKM8() asm volatile("s_waitcnt lgkmcnt(8)" ::: "memory")
#define WAITVM4() asm volatile("s_waitcnt vmcnt(4)" ::: "memory")
#define WAITVM2() asm volatile("s_waitcnt vmcnt(2)" ::: "memory")
#define WAITVM0() asm volatile("s_waitcnt vmcnt(0)" ::: "memory")

// ---------------- async global->LDS 16B ----------------
__device__ __forceinline__ void gload16(const void* g, void* l) {
    __builtin_amdgcn_global_load_lds(
        (const __attribute__((address_space(1))) void*)g,
        (__attribute__((address_space(3))) void*)l, 16, 0, 0);
}

// 2^x in one instruction
__device__ __forceinline__ float fexp2(float x) {
    float r;
    asm("v_exp_f32 %0, %1" : "=v"(r) : "v"(x));
    return r;
}

__device__ __forceinline__ float bf16bits2f(short s) {
    return __uint_as_float(((unsigned)(unsigned short)s) << 16);
}

// ---------------- DPP 16-lane rotate reduce ----------------
template <int CTRL>
__device__ __forceinline__ float dpp_rotf(float x) {
    return __int_as_float(__builtin_amdgcn_update_dpp(
        0, __float_as_int(x), CTRL, 0xf, 0xf, true));
}
__device__ __forceinline__ float red16_max(float v) {
    v = fmaxf(v, dpp_rotf<0x128>(v));
    v = fmaxf(v, dpp_rotf<0x124>(v));
    v = fmaxf(v, dpp_rotf<0x122>(v));
    v = fmaxf(v, dpp_rotf<0x121>(v));
    return v;
}
__device__ __forceinline__ float red16_sum(float v) {
    v += dpp_rotf<0x128>(v);
    v += dpp_rotf<0x124>(v);
    v += dpp_rotf<0x122>(v);
    v += dpp_rotf<0x121>(v);
    return v;
}

// ---------------- f32 -> bf16 convert, 4/thread ----------------
__global__ void cvt_f32_bf16_v4(const float* __restrict__ in, bf16* __restrict__ out, int n4) {
    int i = blockIdx.x * blockDim.x + threadIdx.x;
    if (i < n4) {
        float4 v = ((const float4*)in)[i];
        sh4 o;
        bf16 b0 = __float2bfloat16(v.x), b1 = __float2bfloat16(v.y),
             b2 = __float2bfloat16(v.z), b3 = __float2bfloat16(v.w);
        o[0] = *(short*)&b0; o[1] = *(short*)&b1;
        o[2] = *(short*)&b2; o[3] = *(short*)&b3;
        ((sh4*)out)[i] = o;
    }
}

// ---------------- LayerNorm: TIN in -> bf16 out ----------------
template <typename TIN>
__global__ __launch_bounds__(256) void ln_kernel(const TIN* __restrict__ x,
                                                 const float* __restrict__ w,
                                                 const float* __restrict__ b,
                                                 bf16* __restrict__ out) {
    int row = blockIdx.x;
    int t = threadIdx.x;
    float4 v;
    if constexpr (sizeof(TIN) == 4) {
        v = ((const float4*)(x + (size_t)row * C_))[t];
    } else {
        sh4 h = ((const sh4*)(x + (size_t)row * C_))[t];
        v.x = bf16bits2f(h[0]);
        v.y = bf16bits2f(h[1]);
        v.z = bf16bits2f(h[2]);
        v.w = bf16bits2f(h[3]);
    }
    float s = v.x + v.y + v.z + v.w;
    float s2 = v.x * v.x + v.y * v.y + v.z * v.z + v.w * v.w;
#pragma unroll
    for (int off = 32; off > 0; off >>= 1) {
        s += __shfl_down(s, off);
        s2 += __shfl_down(s2, off);
    }
    __shared__ float ss[4], ss2[4];
    int wave = t >> 6, lane = t & 63;
    if (lane == 0) { ss[wave] = s; ss2[wave] = s2; }
    __syncthreads();
    s = ss[0] + ss[1] + ss[2] + ss[3];
    s2 = ss2[0] + ss2[1] + ss2[2] + ss2[3];
    float mu = s * (1.f / C_);
    float var = s2 * (1.f / C_) - mu * mu;
    float rstd = rsqrtf(var + 1e-5f);
    float4 wv = ((const float4*)w)[t];
    float4 bv = ((const float4*)b)[t];
    sh4 o;
    bf16 b0 = __float2bfloat16((v.x - mu) * rstd * wv.x + bv.x);
    bf16 b1 = __float2bfloat16((v.y - mu) * rstd * wv.y + bv.y);
    bf16 b2 = __float2bfloat16((v.z - mu) * rstd * wv.z + bv.z);
    bf16 b3 = __float2bfloat16((v.w - mu) * rstd * wv.w + bv.w);
    o[0] = *(short*)&b0; o[1] = *(short*)&b1;
    o[2] = *(short*)&b2; o[3] = *(short*)&b3;
    ((sh4*)(out + (size_t)row * C_))[t] = o;
}

// ======== shared staging macro ========
#define STG(ldsbase, g, grow0, k0)                                               \
    {                                                                            \
        _Pragma("unroll") for (int s_ = 0; s_ < 2; s_++) {                       \
            int row_ = s_ * 64 + wid * 8 + sr;                                   \
            gload16(g + (size_t)((grow0) + row_) * K + (k0) + ssc,               \
                    (ldsbase) + row_ * 64 + (lane & 7) * 8);                     \
        }                                                                        \
    }

// ---------------- 256x256 8-phase NT GEMM (T2+T3+T4+T5) ----------------
// EPI 0: bf16  EPI 2: bf16 gelu  EPI 5: bf16, cols<C_ scaled by SCALE2 (Q prescale)
#define HALF256 (128 * 64)
template <int EPI>
__global__ __launch_bounds__(512, 2) void gemm256(const bf16* __restrict__ Ag,
                                                  const bf16* __restrict__ Bg,
                                                  void* __restrict__ Cout,
                                                  int M, int N, int K) {
    __shared__ short SA[2][256 * 64];
    __shared__ short SB[2][256 * 64];

    const int nbx = N >> 8;
    const int nwg = nbx * (M >> 8);
    const int bid = blockIdx.x;
    const int cpx = nwg >> 3;
    const int swzb = (bid & 7) * cpx + (bid >> 3);
    const int m0 = (swzb / nbx) * 256;
    const int n0 = (swzb % nbx) * 256;

    const int t = threadIdx.x;
    const int wid = t >> 6, lane = t & 63;
    const int wm = wid >> 2, wn = wid & 3;
    const int lrow = lane & 15, lg = lane >> 4;
    const int swzr = (lane & 7) * 8;
    const int sr = lane >> 3;
    const int ssc = ((lane & 7) ^ sr) * 8;

    f32x4 acc[8][4];
#pragma unroll
    for (int mi = 0; mi < 8; mi++)
#pragma unroll
        for (int ni = 0; ni < 4; ni++) acc[mi][ni] = (f32x4){0.f, 0.f, 0.f, 0.f};
    short8 bfr[4][2];

    const int T = K >> 6;
    const int niter = T >> 1;

#define DSREADS256(q, buf)                                                       \
    if ((q) == 0) {                                                              \
        _Pragma("unroll") for (int ni = 0; ni < 4; ni++)                         \
        _Pragma("unroll") for (int ks = 0; ks < 2; ks++)                         \
            bfr[ni][ks] = *(const short8*)(&SB[buf][(wn * 64 + ni * 16 + lrow) * 64 + \
                                                    ((ks * 32 + lg * 8) ^ swzr)]);    \
    }                                                                            \
    _Pragma("unroll") for (int mi2 = 0; mi2 < 2; mi2++)                          \
    _Pragma("unroll") for (int ks = 0; ks < 2; ks++)                             \
        af[mi2 * 2 + ks] = *(const short8*)(&SA[buf][(wm * 128 + (2 * (q) + mi2) * 16 + lrow) * 64 + \
                                                     ((ks * 32 + lg * 8) ^ swzr)]);

#define MFMAS256(q)                                                              \
    __builtin_amdgcn_s_setprio(1);                                               \
    _Pragma("unroll") for (int ks = 0; ks < 2; ks++)                             \
    _Pragma("unroll") for (int ni = 0; ni < 4; ni++)                             \
    _Pragma("unroll") for (int mi2 = 0; mi2 < 2; mi2++)                          \
        acc[2 * (q) + mi2][ni] = __builtin_amdgcn_mfma_f32_16x16x32_bf16(        \
            af[mi2 * 2 + ks], bfr[ni][ks], acc[2 * (q) + mi2][ni], 0, 0, 0);     \
    __builtin_amdgcn_s_setprio(0);

    STG(&SA[0][0], Ag, m0, 0);
    STG(&SA[0][HALF256], Ag, m0 + 128, 0);
    STG(&SB[0][0], Bg, n0, 0);
    STG(&SB[0][HALF256], Bg, n0 + 128, 0);
    STG(&SB[1][0], Bg, n0, 64);
    STG(&SB[1][HALF256], Bg, n0 + 128, 64);
    WAITVM4();
    BARRIER();

    for (int iter = 0; iter < niter; iter++) {
        const int tt = 2 * iter;
        const int ka = (tt + 1) * 64, kb = (tt + 2) * 64, kc = (tt + 3) * 64;
        const bool s2 = (tt + 2 < T), s3 = (tt + 3 < T);
        const bool last = (iter == niter - 1);
        short8 af[4];

        DSREADS256(0, 0);
        STG(&SA[1][0], Ag, m0, ka);
        WAITLGKM8();
        BARRIER(); WAITLGKM0(); MFMAS256(0); BARRIER();
        DSREADS256(1, 0);
        STG(&SA[1][HALF256], Ag, m0 + 128, ka);
        BARRIER(); WAITLGKM0(); MFMAS256(1); BARRIER();
        DSREADS256(2, 0);
        if (s2) STG(&SB[0][0], Bg, n0, kb);
        BARRIER(); WAITLGKM0(); MFMAS256(2); BARRIER();
        DSREADS256(3, 0);
        if (s2) STG(&SB[0][HALF256], Bg, n0 + 128, kb);
        BARRIER(); WAITLGKM0(); MFMAS256(3);
        if (last) { WAITVM0(); } else { WAITVM4(); }
        BARRIER();
        DSREADS256(0, 1);
        if (s2) STG(&SA[0][0], Ag, m0, kb);
        WAITLGKM8();
        BARRIER(); WAITLGKM0(); MFMAS256(0); BARRIER();
        DSREADS256(1, 1);
        if (s2) STG(&SA[0][HALF256], Ag, m0 + 128, kb);
        BARRIER(); WAITLGKM0(); MFMAS256(1); BARRIER();
        DSREADS256(2, 1);
        if (s3) STG(&SB[1][0], Bg, n0, kc);
        BARRIER(); WAITLGKM0(); MFMAS256(2); BARRIER();
        DSREADS256(3, 1);
        if (s3) STG(&SB[1][HALF256], Bg, n0 + 128, kc);
        BARRIER(); WAITLGKM0(); MFMAS256(3);
        if (!last) WAITVM4();
        BARRIER();
    }

#pragma unroll
    for (int mi = 0; mi < 8; mi++) {
#pragma unroll
        for (int ni = 0; ni < 4; ni++) {
            int gr = m0 + wm * 128 + mi * 16 + lg * 4;
            int gc = n0 + wn * 64 + ni * 16 + lrow;
#pragma unroll
            for (int r = 0; r < 4; r++) {
                size_t gi = (size_t)(gr + r) * N + gc;
                float v = acc[mi][ni][r];
                if constexpr (EPI == 0) {
                    ((bf16*)Cout)[gi] = __float2bfloat16(v);
                } else if constexpr (EPI == 5) {
                    float vv = (gc < C_) ? v * SCALE2 : v;
                    ((bf16*)Cout)[gi] = __float2bfloat16(vv);
                } else {
                    float ge = 0.5f * v * (1.f + erff(v * 0.70710678f));
                    ((bf16*)Cout)[gi] = __float2bfloat16(ge);
                }
            }
        }
    }
}

// ---------------- 256x128 8-phase NT GEMM (N=1024-class shapes) ----------------
template <int EPI>
__global__ __launch_bounds__(512, 2) void gemm256x128(const bf16* __restrict__ Ag,
                                                      const bf16* __restrict__ Bg,
                                                      void* __restrict__ Cout,
                                                      const void* __restrict__ Res,
                                                      int M, int N, int K) {
    __shared__ short SA[2][256 * 64];
    __shared__ short SB[2][128 * 64];

    const int nbx = N >> 7;
    const int nwg = nbx * (M >> 8);
    const int bid = blockIdx.x;
    const int cpx = nwg >> 3;
    const int swzb = (bid & 7) * cpx + (bid >> 3);
    const int m0 = (swzb / nbx) * 256;
    const int n0 = (swzb % nbx) * 128;

    const int t = threadIdx.x;
    const int wid = t >> 6, lane = t & 63;
    const int wm = wid >> 1, wn = wid & 1;
    const int lrow = lane & 15, lg = lane >> 4;
    const int swzr = (lane & 7) * 8;
    const int sr = lane >> 3;
    const int ssc = ((lane & 7) ^ sr) * 8;

    f32x4 acc[4][4];
#pragma unroll
    for (int mi = 0; mi < 4; mi++)
#pragma unroll
        for (int ni = 0; ni < 4; ni++) acc[mi][ni] = (f32x4){0.f, 0.f, 0.f, 0.f};
    short8 bfr[4][2];

    const int T = K >> 6;
    const int niter = T >> 1;

#define DSRX(p, buf)                                                             \
    if ((p) == 0) {                                                              \
        _Pragma("unroll") for (int ni = 0; ni < 4; ni++)                         \
        _Pragma("unroll") for (int ks = 0; ks < 2; ks++)                         \
            bfr[ni][ks] = *(const short8*)(&SB[buf][(wn * 64 + ni * 16 + lrow) * 64 + \
                                                    ((ks * 32 + lg * 8) ^ swzr)]);    \
    }                                                                            \
    _Pragma("unroll") for (int mi2 = 0; mi2 < 2; mi2++)                          \
    _Pragma("unroll") for (int ks = 0; ks < 2; ks++)                             \
        af[mi2 * 2 + ks] = *(const short8*)(&SA[buf][(wm * 64 + (2 * (p) + mi2) * 16 + lrow) * 64 + \
                                                     ((ks * 32 + lg * 8) ^ swzr)]);

#define MFX(p)                                                                   \
    __builtin_amdgcn_s_setprio(1);                                               \
    _Pragma("unroll") for (int ks = 0; ks < 2; ks++)                             \
    _Pragma("unroll") for (int ni = 0; ni < 4; ni++)                             \
    _Pragma("unroll") for (int mi2 = 0; mi2 < 2; mi2++)                          \
        acc[2 * (p) + mi2][ni] = __builtin_amdgcn_mfma_f32_16x16x32_bf16(        \
            af[mi2 * 2 + ks], bfr[ni][ks], acc[2 * (p) + mi2][ni], 0, 0, 0);     \
    __builtin_amdgcn_s_setprio(0);

    STG(&SA[0][0], Ag, m0, 0);
    STG(&SA[0][HALF256], Ag, m0 + 128, 0);
    STG(&SB[0][0], Bg, n0, 0);
    STG(&SB[1][0], Bg, n0, 64);
    WAITVM2();
    BARRIER();

    for (int iter = 0; iter < niter; iter++) {
        const int tt = 2 * iter;
        const int ka = (tt + 1) * 64, kb = (tt + 2) * 64, kc = (tt + 3) * 64;
        const bool s2 = (tt + 2 < T), s3 = (tt + 3 < T);
        const bool last = (iter == niter - 1);
        short8 af[4];

        DSRX(0, 0);
        STG(&SA[1][0], Ag, m0, ka);
        STG(&SA[1][HALF256], Ag, m0 + 128, ka);
        WAITLGKM8();
        BARRIER(); WAITLGKM0(); MFX(0); BARRIER();
        DSRX(1, 0);
        if (s2) STG(&SB[0][0], Bg, n0, kb);
        BARRIER(); WAITLGKM0(); MFX(1);
        if (last) { WAITVM0(); } else { WAITVM2(); }
        BARRIER();
        DSRX(0, 1);
        if (s2) {
            STG(&SA[0][0], Ag, m0, kb);
            STG(&SA[0][HALF256], Ag, m0 + 128, kb);
        }
        WAITLGKM8();
        BARRIER(); WAITLGKM0(); MFX(0); BARRIER();
        DSRX(1, 1);
        if (s3) STG(&SB[1][0], Bg, n0, kc);
        BARRIER(); WAITLGKM0(); MFX(1);
        if (last) { WAITVM0(); } else { WAITVM2(); }
        BARRIER();
    }

#pragma unroll
    for (int mi = 0; mi < 4; mi++) {
#pragma unroll
        for (int ni = 0; ni < 4; ni++) {
            int gr = m0 + wm * 64 + mi * 16 + lg * 4;
            int gc = n0 + wn * 64 + ni * 16 + lrow;
#pragma unroll
            for (int r = 0; r < 4; r++) {
                size_t gi = (size_t)(gr + r) * N + gc;
                float v = acc[mi][ni][r];
                if constexpr (EPI == 0) {
                    ((bf16*)Cout)[gi] = __float2bfloat16(v);
                } else if constexpr (EPI == 3) {
                    float res = ((const float*)Res)[gi];
                    ((bf16*)Cout)[gi] = __float2bfloat16(res + v);
                } else {
                    float res = __bfloat162float(((const bf16*)Res)[gi]);
                    ((float*)Cout)[gi] = res + v;
                }
            }
        }
    }
}

// ---------------- MFMA flash attention: 64-row q-tiles, 16 rows/wave ----------------
// grid (16, B*H): block handles q-tiles {31-pi, pi}; Q pre-scaled by SCALE2 (exp2 domain).
__global__ __launch_bounds__(256, 4) void flash_attn(const bf16* __restrict__ qk,
                                                     const bf16* __restrict__ vt,
                                                     bf16* __restrict__ y) {
    const int pi = blockIdx.x;
    const int bh = blockIdx.y;
    const int b = bh >> 4, h = bh & 15;
    const int t = threadIdx.x;
    const int wave = t >> 6, lane = t & 63;
    const int lrow = lane & 15, g = lane >> 4, lk = g * 8;

    __shared__ alignas(16) short Ks[64 * 72];
    __shared__ alignas(16) short Vs[64 * 72];
    __shared__ alignas(16) short Ps[64 * 72];

    const size_t rs = 2 * C_;
    const bf16* Qg = qk + (size_t)b * T_ * rs + h * 64;
    const bf16* Kg = Qg + C_;
    const bf16* Vg = vt + (size_t)(h * 64) * M_TOK + b * T_;

    const int srow = t >> 3;
    const int sc8 = (t & 7) * 8;

    for (int sel = 0; sel < 2; sel++) {
        const int qtb = sel ? pi : 31 - pi;   // heavy first
        const int q0 = qtb * 64;
        const int nkt = qtb + 1;

        short8 qf[2];
        {
            const bf16* qr = Qg + (size_t)(q0 + wave * 16 + lrow) * rs;
            qf[0] = *(const short8*)(qr + lk);
            qf[1] = *(const short8*)(qr + 32 + lk);
        }

        f32x4 o[4];
        float m[4], l[4];
#pragma unroll
        for (int ni = 0; ni < 4; ni++) o[ni] = (f32x4){0.f, 0.f, 0.f, 0.f};
#pragma unroll
        for (int r = 0; r < 4; r++) { m[r] = -1e30f; l[r] = 0.f; }

        short8 kr[2], vr[2];
#pragma unroll
        for (int p = 0; p < 2; p++) {
            int r = srow + p * 32;
            kr[p] = *(const short8*)(Kg + (size_t)r * rs + sc8);
            vr[p] = *(const short8*)(Vg + (size_t)r * M_TOK + sc8);
        }

        for (int kt = 0; kt < nkt; kt++) {
            const int s0 = kt * 64;
#pragma unroll
            for (int p = 0; p < 2; p++) {
                int r = srow + p * 32;
                *(short8*)(&Ks[r * 72 + sc8]) = kr[p];
                *(short8*)(&Vs[r * 72 + sc8]) = vr[p];
            }
            __syncthreads();
            if (kt + 1 < nkt) {
                const int s0n = (kt + 1) * 64;
#pragma unroll
                for (int p = 0; p < 2; p++) {
                    int r = srow + p * 32;
                    kr[p] = *(const short8*)(Kg + (size_t)(s0n + r) * rs + sc8);
                    vr[p] = *(const short8*)(Vg + (size_t)r * M_TOK + s0n + sc8);
                }
            }

            // ---- S = Q K^T (16x64 per wave), Q pre-scaled ----
            f32x4 s[4];
#pragma unroll
            for (int ni = 0; ni < 4; ni++) s[ni] = (f32x4){0.f, 0.f, 0.f, 0.f};
            __builtin_amdgcn_s_setprio(1);
#pragma unroll
            for (int ks = 0; ks < 2; ks++) {
#pragma unroll
                for (int ni = 0; ni < 4; ni++) {
                    short8 kf = *(const short8*)(&Ks[(ni * 16 + lrow) * 72 + ks * 32 + lk]);
                    s[ni] = __builtin_amdgcn_mfma_f32_16x16x32_bf16(qf[ks], kf, s[ni], 0, 0, 0);
                }
            }
            __builtin_amdgcn_s_setprio(0);

            // causal mask on diagonal tile only
            if (kt == nkt - 1) {
#pragma unroll
                for (int ni = 0; ni < 4; ni++)
#pragma unroll
                    for (int r = 0; r < 4; r++) {
                        int qg = q0 + wave * 16 + g * 4 + r;
                        int kvg = s0 + ni * 16 + lrow;
                        if (kvg > qg) s[ni][r] = -1e30f;
                    }
            }

            // ---- online softmax (exp2 domain) ----
            float pm[4];
#pragma unroll
            for (int r = 0; r < 4; r++) {
                float v = fmaxf(fmaxf(s[0][r], s[1][r]), fmaxf(s[2][r], s[3][r]));
                pm[r] = red16_max(v);
            }
            float dmax = fmaxf(fmaxf(pm[0] - m[0], pm[1] - m[1]),
                               fmaxf(pm[2] - m[2], pm[3] - m[3]));
            if (!__all(dmax <= 8.f)) {
                float alpha[4];
#pragma unroll
                for (int r = 0; r < 4; r++) {
                    float mn = fmaxf(m[r], pm[r]);
                    alpha[r] = fexp2(m[r] - mn);
                    m[r] = mn;
                    l[r] *= alpha[r];
                }
#pragma unroll
                for (int ni = 0; ni < 4; ni++)
#pragma unroll
                    for (int r = 0; r < 4; r++) o[ni][r] *= alpha[r];
            }
            float rowsum[4] = {0.f, 0.f, 0.f, 0.f};
#pragma unroll
            for (int ni = 0; ni < 4; ni++) {
#pragma unroll
                for (int r = 0; r < 4; r++) {
                    float p = fexp2(s[ni][r] - m[r]);
                    rowsum[r] += p;
                    bf16 pb = __float2bfloat16(p);
                    Ps[(wave * 16 + g * 4 + r) * 72 + ni * 16 + lrow] = *(short*)&pb;
                }
            }
#pragma unroll
            for (int r = 0; r < 4; r++)
                l[r] += red16_sum(rowsum[r]);

            // ---- PV (wave-private P strip) ----
            __builtin_amdgcn_s_setprio(1);
#pragma unroll
            for (int ks2 = 0; ks2 < 2; ks2++) {
                short8 pf = *(const short8*)(&Ps[(wave * 16 + lrow) * 72 + ks2 * 32 + lk]);
#pragma unroll
                for (int ni = 0; ni < 4; ni++) {
                    short8 vf = *(const short8*)(&Vs[(ni * 16 + lrow) * 72 + ks2 * 32 + lk]);
                    o[ni] = __builtin_amdgcn_mfma_f32_16x16x32_bf16(pf, vf, o[ni], 0, 0, 0);
                }
            }
            __builtin_amdgcn_s_setprio(0);
            __syncthreads();
        }

        float inv[4];
#pragma unroll
        for (int r = 0; r < 4; r++) inv[r] = 1.f / l[r];
#pragma unroll
        for (int ni = 0; ni < 4; ni++)
#pragma unroll
            for (int r = 0; r < 4; r++) {
                int qrow = q0 + wave * 16 + g * 4 + r;
                y[((size_t)(b * T_ + qrow)) * C_ + h * 64 + ni * 16 + lrow] =
                    __float2bfloat16(o[ni][r] * inv[r]);
            }
    }
}

// ---------------- launch ----------------
extern "C" void kernel_launch(void* const* d_in, const int* in_sizes, int n_in,
                              void* d_out, int out_size, void* d_ws, size_t ws_size,
                              hipStream_t stream) {
    const float* x      = (const float*)d_in[0];
    const float* ln1w   = (const float*)d_in[1];
    const float* ln1b   = (const float*)d_in[2];
    const float* ln2w   = (const float*)d_in[3];
    const float* ln2b   = (const float*)d_in[4];
    const float* w_attn = (const float*)d_in[5];
    const float* w_proj = (const float*)d_in[6];
    const float* w_fc   = (const float*)d_in[7];
    const float* w_fcp  = (const float*)d_in[8];
    float* out = (float*)d_out;

    char* ws = (char*)d_ws;
    bf16* ln_buf  = (bf16*)(ws);                   // [0,16M)
    bf16* qk_buf  = (bf16*)(ws + (16u << 20));     // [16,48M)
    bf16* vt_buf  = (bf16*)(ws + (48u << 20));     // [48,64M)
    bf16* ybuf    = (bf16*)(ws + (64u << 20));     // [64,80M)
    bf16* ubuf    = (bf16*)(ws + (16u << 20));     // [16,80M) reuse after attn
    bf16* x2b     = (bf16*)(ws + (80u << 20));     // [80,96M)
    bf16* wattn_h = (bf16*)(ws + (112u << 20));
    bf16* wproj_h = (bf16*)(ws + (118u << 20));
    bf16* wfc_h   = (bf16*)(ws + (120u << 20));
    bf16* wfcp_h  = (bf16*)(ws + (128u << 20));

    {
        int n1 = 3 * C_ * C_ / 4, n2 = C_ * C_ / 4, n3 = FF_ * C_ / 4, n4 = C_ * FF_ / 4;
        cvt_f32_bf16_v4<<<(n1 + 255) / 256, 256, 0, stream>>>(w_attn, wattn_h, n1);
        cvt_f32_bf16_v4<<<(n2 + 255) / 256, 256, 0, stream>>>(w_proj, wproj_h, n2);
        cvt_f32_bf16_v4<<<(n3 + 255) / 256, 256, 0, stream>>>(w_fc, wfc_h, n3);
        cvt_f32_bf16_v4<<<(n4 + 255) / 256, 256, 0, stream>>>(w_fcp, wfcp_h, n4);
    }

    // LN1 (f32 in)
    ln_kernel<float><<<M_TOK, 256, 0, stream>>>(x, ln1w, ln1b, ln_buf);

    // qk = ln_buf @ w_attn[0:2C]^T  (256^2 8-phase; Q columns pre-scaled)
    gemm256<5><<<dim3((M_TOK / 256) * (2 * C_ / 256)), 512, 0, stream>>>(
        ln_buf, wattn_h, qk_buf, M_TOK, 2 * C_, C_);

    // vt = w_v @ ln_buf^T  [1024, 8192]  (256x128 8-phase)
    gemm256x128<0><<<dim3((C_ / 256) * (M_TOK / 128)), 512, 0, stream>>>(
        wattn_h + (size_t)2 * C_ * C_, ln_buf, vt_buf, nullptr, C_, M_TOK, C_);

    // attention (64-row tiles, 1024 blocks)
    flash_attn<<<dim3(16, B_ * H_), 256, 0, stream>>>(qk_buf, vt_buf, ybuf);

    // x2b = bf16(x + ybuf @ w_proj^T)  (256x128 8-phase)
    gemm256x128<3><<<dim3((M_TOK / 256) * (C_ / 128)), 512, 0, stream>>>(
        ybuf, wproj_h, x2b, x, M_TOK, C_, C_);

    // LN2 (bf16 in)
    ln_kernel<bf16><<<M_TOK, 256, 0, stream>>>(x2b, ln2w, ln2b, ln_buf);

    // u = gelu(ln_buf @ w_fc^T)  (256^2 8-phase)
    gemm256<2><<<dim3((M_TOK / 256) * (FF_ / 256)), 512, 0, stream>>>(
        ln_buf, wfc_h, ubuf, M_TOK, FF_, C_);

    // out = f32(x2b) + u @ w_fcp^T  (256x128 8-phase)
    gemm256x128<4><<<dim3((M_TOK / 256) * (C_ / 128)), 512, 0, stream>>>(
        ubuf, wfcp_h, out, x2b, M_TOK, C_, FF_);
}

// Round 10
// 382.116 us; speedup vs baseline: 24.5253x; 1.0003x over previous
//
#include <hip/hip_runtime.h>
#include <hip/hip_bf16.h>

using bf16 = __hip_bfloat16;
typedef __attribute__((ext_vector_type(8))) short short8;
typedef __attribute__((ext_vector_type(4))) short sh4;
typedef __attribute__((ext_vector_type(4))) float f32x4;

#define B_ 4
#define T_ 2048
#define C_ 1024
#define H_ 16
#define FF_ 4096
#define M_TOK (B_ * T_)   // 8192
#define SCALE2 0.1803368801111f   // 0.125 * log2(e)

#define BARRIER() asm volatile("s_barrier" ::: "memory")
#define WAITLGKM0() asm volatile("s_waitcnt lgkmcnt(0)" ::: "memory")
#define WAITLGKM8() asm volatile("s_waitcnt lgkmcnt(8)" ::: "memory")
#define WAITVM4() asm volatile("s_waitcnt vmcnt(4)" ::: "memory")
#define WAITVM2() asm volatile("s_waitcnt vmcnt(2)" ::: "memory")
#define WAITVM0() asm volatile("s_waitcnt vmcnt(0)" ::: "memory")

// ---------------- async global->LDS 16B ----------------
__device__ __forceinline__ void gload16(const void* g, void* l) {
    __builtin_amdgcn_global_load_lds(
        (const __attribute__((address_space(1))) void*)g,
        (__attribute__((address_space(3))) void*)l, 16, 0, 0);
}

// 2^x in one instruction
__device__ __forceinline__ float fexp2(float x) {
    float r;
    asm("v_exp_f32 %0, %1" : "=v"(r) : "v"(x));
    return r;
}

__device__ __forceinline__ float bf16bits2f(short s) {
    return __uint_as_float(((unsigned)(unsigned short)s) << 16);
}

// pack two f32 -> one dword of 2 bf16
__device__ __forceinline__ unsigned bf2(float a, float b) {
    bf16 x = __float2bfloat16(a), y = __float2bfloat16(b);
    unsigned short ux = *(unsigned short*)&x, uy = *(unsigned short*)&y;
    return (unsigned)ux | ((unsigned)uy << 16);
}

// ---------------- f32 -> bf16 convert, 4/thread ----------------
__global__ void cvt_f32_bf16_v4(const float* __restrict__ in, bf16* __restrict__ out, int n4) {
    int i = blockIdx.x * blockDim.x + threadIdx.x;
    if (i < n4) {
        float4 v = ((const float4*)in)[i];
        uint2 o;
        o.x = bf2(v.x, v.y);
        o.y = bf2(v.z, v.w);
        ((uint2*)out)[i] = o;
    }
}

// ---------------- LayerNorm: TIN in -> bf16 out ----------------
template <typename TIN>
__global__ __launch_bounds__(256) void ln_kernel(const TIN* __restrict__ x,
                                                 const float* __restrict__ w,
                                                 const float* __restrict__ b,
                                                 bf16* __restrict__ out) {
    int row = blockIdx.x;
    int t = threadIdx.x;
    float4 v;
    if constexpr (sizeof(TIN) == 4) {
        v = ((const float4*)(x + (size_t)row * C_))[t];
    } else {
        sh4 h = ((const sh4*)(x + (size_t)row * C_))[t];
        v.x = bf16bits2f(h[0]);
        v.y = bf16bits2f(h[1]);
        v.z = bf16bits2f(h[2]);
        v.w = bf16bits2f(h[3]);
    }
    float s = v.x + v.y + v.z + v.w;
    float s2 = v.x * v.x + v.y * v.y + v.z * v.z + v.w * v.w;
#pragma unroll
    for (int off = 32; off > 0; off >>= 1) {
        s += __shfl_down(s, off);
        s2 += __shfl_down(s2, off);
    }
    __shared__ float ss[4], ss2[4];
    int wave = t >> 6, lane = t & 63;
    if (lane == 0) { ss[wave] = s; ss2[wave] = s2; }
    __syncthreads();
    s = ss[0] + ss[1] + ss[2] + ss[3];
    s2 = ss2[0] + ss2[1] + ss2[2] + ss2[3];
    float mu = s * (1.f / C_);
    float var = s2 * (1.f / C_) - mu * mu;
    float rstd = rsqrtf(var + 1e-5f);
    float4 wv = ((const float4*)w)[t];
    float4 bv = ((const float4*)b)[t];
    uint2 o;
    o.x = bf2((v.x - mu) * rstd * wv.x + bv.x, (v.y - mu) * rstd * wv.y + bv.y);
    o.y = bf2((v.z - mu) * rstd * wv.z + bv.z, (v.w - mu) * rstd * wv.w + bv.w);
    ((uint2*)(out + (size_t)row * C_))[t] = o;
}

// ======== shared staging macro ========
#define STG(ldsbase, g, grow0, k0)                                               \
    {                                                                            \
        _Pragma("unroll") for (int s_ = 0; s_ < 2; s_++) {                       \
            int row_ = s_ * 64 + wid * 8 + sr;                                   \
            gload16(g + (size_t)((grow0) + row_) * K + (k0) + ssc,               \
                    (ldsbase) + row_ * 64 + (lane & 7) * 8);                     \
        }                                                                        \
    }

// ---------------- 256x256 8-phase NT GEMM (T2+T3+T4+T5) ----------------
// Operand-swapped MFMA: D reg-dim = N (4 consecutive cols/lane) -> packed stores.
// EPI 0: bf16  EPI 2: bf16 gelu  EPI 5: bf16, cols<C_ scaled by SCALE2
#define HALF256 (128 * 64)
template <int EPI>
__global__ __launch_bounds__(512, 2) void gemm256(const bf16* __restrict__ Ag,
                                                  const bf16* __restrict__ Bg,
                                                  void* __restrict__ Cout,
                                                  int M, int N, int K) {
    __shared__ short SA[2][256 * 64];
    __shared__ short SB[2][256 * 64];

    const int nbx = N >> 8;
    const int nwg = nbx * (M >> 8);
    const int bid = blockIdx.x;
    const int cpx = nwg >> 3;
    const int swzb = (bid & 7) * cpx + (bid >> 3);
    const int m0 = (swzb / nbx) * 256;
    const int n0 = (swzb % nbx) * 256;

    const int t = threadIdx.x;
    const int wid = t >> 6, lane = t & 63;
    const int wm = wid >> 2, wn = wid & 3;
    const int lrow = lane & 15, lg = lane >> 4;
    const int swzr = (lane & 7) * 8;
    const int sr = lane >> 3;
    const int ssc = ((lane & 7) ^ sr) * 8;

    f32x4 acc[8][4];
#pragma unroll
    for (int mi = 0; mi < 8; mi++)
#pragma unroll
        for (int ni = 0; ni < 4; ni++) acc[mi][ni] = (f32x4){0.f, 0.f, 0.f, 0.f};
    short8 bfr[4][2];

    const int T = K >> 6;
    const int niter = T >> 1;

#define DSREADS256(q, buf)                                                       \
    if ((q) == 0) {                                                              \
        _Pragma("unroll") for (int ni = 0; ni < 4; ni++)                         \
        _Pragma("unroll") for (int ks = 0; ks < 2; ks++)                         \
            bfr[ni][ks] = *(const short8*)(&SB[buf][(wn * 64 + ni * 16 + lrow) * 64 + \
                                                    ((ks * 32 + lg * 8) ^ swzr)]);    \
    }                                                                            \
    _Pragma("unroll") for (int mi2 = 0; mi2 < 2; mi2++)                          \
    _Pragma("unroll") for (int ks = 0; ks < 2; ks++)                             \
        af[mi2 * 2 + ks] = *(const short8*)(&SA[buf][(wm * 128 + (2 * (q) + mi2) * 16 + lrow) * 64 + \
                                                     ((ks * 32 + lg * 8) ^ swzr)]);

#define MFMAS256(q)                                                              \
    __builtin_amdgcn_s_setprio(1);                                               \
    _Pragma("unroll") for (int ks = 0; ks < 2; ks++)                             \
    _Pragma("unroll") for (int ni = 0; ni < 4; ni++)                             \
    _Pragma("unroll") for (int mi2 = 0; mi2 < 2; mi2++)                          \
        acc[2 * (q) + mi2][ni] = __builtin_amdgcn_mfma_f32_16x16x32_bf16(        \
            bfr[ni][ks], af[mi2 * 2 + ks], acc[2 * (q) + mi2][ni], 0, 0, 0);     \
    __builtin_amdgcn_s_setprio(0);

    STG(&SA[0][0], Ag, m0, 0);
    STG(&SA[0][HALF256], Ag, m0 + 128, 0);
    STG(&SB[0][0], Bg, n0, 0);
    STG(&SB[0][HALF256], Bg, n0 + 128, 0);
    STG(&SB[1][0], Bg, n0, 64);
    STG(&SB[1][HALF256], Bg, n0 + 128, 64);
    WAITVM4();
    BARRIER();

    for (int iter = 0; iter < niter; iter++) {
        const int tt = 2 * iter;
        const int ka = (tt + 1) * 64, kb = (tt + 2) * 64, kc = (tt + 3) * 64;
        const bool s2 = (tt + 2 < T), s3 = (tt + 3 < T);
        const bool last = (iter == niter - 1);
        short8 af[4];

        DSREADS256(0, 0);
        STG(&SA[1][0], Ag, m0, ka);
        WAITLGKM8();
        BARRIER(); WAITLGKM0(); MFMAS256(0); BARRIER();
        DSREADS256(1, 0);
        STG(&SA[1][HALF256], Ag, m0 + 128, ka);
        BARRIER(); WAITLGKM0(); MFMAS256(1); BARRIER();
        DSREADS256(2, 0);
        if (s2) STG(&SB[0][0], Bg, n0, kb);
        BARRIER(); WAITLGKM0(); MFMAS256(2); BARRIER();
        DSREADS256(3, 0);
        if (s2) STG(&SB[0][HALF256], Bg, n0 + 128, kb);
        BARRIER(); WAITLGKM0(); MFMAS256(3);
        if (last) { WAITVM0(); } else { WAITVM4(); }
        BARRIER();
        DSREADS256(0, 1);
        if (s2) STG(&SA[0][0], Ag, m0, kb);
        WAITLGKM8();
        BARRIER(); WAITLGKM0(); MFMAS256(0); BARRIER();
        DSREADS256(1, 1);
        if (s2) STG(&SA[0][HALF256], Ag, m0 + 128, kb);
        BARRIER(); WAITLGKM0(); MFMAS256(1); BARRIER();
        DSREADS256(2, 1);
        if (s3) STG(&SB[1][0], Bg, n0, kc);
        BARRIER(); WAITLGKM0(); MFMAS256(2); BARRIER();
        DSREADS256(3, 1);
        if (s3) STG(&SB[1][HALF256], Bg, n0 + 128, kc);
        BARRIER(); WAITLGKM0(); MFMAS256(3);
        if (!last) WAITVM4();
        BARRIER();
    }

    // epilogue: lane holds 4 consecutive N-cols per fragment
#pragma unroll
    for (int mi = 0; mi < 8; mi++) {
        const int gm = m0 + wm * 128 + mi * 16 + lrow;
#pragma unroll
        for (int ni = 0; ni < 4; ni++) {
            const int gn = n0 + wn * 64 + ni * 16 + lg * 4;
            size_t gi = (size_t)gm * N + gn;
            f32x4 a = acc[mi][ni];
            if constexpr (EPI == 0) {
                uint2 o; o.x = bf2(a[0], a[1]); o.y = bf2(a[2], a[3]);
                *(uint2*)&(((bf16*)Cout)[gi]) = o;
            } else if constexpr (EPI == 5) {
                float sc = (gn < C_) ? SCALE2 : 1.f;
                uint2 o; o.x = bf2(a[0] * sc, a[1] * sc); o.y = bf2(a[2] * sc, a[3] * sc);
                *(uint2*)&(((bf16*)Cout)[gi]) = o;
            } else {
                float g0 = 0.5f * a[0] * (1.f + erff(a[0] * 0.70710678f));
                float g1 = 0.5f * a[1] * (1.f + erff(a[1] * 0.70710678f));
                float g2 = 0.5f * a[2] * (1.f + erff(a[2] * 0.70710678f));
                float g3 = 0.5f * a[3] * (1.f + erff(a[3] * 0.70710678f));
                uint2 o; o.x = bf2(g0, g1); o.y = bf2(g2, g3);
                *(uint2*)&(((bf16*)Cout)[gi]) = o;
            }
        }
    }
}

// ---------------- 256x128 8-phase NT GEMM (N=1024-class shapes) ----------------
// EPI 0: bf16  EPI 3: bf16 = f32 Res + acc  EPI 4: f32 = bf16 Res + acc
template <int EPI>
__global__ __launch_bounds__(512, 2) void gemm256x128(const bf16* __restrict__ Ag,
                                                      const bf16* __restrict__ Bg,
                                                      void* __restrict__ Cout,
                                                      const void* __restrict__ Res,
                                                      int M, int N, int K) {
    __shared__ short SA[2][256 * 64];
    __shared__ short SB[2][128 * 64];

    const int nbx = N >> 7;
    const int nwg = nbx * (M >> 8);
    const int bid = blockIdx.x;
    const int cpx = nwg >> 3;
    const int swzb = (bid & 7) * cpx + (bid >> 3);
    const int m0 = (swzb / nbx) * 256;
    const int n0 = (swzb % nbx) * 128;

    const int t = threadIdx.x;
    const int wid = t >> 6, lane = t & 63;
    const int wm = wid >> 1, wn = wid & 1;
    const int lrow = lane & 15, lg = lane >> 4;
    const int swzr = (lane & 7) * 8;
    const int sr = lane >> 3;
    const int ssc = ((lane & 7) ^ sr) * 8;

    f32x4 acc[4][4];
#pragma unroll
    for (int mi = 0; mi < 4; mi++)
#pragma unroll
        for (int ni = 0; ni < 4; ni++) acc[mi][ni] = (f32x4){0.f, 0.f, 0.f, 0.f};
    short8 bfr[4][2];

    const int T = K >> 6;
    const int niter = T >> 1;

#define DSRX(p, buf)                                                             \
    if ((p) == 0) {                                                              \
        _Pragma("unroll") for (int ni = 0; ni < 4; ni++)                         \
        _Pragma("unroll") for (int ks = 0; ks < 2; ks++)                         \
            bfr[ni][ks] = *(const short8*)(&SB[buf][(wn * 64 + ni * 16 + lrow) * 64 + \
                                                    ((ks * 32 + lg * 8) ^ swzr)]);    \
    }                                                                            \
    _Pragma("unroll") for (int mi2 = 0; mi2 < 2; mi2++)                          \
    _Pragma("unroll") for (int ks = 0; ks < 2; ks++)                             \
        af[mi2 * 2 + ks] = *(const short8*)(&SA[buf][(wm * 64 + (2 * (p) + mi2) * 16 + lrow) * 64 + \
                                                     ((ks * 32 + lg * 8) ^ swzr)]);

#define MFX(p)                                                                   \
    __builtin_amdgcn_s_setprio(1);                                               \
    _Pragma("unroll") for (int ks = 0; ks < 2; ks++)                             \
    _Pragma("unroll") for (int ni = 0; ni < 4; ni++)                             \
    _Pragma("unroll") for (int mi2 = 0; mi2 < 2; mi2++)                          \
        acc[2 * (p) + mi2][ni] = __builtin_amdgcn_mfma_f32_16x16x32_bf16(        \
            bfr[ni][ks], af[mi2 * 2 + ks], acc[2 * (p) + mi2][ni], 0, 0, 0);     \
    __builtin_amdgcn_s_setprio(0);

    STG(&SA[0][0], Ag, m0, 0);
    STG(&SA[0][HALF256], Ag, m0 + 128, 0);
    STG(&SB[0][0], Bg, n0, 0);
    STG(&SB[1][0], Bg, n0, 64);
    WAITVM2();
    BARRIER();

    for (int iter = 0; iter < niter; iter++) {
        const int tt = 2 * iter;
        const int ka = (tt + 1) * 64, kb = (tt + 2) * 64, kc = (tt + 3) * 64;
        const bool s2 = (tt + 2 < T), s3 = (tt + 3 < T);
        const bool last = (iter == niter - 1);
        short8 af[4];

        DSRX(0, 0);
        STG(&SA[1][0], Ag, m0, ka);
        STG(&SA[1][HALF256], Ag, m0 + 128, ka);
        WAITLGKM8();
        BARRIER(); WAITLGKM0(); MFX(0); BARRIER();
        DSRX(1, 0);
        if (s2) STG(&SB[0][0], Bg, n0, kb);
        BARRIER(); WAITLGKM0(); MFX(1);
        if (last) { WAITVM0(); } else { WAITVM2(); }
        BARRIER();
        DSRX(0, 1);
        if (s2) {
            STG(&SA[0][0], Ag, m0, kb);
            STG(&SA[0][HALF256], Ag, m0 + 128, kb);
        }
        WAITLGKM8();
        BARRIER(); WAITLGKM0(); MFX(0); BARRIER();
        DSRX(1, 1);
        if (s3) STG(&SB[1][0], Bg, n0, kc);
        BARRIER(); WAITLGKM0(); MFX(1);
        if (last) { WAITVM0(); } else { WAITVM2(); }
        BARRIER();
    }

#pragma unroll
    for (int mi = 0; mi < 4; mi++) {
        const int gm = m0 + wm * 64 + mi * 16 + lrow;
#pragma unroll
        for (int ni = 0; ni < 4; ni++) {
            const int gn = n0 + wn * 64 + ni * 16 + lg * 4;
            size_t gi = (size_t)gm * N + gn;
            f32x4 a = acc[mi][ni];
            if constexpr (EPI == 0) {
                uint2 o; o.x = bf2(a[0], a[1]); o.y = bf2(a[2], a[3]);
                *(uint2*)&(((bf16*)Cout)[gi]) = o;
            } else if constexpr (EPI == 3) {
                float4 rv = *(const float4*)&(((const float*)Res)[gi]);
                uint2 o; o.x = bf2(rv.x + a[0], rv.y + a[1]); o.y = bf2(rv.z + a[2], rv.w + a[3]);
                *(uint2*)&(((bf16*)Cout)[gi]) = o;
            } else {
                sh4 hv = *(const sh4*)&(((const bf16*)Res)[gi]);
                float4 o;
                o.x = bf16bits2f(hv[0]) + a[0];
                o.y = bf16bits2f(hv[1]) + a[1];
                o.z = bf16bits2f(hv[2]) + a[2];
                o.w = bf16bits2f(hv[3]) + a[3];
                *(float4*)&(((float*)Cout)[gi]) = o;
            }
        }
    }
}

// ---------------- MFMA flash attention: swapped operands, scalar m/l ----------------
// grid (16, B*H): block handles q-tiles {31-pi, pi}; Q pre-scaled (exp2 domain).
// S = mfma(K,Q): lane owns q-row = lane&15, kv = ni*16 + (lane>>4)*4 + r.
// PV = mfma(V,P): o[ni][r] = out[d = ni*16+(lane>>4)*4+r][q = lane&15].
__global__ __launch_bounds__(256, 4) void flash_attn(const bf16* __restrict__ qk,
                                                     const bf16* __restrict__ vt,
                                                     bf16* __restrict__ y) {
    const int pi = blockIdx.x;
    const int bh = blockIdx.y;
    const int b = bh >> 4, h = bh & 15;
    const int t = threadIdx.x;
    const int wave = t >> 6, lane = t & 63;
    const int lrow = lane & 15, lg = lane >> 4, lk = lg * 8;

    __shared__ alignas(16) short Ks[64 * 72];
    __shared__ alignas(16) short Vs[64 * 72];
    __shared__ alignas(16) short Ps[64 * 72];

    const size_t rs = 2 * C_;
    const bf16* Qg = qk + (size_t)b * T_ * rs + h * 64;
    const bf16* Kg = Qg + C_;
    const bf16* Vg = vt + (size_t)(h * 64) * M_TOK + b * T_;

    const int srow = t >> 3;
    const int sc8 = (t & 7) * 8;

    for (int sel = 0; sel < 2; sel++) {
        const int qtb = sel ? pi : 31 - pi;   // heavy first
        const int q0 = qtb * 64;
        const int nkt = qtb + 1;
        const int qg = q0 + wave * 16 + lrow;  // this lane's q row

        short8 qf[2];
        {
            const bf16* qr = Qg + (size_t)qg * rs;
            qf[0] = *(const short8*)(qr + lk);
            qf[1] = *(const short8*)(qr + 32 + lk);
        }

        f32x4 o[4];
        float m1 = -1e30f, l1 = 0.f;
#pragma unroll
        for (int ni = 0; ni < 4; ni++) o[ni] = (f32x4){0.f, 0.f, 0.f, 0.f};

        short8 kr[2], vr[2];
#pragma unroll
        for (int p = 0; p < 2; p++) {
            int r = srow + p * 32;
            kr[p] = *(const short8*)(Kg + (size_t)r * rs + sc8);
            vr[p] = *(const short8*)(Vg + (size_t)r * M_TOK + sc8);
        }

        for (int kt = 0; kt < nkt; kt++) {
            const int s0 = kt * 64;
#pragma unroll
            for (int p = 0; p < 2; p++) {
                int r = srow + p * 32;
                *(short8*)(&Ks[r * 72 + sc8]) = kr[p];
                *(short8*)(&Vs[r * 72 + sc8]) = vr[p];
            }
            __syncthreads();
            if (kt + 1 < nkt) {
                const int s0n = (kt + 1) * 64;
#pragma unroll
                for (int p = 0; p < 2; p++) {
                    int r = srow + p * 32;
                    kr[p] = *(const short8*)(Kg + (size_t)(s0n + r) * rs + sc8);
                    vr[p] = *(const short8*)(Vg + (size_t)r * M_TOK + s0n + sc8);
                }
            }

            // ---- S = mfma(K, Q): lane = (q=lrow, kv reg-dim) ----
            f32x4 s[4];
#pragma unroll
            for (int ni = 0; ni < 4; ni++) s[ni] = (f32x4){0.f, 0.f, 0.f, 0.f};
            __builtin_amdgcn_s_setprio(1);
#pragma unroll
            for (int ks = 0; ks < 2; ks++) {
#pragma unroll
                for (int ni = 0; ni < 4; ni++) {
                    short8 kf = *(const short8*)(&Ks[(ni * 16 + lrow) * 72 + ks * 32 + lk]);
                    s[ni] = __builtin_amdgcn_mfma_f32_16x16x32_bf16(kf, qf[ks], s[ni], 0, 0, 0);
                }
            }
            __builtin_amdgcn_s_setprio(0);

            // causal mask on diagonal tile only
            if (kt == nkt - 1) {
#pragma unroll
                for (int ni = 0; ni < 4; ni++)
#pragma unroll
                    for (int r = 0; r < 4; r++) {
                        int kvg = s0 + ni * 16 + lg * 4 + r;
                        if (kvg > qg) s[ni][r] = -1e30f;
                    }
            }

            // ---- online softmax (scalar m/l per lane) ----
            float pm = s[0][0];
#pragma unroll
            for (int ni = 0; ni < 4; ni++)
#pragma unroll
                for (int r = 0; r < 4; r++) pm = fmaxf(pm, s[ni][r]);
            pm = fmaxf(pm, __shfl_xor(pm, 16));
            pm = fmaxf(pm, __shfl_xor(pm, 32));
            if (!__all(pm - m1 <= 8.f)) {
                float mn = fmaxf(m1, pm);
                float alpha = fexp2(m1 - mn);
                m1 = mn;
                l1 *= alpha;
#pragma unroll
                for (int ni = 0; ni < 4; ni++)
#pragma unroll
                    for (int r = 0; r < 4; r++) o[ni][r] *= alpha;
            }
            float rsum = 0.f;
#pragma unroll
            for (int ni = 0; ni < 4; ni++) {
                float p0 = fexp2(s[ni][0] - m1);
                float p1 = fexp2(s[ni][1] - m1);
                float p2 = fexp2(s[ni][2] - m1);
                float p3 = fexp2(s[ni][3] - m1);
                rsum += (p0 + p1) + (p2 + p3);
                uint2 pk; pk.x = bf2(p0, p1); pk.y = bf2(p2, p3);
                *(uint2*)(&Ps[(wave * 16 + lrow) * 72 + ni * 16 + lg * 4]) = pk;
            }
            rsum += __shfl_xor(rsum, 16);
            rsum += __shfl_xor(rsum, 32);
            l1 += rsum;

            // ---- PV = mfma(V, P): o[ni] rows = d, col = q ----
            __builtin_amdgcn_s_setprio(1);
#pragma unroll
            for (int ks2 = 0; ks2 < 2; ks2++) {
                short8 pf = *(const short8*)(&Ps[(wave * 16 + lrow) * 72 + ks2 * 32 + lk]);
#pragma unroll
                for (int ni = 0; ni < 4; ni++) {
                    short8 vf = *(const short8*)(&Vs[(ni * 16 + lrow) * 72 + ks2 * 32 + lk]);
                    o[ni] = __builtin_amdgcn_mfma_f32_16x16x32_bf16(vf, pf, o[ni], 0, 0, 0);
                }
            }
            __builtin_amdgcn_s_setprio(0);
            __syncthreads();
        }

        // ---- write O: lane owns q-row qg, 4 consecutive d per fragment ----
        float inv = 1.f / l1;
#pragma unroll
        for (int ni = 0; ni < 4; ni++) {
            uint2 pk;
            pk.x = bf2(o[ni][0] * inv, o[ni][1] * inv);
            pk.y = bf2(o[ni][2] * inv, o[ni][3] * inv);
            *(uint2*)(&y[((size_t)(b * T_ + qg)) * C_ + h * 64 + ni * 16 + lg * 4]) = pk;
        }
    }
}

// ---------------- launch ----------------
extern "C" void kernel_launch(void* const* d_in, const int* in_sizes, int n_in,
                              void* d_out, int out_size, void* d_ws, size_t ws_size,
                              hipStream_t stream) {
    const float* x      = (const float*)d_in[0];
    const float* ln1w   = (const float*)d_in[1];
    const float* ln1b   = (const float*)d_in[2];
    const float* ln2w   = (const float*)d_in[3];
    const float* ln2b   = (const float*)d_in[4];
    const float* w_attn = (const float*)d_in[5];
    const float* w_proj = (const float*)d_in[6];
    const float* w_fc   = (const float*)d_in[7];
    const float* w_fcp  = (const float*)d_in[8];
    float* out = (float*)d_out;

    char* ws = (char*)d_ws;
    bf16* ln_buf  = (bf16*)(ws);                   // [0,16M)
    bf16* qk_buf  = (bf16*)(ws + (16u << 20));     // [16,48M)
    bf16* vt_buf  = (bf16*)(ws + (48u << 20));     // [48,64M)
    bf16* ybuf    = (bf16*)(ws + (64u << 20));     // [64,80M)
    bf16* ubuf    = (bf16*)(ws + (16u << 20));     // [16,80M) reuse after attn
    bf16* x2b     = (bf16*)(ws + (80u << 20));     // [80,96M)
    bf16* wattn_h = (bf16*)(ws + (112u << 20));
    bf16* wproj_h = (bf16*)(ws + (118u << 20));
    bf16* wfc_h   = (bf16*)(ws + (120u << 20));
    bf16* wfcp_h  = (bf16*)(ws + (128u << 20));

    {
        int n1 = 3 * C_ * C_ / 4, n2 = C_ * C_ / 4, n3 = FF_ * C_ / 4, n4 = C_ * FF_ / 4;
        cvt_f32_bf16_v4<<<(n1 + 255) / 256, 256, 0, stream>>>(w_attn, wattn_h, n1);
        cvt_f32_bf16_v4<<<(n2 + 255) / 256, 256, 0, stream>>>(w_proj, wproj_h, n2);
        cvt_f32_bf16_v4<<<(n3 + 255) / 256, 256, 0, stream>>>(w_fc, wfc_h, n3);
        cvt_f32_bf16_v4<<<(n4 + 255) / 256, 256, 0, stream>>>(w_fcp, wfcp_h, n4);
    }

    // LN1 (f32 in)
    ln_kernel<float><<<M_TOK, 256, 0, stream>>>(x, ln1w, ln1b, ln_buf);

    // qk = ln_buf @ w_attn[0:2C]^T  (256^2 8-phase; Q columns pre-scaled)
    gemm256<5><<<dim3((M_TOK / 256) * (2 * C_ / 256)), 512, 0, stream>>>(
        ln_buf, wattn_h, qk_buf, M_TOK, 2 * C_, C_);

    // vt = w_v @ ln_buf^T  [1024, 8192]  (256x128 8-phase)
    gemm256x128<0><<<dim3((C_ / 256) * (M_TOK / 128)), 512, 0, stream>>>(
        wattn_h + (size_t)2 * C_ * C_, ln_buf, vt_buf, nullptr, C_, M_TOK, C_);

    // attention (64-row tiles, 1024 blocks)
    flash_attn<<<dim3(16, B_ * H_), 256, 0, stream>>>(qk_buf, vt_buf, ybuf);

    // x2b = bf16(x + ybuf @ w_proj^T)  (256x128 8-phase)
    gemm256x128<3><<<dim3((M_TOK / 256) * (C_ / 128)), 512, 0, stream>>>(
        ybuf, wproj_h, x2b, x, M_TOK, C_, C_);

    // LN2 (bf16 in)
    ln_kernel<bf16><<<M_TOK, 256, 0, stream>>>(x2b, ln2w, ln2b, ln_buf);

    // u = gelu(ln_buf @ w_fc^T)  (256^2 8-phase)
    gemm256<2><<<dim3((M_TOK / 256) * (FF_ / 256)), 512, 0, stream>>>(
        ln_buf, wfc_h, ubuf, M_TOK, FF_, C_);

    // out = f32(x2b) + u @ w_fcp^T  (256x128 8-phase)
    gemm256x128<4><<<dim3((M_TOK / 256) * (C_ / 128)), 512, 0, stream>>>(
        ubuf, wfcp_h, out, x2b, M_TOK, C_, FF_);
}

// Round 11
// 354.898 us; speedup vs baseline: 26.4063x; 1.0767x over previous
//
#include <hip/hip_runtime.h>
#include <hip/hip_bf16.h>

using bf16 = __hip_bfloat16;
typedef __attribute__((ext_vector_type(8))) short short8;
typedef __attribute__((ext_vector_type(4))) short sh4;
typedef __attribute__((ext_vector_type(4))) float f32x4;

#define B_ 4
#define T_ 2048
#define C_ 1024
#define H_ 16
#define FF_ 4096
#define M_TOK (B_ * T_)   // 8192
#define SCALE2 0.1803368801111f   // 0.125 * log2(e)

#define BARRIER() asm volatile("s_barrier" ::: "memory")
#define WAITLGKM0() asm volatile("s_waitcnt lgkmcnt(0)" ::: "memory")
#define WAITLGKM8() asm volatile("s_waitcnt lgkmcnt(8)" ::: "memory")
#define WAITVM4() asm volatile("s_waitcnt vmcnt(4)" ::: "memory")
#define WAITVM2() asm volatile("s_waitcnt vmcnt(2)" ::: "memory")
#define WAITVM0() asm volatile("s_waitcnt vmcnt(0)" ::: "memory")

// ---------------- async global->LDS 16B ----------------
__device__ __forceinline__ void gload16(const void* g, void* l) {
    __builtin_amdgcn_global_load_lds(
        (const __attribute__((address_space(1))) void*)g,
        (__attribute__((address_space(3))) void*)l, 16, 0, 0);
}

// 2^x in one instruction
__device__ __forceinline__ float fexp2(float x) {
    float r;
    asm("v_exp_f32 %0, %1" : "=v"(r) : "v"(x));
    return r;
}

__device__ __forceinline__ float bf16bits2f(short s) {
    return __uint_as_float(((unsigned)(unsigned short)s) << 16);
}

// pack two f32 -> one dword of 2 bf16
__device__ __forceinline__ unsigned bf2(float a, float b) {
    bf16 x = __float2bfloat16(a), y = __float2bfloat16(b);
    unsigned short ux = *(unsigned short*)&x, uy = *(unsigned short*)&y;
    return (unsigned)ux | ((unsigned)uy << 16);
}

// fast gelu: x * t / (t + 1), t = exp(2 * 0.79788456(x + 0.044715 x^3))
__device__ __forceinline__ float fgelu(float x) {
    float y = 0.79788456f * (x + 0.044715f * x * x * x);
    float tv = fexp2(y * 2.885390082f);   // e^{2y} = 2^{2y*log2e}
    return x * tv * __builtin_amdgcn_rcpf(tv + 1.f);
}

// ---------------- fused prep: LN1 (blocks 0..8191) + weight cvt (rest) ----------------
__global__ __launch_bounds__(256) void prep_kernel(
    const float* __restrict__ x, const float* __restrict__ ln1w, const float* __restrict__ ln1b,
    bf16* __restrict__ ln_out,
    const float* __restrict__ w_attn, const float* __restrict__ w_proj,
    const float* __restrict__ w_fc, const float* __restrict__ w_fcp,
    bf16* __restrict__ wattn_h, bf16* __restrict__ wproj_h,
    bf16* __restrict__ wfc_h, bf16* __restrict__ wfcp_h) {
    const int bid = blockIdx.x;
    const int t = threadIdx.x;
    if (bid < M_TOK) {
        // ---- LayerNorm row ----
        float4 v = ((const float4*)(x + (size_t)bid * C_))[t];
        float s = v.x + v.y + v.z + v.w;
        float s2 = v.x * v.x + v.y * v.y + v.z * v.z + v.w * v.w;
#pragma unroll
        for (int off = 32; off > 0; off >>= 1) {
            s += __shfl_down(s, off);
            s2 += __shfl_down(s2, off);
        }
        __shared__ float ss[4], ss2[4];
        int wave = t >> 6, lane = t & 63;
        if (lane == 0) { ss[wave] = s; ss2[wave] = s2; }
        __syncthreads();
        s = ss[0] + ss[1] + ss[2] + ss[3];
        s2 = ss2[0] + ss2[1] + ss2[2] + ss2[3];
        float mu = s * (1.f / C_);
        float var = s2 * (1.f / C_) - mu * mu;
        float rstd = rsqrtf(var + 1e-5f);
        float4 wv = ((const float4*)ln1w)[t];
        float4 bv = ((const float4*)ln1b)[t];
        uint2 o;
        o.x = bf2((v.x - mu) * rstd * wv.x + bv.x, (v.y - mu) * rstd * wv.y + bv.y);
        o.y = bf2((v.z - mu) * rstd * wv.z + bv.z, (v.w - mu) * rstd * wv.w + bv.w);
        ((uint2*)(ln_out + (size_t)bid * C_))[t] = o;
    } else {
        // ---- weight convert, 4 floats/thread over concatenated ranges ----
        int i = (bid - M_TOK) * 256 + t;   // float4 index
        const float* src;
        bf16* dst;
        int base;
        if (i < 786432) {            // w_attn: 3C*C/4
            src = w_attn; dst = wattn_h; base = 0;
        } else if (i < 1048576) {    // w_proj: C*C/4
            src = w_proj; dst = wproj_h; base = 786432;
        } else if (i < 2097152) {    // w_fc: FF*C/4
            src = w_fc; dst = wfc_h; base = 1048576;
        } else {                     // w_fcp: C*FF/4
            src = w_fcp; dst = wfcp_h; base = 2097152;
        }
        int j = i - base;
        float4 v = ((const float4*)src)[j];
        uint2 o;
        o.x = bf2(v.x, v.y);
        o.y = bf2(v.z, v.w);
        ((uint2*)dst)[j] = o;
    }
}

// ---------------- LayerNorm (LN2): bf16 in -> bf16 out ----------------
__global__ __launch_bounds__(256) void ln_kernel_b(const bf16* __restrict__ x,
                                                   const float* __restrict__ w,
                                                   const float* __restrict__ b,
                                                   bf16* __restrict__ out) {
    int row = blockIdx.x;
    int t = threadIdx.x;
    sh4 h = ((const sh4*)(x + (size_t)row * C_))[t];
    float4 v;
    v.x = bf16bits2f(h[0]);
    v.y = bf16bits2f(h[1]);
    v.z = bf16bits2f(h[2]);
    v.w = bf16bits2f(h[3]);
    float s = v.x + v.y + v.z + v.w;
    float s2 = v.x * v.x + v.y * v.y + v.z * v.z + v.w * v.w;
#pragma unroll
    for (int off = 32; off > 0; off >>= 1) {
        s += __shfl_down(s, off);
        s2 += __shfl_down(s2, off);
    }
    __shared__ float ss[4], ss2[4];
    int wave = t >> 6, lane = t & 63;
    if (lane == 0) { ss[wave] = s; ss2[wave] = s2; }
    __syncthreads();
    s = ss[0] + ss[1] + ss[2] + ss[3];
    s2 = ss2[0] + ss2[1] + ss2[2] + ss2[3];
    float mu = s * (1.f / C_);
    float var = s2 * (1.f / C_) - mu * mu;
    float rstd = rsqrtf(var + 1e-5f);
    float4 wv = ((const float4*)w)[t];
    float4 bv = ((const float4*)b)[t];
    uint2 o;
    o.x = bf2((v.x - mu) * rstd * wv.x + bv.x, (v.y - mu) * rstd * wv.y + bv.y);
    o.y = bf2((v.z - mu) * rstd * wv.z + bv.z, (v.w - mu) * rstd * wv.w + bv.w);
    ((uint2*)(out + (size_t)row * C_))[t] = o;
}

// ======== shared staging macro ========
#define STG(ldsbase, g, grow0, k0)                                               \
    {                                                                            \
        _Pragma("unroll") for (int s_ = 0; s_ < 2; s_++) {                       \
            int row_ = s_ * 64 + wid * 8 + sr;                                   \
            gload16(g + (size_t)((grow0) + row_) * K + (k0) + ssc,               \
                    (ldsbase) + row_ * 64 + (lane & 7) * 8);                     \
        }                                                                        \
    }

// ---------------- 256x256 8-phase NT GEMM (T2+T3+T4+T5) ----------------
// Operand-swapped MFMA: D reg-dim = N (4 consecutive cols/lane).
// EPI 0: bf16  EPI 2: bf16 fgelu  EPI 5: bf16, cols<C_ scaled by SCALE2
#define HALF256 (128 * 64)
template <int EPI>
__global__ __launch_bounds__(512, 2) void gemm256(const bf16* __restrict__ Ag,
                                                  const bf16* __restrict__ Bg,
                                                  void* __restrict__ Cout,
                                                  int M, int N, int K) {
    __shared__ short SA[2][256 * 64];
    __shared__ short SB[2][256 * 64];

    const int nbx = N >> 8;
    const int nwg = nbx * (M >> 8);
    const int bid = blockIdx.x;
    const int cpx = nwg >> 3;
    const int swzb = (bid & 7) * cpx + (bid >> 3);
    const int m0 = (swzb / nbx) * 256;
    const int n0 = (swzb % nbx) * 256;

    const int t = threadIdx.x;
    const int wid = t >> 6, lane = t & 63;
    const int wm = wid >> 2, wn = wid & 3;
    const int lrow = lane & 15, lg = lane >> 4;
    const int swzr = (lane & 7) * 8;
    const int sr = lane >> 3;
    const int ssc = ((lane & 7) ^ sr) * 8;

    f32x4 acc[8][4];
#pragma unroll
    for (int mi = 0; mi < 8; mi++)
#pragma unroll
        for (int ni = 0; ni < 4; ni++) acc[mi][ni] = (f32x4){0.f, 0.f, 0.f, 0.f};
    short8 bfr[4][2];

    const int T = K >> 6;
    const int niter = T >> 1;

#define DSREADS256(q, buf)                                                       \
    if ((q) == 0) {                                                              \
        _Pragma("unroll") for (int ni = 0; ni < 4; ni++)                         \
        _Pragma("unroll") for (int ks = 0; ks < 2; ks++)                         \
            bfr[ni][ks] = *(const short8*)(&SB[buf][(wn * 64 + ni * 16 + lrow) * 64 + \
                                                    ((ks * 32 + lg * 8) ^ swzr)]);    \
    }                                                                            \
    _Pragma("unroll") for (int mi2 = 0; mi2 < 2; mi2++)                          \
    _Pragma("unroll") for (int ks = 0; ks < 2; ks++)                             \
        af[mi2 * 2 + ks] = *(const short8*)(&SA[buf][(wm * 128 + (2 * (q) + mi2) * 16 + lrow) * 64 + \
                                                     ((ks * 32 + lg * 8) ^ swzr)]);

#define MFMAS256(q)                                                              \
    __builtin_amdgcn_s_setprio(1);                                               \
    _Pragma("unroll") for (int ks = 0; ks < 2; ks++)                             \
    _Pragma("unroll") for (int ni = 0; ni < 4; ni++)                             \
    _Pragma("unroll") for (int mi2 = 0; mi2 < 2; mi2++)                          \
        acc[2 * (q) + mi2][ni] = __builtin_amdgcn_mfma_f32_16x16x32_bf16(        \
            bfr[ni][ks], af[mi2 * 2 + ks], acc[2 * (q) + mi2][ni], 0, 0, 0);     \
    __builtin_amdgcn_s_setprio(0);

    STG(&SA[0][0], Ag, m0, 0);
    STG(&SA[0][HALF256], Ag, m0 + 128, 0);
    STG(&SB[0][0], Bg, n0, 0);
    STG(&SB[0][HALF256], Bg, n0 + 128, 0);
    STG(&SB[1][0], Bg, n0, 64);
    STG(&SB[1][HALF256], Bg, n0 + 128, 64);
    WAITVM4();
    BARRIER();

    for (int iter = 0; iter < niter; iter++) {
        const int tt = 2 * iter;
        const int ka = (tt + 1) * 64, kb = (tt + 2) * 64, kc = (tt + 3) * 64;
        const bool s2 = (tt + 2 < T), s3 = (tt + 3 < T);
        const bool last = (iter == niter - 1);
        short8 af[4];

        DSREADS256(0, 0);
        STG(&SA[1][0], Ag, m0, ka);
        WAITLGKM8();
        BARRIER(); WAITLGKM0(); MFMAS256(0); BARRIER();
        DSREADS256(1, 0);
        STG(&SA[1][HALF256], Ag, m0 + 128, ka);
        BARRIER(); WAITLGKM0(); MFMAS256(1); BARRIER();
        DSREADS256(2, 0);
        if (s2) STG(&SB[0][0], Bg, n0, kb);
        BARRIER(); WAITLGKM0(); MFMAS256(2); BARRIER();
        DSREADS256(3, 0);
        if (s2) STG(&SB[0][HALF256], Bg, n0 + 128, kb);
        BARRIER(); WAITLGKM0(); MFMAS256(3);
        if (last) { WAITVM0(); } else { WAITVM4(); }
        BARRIER();
        DSREADS256(0, 1);
        if (s2) STG(&SA[0][0], Ag, m0, kb);
        WAITLGKM8();
        BARRIER(); WAITLGKM0(); MFMAS256(0); BARRIER();
        DSREADS256(1, 1);
        if (s2) STG(&SA[0][HALF256], Ag, m0 + 128, kb);
        BARRIER(); WAITLGKM0(); MFMAS256(1); BARRIER();
        DSREADS256(2, 1);
        if (s3) STG(&SB[1][0], Bg, n0, kc);
        BARRIER(); WAITLGKM0(); MFMAS256(2); BARRIER();
        DSREADS256(3, 1);
        if (s3) STG(&SB[1][HALF256], Bg, n0 + 128, kc);
        BARRIER(); WAITLGKM0(); MFMAS256(3);
        if (!last) WAITVM4();
        BARRIER();
    }

    // epilogue: lane holds 4 consecutive N-cols per fragment
#pragma unroll
    for (int mi = 0; mi < 8; mi++) {
        const int gm = m0 + wm * 128 + mi * 16 + lrow;
#pragma unroll
        for (int ni = 0; ni < 4; ni++) {
            const int gn = n0 + wn * 64 + ni * 16 + lg * 4;
            size_t gi = (size_t)gm * N + gn;
            f32x4 a = acc[mi][ni];
            if constexpr (EPI == 0) {
                uint2 o; o.x = bf2(a[0], a[1]); o.y = bf2(a[2], a[3]);
                *(uint2*)&(((bf16*)Cout)[gi]) = o;
            } else if constexpr (EPI == 5) {
                float sc = (gn < C_) ? SCALE2 : 1.f;
                uint2 o; o.x = bf2(a[0] * sc, a[1] * sc); o.y = bf2(a[2] * sc, a[3] * sc);
                *(uint2*)&(((bf16*)Cout)[gi]) = o;
            } else {
                uint2 o;
                o.x = bf2(fgelu(a[0]), fgelu(a[1]));
                o.y = bf2(fgelu(a[2]), fgelu(a[3]));
                *(uint2*)&(((bf16*)Cout)[gi]) = o;
            }
        }
    }
}

// ---------------- 256x128 8-phase NT GEMM (N=1024-class shapes) ----------------
// EPI 0: bf16  EPI 3: bf16 = f32 Res + acc  EPI 4: f32 = bf16 Res + acc
template <int EPI>
__global__ __launch_bounds__(512, 2) void gemm256x128(const bf16* __restrict__ Ag,
                                                      const bf16* __restrict__ Bg,
                                                      void* __restrict__ Cout,
                                                      const void* __restrict__ Res,
                                                      int M, int N, int K) {
    __shared__ short SA[2][256 * 64];
    __shared__ short SB[2][128 * 64];

    const int nbx = N >> 7;
    const int nwg = nbx * (M >> 8);
    const int bid = blockIdx.x;
    const int cpx = nwg >> 3;
    const int swzb = (bid & 7) * cpx + (bid >> 3);
    const int m0 = (swzb / nbx) * 256;
    const int n0 = (swzb % nbx) * 128;

    const int t = threadIdx.x;
    const int wid = t >> 6, lane = t & 63;
    const int wm = wid >> 1, wn = wid & 1;
    const int lrow = lane & 15, lg = lane >> 4;
    const int swzr = (lane & 7) * 8;
    const int sr = lane >> 3;
    const int ssc = ((lane & 7) ^ sr) * 8;

    f32x4 acc[4][4];
#pragma unroll
    for (int mi = 0; mi < 4; mi++)
#pragma unroll
        for (int ni = 0; ni < 4; ni++) acc[mi][ni] = (f32x4){0.f, 0.f, 0.f, 0.f};
    short8 bfr[4][2];

    const int T = K >> 6;
    const int niter = T >> 1;

#define DSRX(p, buf)                                                             \
    if ((p) == 0) {                                                              \
        _Pragma("unroll") for (int ni = 0; ni < 4; ni++)                         \
        _Pragma("unroll") for (int ks = 0; ks < 2; ks++)                         \
            bfr[ni][ks] = *(const short8*)(&SB[buf][(wn * 64 + ni * 16 + lrow) * 64 + \
                                                    ((ks * 32 + lg * 8) ^ swzr)]);    \
    }                                                                            \
    _Pragma("unroll") for (int mi2 = 0; mi2 < 2; mi2++)                          \
    _Pragma("unroll") for (int ks = 0; ks < 2; ks++)                             \
        af[mi2 * 2 + ks] = *(const short8*)(&SA[buf][(wm * 64 + (2 * (p) + mi2) * 16 + lrow) * 64 + \
                                                     ((ks * 32 + lg * 8) ^ swzr)]);

#define MFX(p)                                                                   \
    __builtin_amdgcn_s_setprio(1);                                               \
    _Pragma("unroll") for (int ks = 0; ks < 2; ks++)                             \
    _Pragma("unroll") for (int ni = 0; ni < 4; ni++)                             \
    _Pragma("unroll") for (int mi2 = 0; mi2 < 2; mi2++)                          \
        acc[2 * (p) + mi2][ni] = __builtin_amdgcn_mfma_f32_16x16x32_bf16(        \
            bfr[ni][ks], af[mi2 * 2 + ks], acc[2 * (p) + mi2][ni], 0, 0, 0);     \
    __builtin_amdgcn_s_setprio(0);

    STG(&SA[0][0], Ag, m0, 0);
    STG(&SA[0][HALF256], Ag, m0 + 128, 0);
    STG(&SB[0][0], Bg, n0, 0);
    STG(&SB[1][0], Bg, n0, 64);
    WAITVM2();
    BARRIER();

    for (int iter = 0; iter < niter; iter++) {
        const int tt = 2 * iter;
        const int ka = (tt + 1) * 64, kb = (tt + 2) * 64, kc = (tt + 3) * 64;
        const bool s2 = (tt + 2 < T), s3 = (tt + 3 < T);
        const bool last = (iter == niter - 1);
        short8 af[4];

        DSRX(0, 0);
        STG(&SA[1][0], Ag, m0, ka);
        STG(&SA[1][HALF256], Ag, m0 + 128, ka);
        WAITLGKM8();
        BARRIER(); WAITLGKM0(); MFX(0); BARRIER();
        DSRX(1, 0);
        if (s2) STG(&SB[0][0], Bg, n0, kb);
        BARRIER(); WAITLGKM0(); MFX(1);
        if (last) { WAITVM0(); } else { WAITVM2(); }
        BARRIER();
        DSRX(0, 1);
        if (s2) {
            STG(&SA[0][0], Ag, m0, kb);
            STG(&SA[0][HALF256], Ag, m0 + 128, kb);
        }
        WAITLGKM8();
        BARRIER(); WAITLGKM0(); MFX(0); BARRIER();
        DSRX(1, 1);
        if (s3) STG(&SB[1][0], Bg, n0, kc);
        BARRIER(); WAITLGKM0(); MFX(1);
        if (last) { WAITVM0(); } else { WAITVM2(); }
        BARRIER();
    }

#pragma unroll
    for (int mi = 0; mi < 4; mi++) {
        const int gm = m0 + wm * 64 + mi * 16 + lrow;
#pragma unroll
        for (int ni = 0; ni < 4; ni++) {
            const int gn = n0 + wn * 64 + ni * 16 + lg * 4;
            size_t gi = (size_t)gm * N + gn;
            f32x4 a = acc[mi][ni];
            if constexpr (EPI == 0) {
                uint2 o; o.x = bf2(a[0], a[1]); o.y = bf2(a[2], a[3]);
                *(uint2*)&(((bf16*)Cout)[gi]) = o;
            } else if constexpr (EPI == 3) {
                float4 rv = *(const float4*)&(((const float*)Res)[gi]);
                uint2 o; o.x = bf2(rv.x + a[0], rv.y + a[1]); o.y = bf2(rv.z + a[2], rv.w + a[3]);
                *(uint2*)&(((bf16*)Cout)[gi]) = o;
            } else {
                sh4 hv = *(const sh4*)&(((const bf16*)Res)[gi]);
                float4 o;
                o.x = bf16bits2f(hv[0]) + a[0];
                o.y = bf16bits2f(hv[1]) + a[1];
                o.z = bf16bits2f(hv[2]) + a[2];
                o.w = bf16bits2f(hv[3]) + a[3];
                *(float4*)&(((float*)Cout)[gi]) = o;
            }
        }
    }
}

// ---------------- MFMA flash attention: swapped operands, scalar m/l ----------------
__global__ __launch_bounds__(256, 4) void flash_attn(const bf16* __restrict__ qk,
                                                     const bf16* __restrict__ vt,
                                                     bf16* __restrict__ y) {
    const int pi = blockIdx.x;
    const int bh = blockIdx.y;
    const int b = bh >> 4, h = bh & 15;
    const int t = threadIdx.x;
    const int wave = t >> 6, lane = t & 63;
    const int lrow = lane & 15, lg = lane >> 4, lk = lg * 8;

    __shared__ alignas(16) short Ks[64 * 72];
    __shared__ alignas(16) short Vs[64 * 72];
    __shared__ alignas(16) short Ps[64 * 72];

    const size_t rs = 2 * C_;
    const bf16* Qg = qk + (size_t)b * T_ * rs + h * 64;
    const bf16* Kg = Qg + C_;
    const bf16* Vg = vt + (size_t)(h * 64) * M_TOK + b * T_;

    const int srow = t >> 3;
    const int sc8 = (t & 7) * 8;

    for (int sel = 0; sel < 2; sel++) {
        const int qtb = sel ? pi : 31 - pi;
        const int q0 = qtb * 64;
        const int nkt = qtb + 1;
        const int qg = q0 + wave * 16 + lrow;

        short8 qf[2];
        {
            const bf16* qr = Qg + (size_t)qg * rs;
            qf[0] = *(const short8*)(qr + lk);
            qf[1] = *(const short8*)(qr + 32 + lk);
        }

        f32x4 o[4];
        float m1 = -1e30f, l1 = 0.f;
#pragma unroll
        for (int ni = 0; ni < 4; ni++) o[ni] = (f32x4){0.f, 0.f, 0.f, 0.f};

        short8 kr[2], vr[2];
#pragma unroll
        for (int p = 0; p < 2; p++) {
            int r = srow + p * 32;
            kr[p] = *(const short8*)(Kg + (size_t)r * rs + sc8);
            vr[p] = *(const short8*)(Vg + (size_t)r * M_TOK + sc8);
        }

        for (int kt = 0; kt < nkt; kt++) {
            const int s0 = kt * 64;
#pragma unroll
            for (int p = 0; p < 2; p++) {
                int r = srow + p * 32;
                *(short8*)(&Ks[r * 72 + sc8]) = kr[p];
                *(short8*)(&Vs[r * 72 + sc8]) = vr[p];
            }
            __syncthreads();
            if (kt + 1 < nkt) {
                const int s0n = (kt + 1) * 64;
#pragma unroll
                for (int p = 0; p < 2; p++) {
                    int r = srow + p * 32;
                    kr[p] = *(const short8*)(Kg + (size_t)(s0n + r) * rs + sc8);
                    vr[p] = *(const short8*)(Vg + (size_t)r * M_TOK + s0n + sc8);
                }
            }

            f32x4 s[4];
#pragma unroll
            for (int ni = 0; ni < 4; ni++) s[ni] = (f32x4){0.f, 0.f, 0.f, 0.f};
            __builtin_amdgcn_s_setprio(1);
#pragma unroll
            for (int ks = 0; ks < 2; ks++) {
#pragma unroll
                for (int ni = 0; ni < 4; ni++) {
                    short8 kf = *(const short8*)(&Ks[(ni * 16 + lrow) * 72 + ks * 32 + lk]);
                    s[ni] = __builtin_amdgcn_mfma_f32_16x16x32_bf16(kf, qf[ks], s[ni], 0, 0, 0);
                }
            }
            __builtin_amdgcn_s_setprio(0);

            if (kt == nkt - 1) {
#pragma unroll
                for (int ni = 0; ni < 4; ni++)
#pragma unroll
                    for (int r = 0; r < 4; r++) {
                        int kvg = s0 + ni * 16 + lg * 4 + r;
                        if (kvg > qg) s[ni][r] = -1e30f;
                    }
            }

            float pm = s[0][0];
#pragma unroll
            for (int ni = 0; ni < 4; ni++)
#pragma unroll
                for (int r = 0; r < 4; r++) pm = fmaxf(pm, s[ni][r]);
            pm = fmaxf(pm, __shfl_xor(pm, 16));
            pm = fmaxf(pm, __shfl_xor(pm, 32));
            if (!__all(pm - m1 <= 8.f)) {
                float mn = fmaxf(m1, pm);
                float alpha = fexp2(m1 - mn);
                m1 = mn;
                l1 *= alpha;
#pragma unroll
                for (int ni = 0; ni < 4; ni++)
#pragma unroll
                    for (int r = 0; r < 4; r++) o[ni][r] *= alpha;
            }
            float rsum = 0.f;
#pragma unroll
            for (int ni = 0; ni < 4; ni++) {
                float p0 = fexp2(s[ni][0] - m1);
                float p1 = fexp2(s[ni][1] - m1);
                float p2 = fexp2(s[ni][2] - m1);
                float p3 = fexp2(s[ni][3] - m1);
                rsum += (p0 + p1) + (p2 + p3);
                uint2 pk; pk.x = bf2(p0, p1); pk.y = bf2(p2, p3);
                *(uint2*)(&Ps[(wave * 16 + lrow) * 72 + ni * 16 + lg * 4]) = pk;
            }
            rsum += __shfl_xor(rsum, 16);
            rsum += __shfl_xor(rsum, 32);
            l1 += rsum;

            __builtin_amdgcn_s_setprio(1);
#pragma unroll
            for (int ks2 = 0; ks2 < 2; ks2++) {
                short8 pf = *(const short8*)(&Ps[(wave * 16 + lrow) * 72 + ks2 * 32 + lk]);
#pragma unroll
                for (int ni = 0; ni < 4; ni++) {
                    short8 vf = *(const short8*)(&Vs[(ni * 16 + lrow) * 72 + ks2 * 32 + lk]);
                    o[ni] = __builtin_amdgcn_mfma_f32_16x16x32_bf16(vf, pf, o[ni], 0, 0, 0);
                }
            }
            __builtin_amdgcn_s_setprio(0);
            __syncthreads();
        }

        float inv = 1.f / l1;
#pragma unroll
        for (int ni = 0; ni < 4; ni++) {
            uint2 pk;
            pk.x = bf2(o[ni][0] * inv, o[ni][1] * inv);
            pk.y = bf2(o[ni][2] * inv, o[ni][3] * inv);
            *(uint2*)(&y[((size_t)(b * T_ + qg)) * C_ + h * 64 + ni * 16 + lg * 4]) = pk;
        }
    }
}

// ---------------- launch ----------------
extern "C" void kernel_launch(void* const* d_in, const int* in_sizes, int n_in,
                              void* d_out, int out_size, void* d_ws, size_t ws_size,
                              hipStream_t stream) {
    const float* x      = (const float*)d_in[0];
    const float* ln1w   = (const float*)d_in[1];
    const float* ln1b   = (const float*)d_in[2];
    const float* ln2w   = (const float*)d_in[3];
    const float* ln2b   = (const float*)d_in[4];
    const float* w_attn = (const float*)d_in[5];
    const float* w_proj = (const float*)d_in[6];
    const float* w_fc   = (const float*)d_in[7];
    const float* w_fcp  = (const float*)d_in[8];
    float* out = (float*)d_out;

    char* ws = (char*)d_ws;
    bf16* ln_buf  = (bf16*)(ws);                   // [0,16M)
    bf16* qk_buf  = (bf16*)(ws + (16u << 20));     // [16,48M)
    bf16* vt_buf  = (bf16*)(ws + (48u << 20));     // [48,64M)
    bf16* ybuf    = (bf16*)(ws + (64u << 20));     // [64,80M)
    bf16* ubuf    = (bf16*)(ws + (16u << 20));     // [16,80M) reuse after attn
    bf16* x2b     = (bf16*)(ws + (80u << 20));     // [80,96M)
    bf16* wattn_h = (bf16*)(ws + (112u << 20));
    bf16* wproj_h = (bf16*)(ws + (118u << 20));
    bf16* wfc_h   = (bf16*)(ws + (120u << 20));
    bf16* wfcp_h  = (bf16*)(ws + (128u << 20));

    // fused LN1 + all weight conversions (1 dispatch)
    // cvt float4 count: (3C*C + C*C + FF*C + C*FF)/4 = 3,145,728 -> 12288 blocks
    prep_kernel<<<M_TOK + 12288, 256, 0, stream>>>(
        x, ln1w, ln1b, ln_buf,
        w_attn, w_proj, w_fc, w_fcp,
        wattn_h, wproj_h, wfc_h, wfcp_h);

    // qk = ln_buf @ w_attn[0:2C]^T  (256^2 8-phase; Q columns pre-scaled)
    gemm256<5><<<dim3((M_TOK / 256) * (2 * C_ / 256)), 512, 0, stream>>>(
        ln_buf, wattn_h, qk_buf, M_TOK, 2 * C_, C_);

    // vt = w_v @ ln_buf^T  [1024, 8192]  (256x128 8-phase)
    gemm256x128<0><<<dim3((C_ / 256) * (M_TOK / 128)), 512, 0, stream>>>(
        wattn_h + (size_t)2 * C_ * C_, ln_buf, vt_buf, nullptr, C_, M_TOK, C_);

    // attention (64-row tiles, 1024 blocks)
    flash_attn<<<dim3(16, B_ * H_), 256, 0, stream>>>(qk_buf, vt_buf, ybuf);

    // x2b = bf16(x + ybuf @ w_proj^T)  (256x128 8-phase)
    gemm256x128<3><<<dim3((M_TOK / 256) * (C_ / 128)), 512, 0, stream>>>(
        ybuf, wproj_h, x2b, x, M_TOK, C_, C_);

    // LN2 (bf16 in)
    ln_kernel_b<<<M_TOK, 256, 0, stream>>>(x2b, ln2w, ln2b, ln_buf);

    // u = fgelu(ln_buf @ w_fc^T)  (256^2 8-phase)
    gemm256<2><<<dim3((M_TOK / 256) * (FF_ / 256)), 512, 0, stream>>>(
        ln_buf, wfc_h, ubuf, M_TOK, FF_, C_);

    // out = f32(x2b) + u @ w_fcp^T  (256x128 8-phase)
    gemm256x128<4><<<dim3((M_TOK / 256) * (C_ / 128)), 512, 0, stream>>>(
        ubuf, wfcp_h, out, x2b, M_TOK, C_, FF_);
}

// Round 12
// 349.454 us; speedup vs baseline: 26.8176x; 1.0156x over previous
//
#include <hip/hip_runtime.h>
#include <hip/hip_bf16.h>

using bf16 = __hip_bfloat16;
typedef __attribute__((ext_vector_type(8))) short short8;
typedef __attribute__((ext_vector_type(4))) short sh4;
typedef __attribute__((ext_vector_type(4))) float f32x4;

#define B_ 4
#define T_ 2048
#define C_ 1024
#define H_ 16
#define FF_ 4096
#define M_TOK (B_ * T_)   // 8192
#define SCALE2 0.1803368801111f   // 0.125 * log2(e)

#define BARRIER() asm volatile("s_barrier" ::: "memory")
#define WAITLGKM0() asm volatile("s_waitcnt lgkmcnt(0)" ::: "memory")
#define WAITLGKM8() asm volatile("s_waitcnt lgkmcnt(8)" ::: "memory")
#define WAITVM4() asm volatile("s_waitcnt vmcnt(4)" ::: "memory")
#define WAITVM2() asm volatile("s_waitcnt vmcnt(2)" ::: "memory")
#define WAITVM0() asm volatile("s_waitcnt vmcnt(0)" ::: "memory")

// ---------------- async global->LDS 16B ----------------
__device__ __forceinline__ void gload16(const void* g, void* l) {
    __builtin_amdgcn_global_load_lds(
        (const __attribute__((address_space(1))) void*)g,
        (__attribute__((address_space(3))) void*)l, 16, 0, 0);
}

// 2^x in one instruction
__device__ __forceinline__ float fexp2(float x) {
    float r;
    asm("v_exp_f32 %0, %1" : "=v"(r) : "v"(x));
    return r;
}

__device__ __forceinline__ float bf16bits2f(short s) {
    return __uint_as_float(((unsigned)(unsigned short)s) << 16);
}

// pack two f32 -> one dword of 2 bf16
__device__ __forceinline__ unsigned bf2(float a, float b) {
    bf16 x = __float2bfloat16(a), y = __float2bfloat16(b);
    unsigned short ux = *(unsigned short*)&x, uy = *(unsigned short*)&y;
    return (unsigned)ux | ((unsigned)uy << 16);
}

// fast gelu: x * t / (t + 1), t = exp(2 * 0.79788456(x + 0.044715 x^3))
__device__ __forceinline__ float fgelu(float x) {
    float y = 0.79788456f * (x + 0.044715f * x * x * x);
    float tv = fexp2(y * 2.885390082f);   // e^{2y} = 2^{2y*log2e}
    return x * tv * __builtin_amdgcn_rcpf(tv + 1.f);
}

// ---------------- fused prep: LN1 (blocks 0..8191) + weight cvt (rest) ----------------
__global__ __launch_bounds__(256) void prep_kernel(
    const float* __restrict__ x, const float* __restrict__ ln1w, const float* __restrict__ ln1b,
    bf16* __restrict__ ln_out,
    const float* __restrict__ w_attn, const float* __restrict__ w_proj,
    const float* __restrict__ w_fc, const float* __restrict__ w_fcp,
    bf16* __restrict__ wattn_h, bf16* __restrict__ wproj_h,
    bf16* __restrict__ wfc_h, bf16* __restrict__ wfcp_h) {
    const int bid = blockIdx.x;
    const int t = threadIdx.x;
    if (bid < M_TOK) {
        float4 v = ((const float4*)(x + (size_t)bid * C_))[t];
        float s = v.x + v.y + v.z + v.w;
        float s2 = v.x * v.x + v.y * v.y + v.z * v.z + v.w * v.w;
#pragma unroll
        for (int off = 32; off > 0; off >>= 1) {
            s += __shfl_down(s, off);
            s2 += __shfl_down(s2, off);
        }
        __shared__ float ss[4], ss2[4];
        int wave = t >> 6, lane = t & 63;
        if (lane == 0) { ss[wave] = s; ss2[wave] = s2; }
        __syncthreads();
        s = ss[0] + ss[1] + ss[2] + ss[3];
        s2 = ss2[0] + ss2[1] + ss2[2] + ss2[3];
        float mu = s * (1.f / C_);
        float var = s2 * (1.f / C_) - mu * mu;
        float rstd = rsqrtf(var + 1e-5f);
        float4 wv = ((const float4*)ln1w)[t];
        float4 bv = ((const float4*)ln1b)[t];
        uint2 o;
        o.x = bf2((v.x - mu) * rstd * wv.x + bv.x, (v.y - mu) * rstd * wv.y + bv.y);
        o.y = bf2((v.z - mu) * rstd * wv.z + bv.z, (v.w - mu) * rstd * wv.w + bv.w);
        ((uint2*)(ln_out + (size_t)bid * C_))[t] = o;
    } else {
        int i = (bid - M_TOK) * 256 + t;
        const float* src;
        bf16* dst;
        int base;
        if (i < 786432) {            // w_attn: 3C*C/4
            src = w_attn; dst = wattn_h; base = 0;
        } else if (i < 1048576) {    // w_proj: C*C/4
            src = w_proj; dst = wproj_h; base = 786432;
        } else if (i < 2097152) {    // w_fc: FF*C/4
            src = w_fc; dst = wfc_h; base = 1048576;
        } else {                     // w_fcp: C*FF/4
            src = w_fcp; dst = wfcp_h; base = 2097152;
        }
        int j = i - base;
        float4 v = ((const float4*)src)[j];
        uint2 o;
        o.x = bf2(v.x, v.y);
        o.y = bf2(v.z, v.w);
        ((uint2*)dst)[j] = o;
    }
}

// ---------------- LayerNorm (LN2): bf16 in -> bf16 out ----------------
__global__ __launch_bounds__(256) void ln_kernel_b(const bf16* __restrict__ x,
                                                   const float* __restrict__ w,
                                                   const float* __restrict__ b,
                                                   bf16* __restrict__ out) {
    int row = blockIdx.x;
    int t = threadIdx.x;
    sh4 h = ((const sh4*)(x + (size_t)row * C_))[t];
    float4 v;
    v.x = bf16bits2f(h[0]);
    v.y = bf16bits2f(h[1]);
    v.z = bf16bits2f(h[2]);
    v.w = bf16bits2f(h[3]);
    float s = v.x + v.y + v.z + v.w;
    float s2 = v.x * v.x + v.y * v.y + v.z * v.z + v.w * v.w;
#pragma unroll
    for (int off = 32; off > 0; off >>= 1) {
        s += __shfl_down(s, off);
        s2 += __shfl_down(s2, off);
    }
    __shared__ float ss[4], ss2[4];
    int wave = t >> 6, lane = t & 63;
    if (lane == 0) { ss[wave] = s; ss2[wave] = s2; }
    __syncthreads();
    s = ss[0] + ss[1] + ss[2] + ss[3];
    s2 = ss2[0] + ss2[1] + ss2[2] + ss2[3];
    float mu = s * (1.f / C_);
    float var = s2 * (1.f / C_) - mu * mu;
    float rstd = rsqrtf(var + 1e-5f);
    float4 wv = ((const float4*)w)[t];
    float4 bv = ((const float4*)b)[t];
    uint2 o;
    o.x = bf2((v.x - mu) * rstd * wv.x + bv.x, (v.y - mu) * rstd * wv.y + bv.y);
    o.y = bf2((v.z - mu) * rstd * wv.z + bv.z, (v.w - mu) * rstd * wv.w + bv.w);
    ((uint2*)(out + (size_t)row * C_))[t] = o;
}

// ======== shared staging macro ========
#define STG(ldsbase, g, grow0, k0)                                               \
    {                                                                            \
        _Pragma("unroll") for (int s_ = 0; s_ < 2; s_++) {                       \
            int row_ = s_ * 64 + wid * 8 + sr;                                   \
            gload16(g + (size_t)((grow0) + row_) * K + (k0) + ssc,               \
                    (ldsbase) + row_ * 64 + (lane & 7) * 8);                     \
        }                                                                        \
    }

// ---------------- 256x256 8-phase NT GEMM (T2+T3+T4+T5) ----------------
#define HALF256 (128 * 64)
template <int EPI>
__global__ __launch_bounds__(512, 2) void gemm256(const bf16* __restrict__ Ag,
                                                  const bf16* __restrict__ Bg,
                                                  void* __restrict__ Cout,
                                                  int M, int N, int K) {
    __shared__ short SA[2][256 * 64];
    __shared__ short SB[2][256 * 64];

    const int nbx = N >> 8;
    const int nwg = nbx * (M >> 8);
    const int bid = blockIdx.x;
    const int cpx = nwg >> 3;
    const int swzb = (bid & 7) * cpx + (bid >> 3);
    const int m0 = (swzb / nbx) * 256;
    const int n0 = (swzb % nbx) * 256;

    const int t = threadIdx.x;
    const int wid = t >> 6, lane = t & 63;
    const int wm = wid >> 2, wn = wid & 3;
    const int lrow = lane & 15, lg = lane >> 4;
    const int swzr = (lane & 7) * 8;
    const int sr = lane >> 3;
    const int ssc = ((lane & 7) ^ sr) * 8;

    f32x4 acc[8][4];
#pragma unroll
    for (int mi = 0; mi < 8; mi++)
#pragma unroll
        for (int ni = 0; ni < 4; ni++) acc[mi][ni] = (f32x4){0.f, 0.f, 0.f, 0.f};
    short8 bfr[4][2];

    const int T = K >> 6;
    const int niter = T >> 1;

#define DSREADS256(q, buf)                                                       \
    if ((q) == 0) {                                                              \
        _Pragma("unroll") for (int ni = 0; ni < 4; ni++)                         \
        _Pragma("unroll") for (int ks = 0; ks < 2; ks++)                         \
            bfr[ni][ks] = *(const short8*)(&SB[buf][(wn * 64 + ni * 16 + lrow) * 64 + \
                                                    ((ks * 32 + lg * 8) ^ swzr)]);    \
    }                                                                            \
    _Pragma("unroll") for (int mi2 = 0; mi2 < 2; mi2++)                          \
    _Pragma("unroll") for (int ks = 0; ks < 2; ks++)                             \
        af[mi2 * 2 + ks] = *(const short8*)(&SA[buf][(wm * 128 + (2 * (q) + mi2) * 16 + lrow) * 64 + \
                                                     ((ks * 32 + lg * 8) ^ swzr)]);

#define MFMAS256(q)                                                              \
    __builtin_amdgcn_s_setprio(1);                                               \
    _Pragma("unroll") for (int ks = 0; ks < 2; ks++)                             \
    _Pragma("unroll") for (int ni = 0; ni < 4; ni++)                             \
    _Pragma("unroll") for (int mi2 = 0; mi2 < 2; mi2++)                          \
        acc[2 * (q) + mi2][ni] = __builtin_amdgcn_mfma_f32_16x16x32_bf16(        \
            bfr[ni][ks], af[mi2 * 2 + ks], acc[2 * (q) + mi2][ni], 0, 0, 0);     \
    __builtin_amdgcn_s_setprio(0);

    STG(&SA[0][0], Ag, m0, 0);
    STG(&SA[0][HALF256], Ag, m0 + 128, 0);
    STG(&SB[0][0], Bg, n0, 0);
    STG(&SB[0][HALF256], Bg, n0 + 128, 0);
    STG(&SB[1][0], Bg, n0, 64);
    STG(&SB[1][HALF256], Bg, n0 + 128, 64);
    WAITVM4();
    BARRIER();

    for (int iter = 0; iter < niter; iter++) {
        const int tt = 2 * iter;
        const int ka = (tt + 1) * 64, kb = (tt + 2) * 64, kc = (tt + 3) * 64;
        const bool s2 = (tt + 2 < T), s3 = (tt + 3 < T);
        const bool last = (iter == niter - 1);
        short8 af[4];

        DSREADS256(0, 0);
        STG(&SA[1][0], Ag, m0, ka);
        WAITLGKM8();
        BARRIER(); WAITLGKM0(); MFMAS256(0); BARRIER();
        DSREADS256(1, 0);
        STG(&SA[1][HALF256], Ag, m0 + 128, ka);
        BARRIER(); WAITLGKM0(); MFMAS256(1); BARRIER();
        DSREADS256(2, 0);
        if (s2) STG(&SB[0][0], Bg, n0, kb);
        BARRIER(); WAITLGKM0(); MFMAS256(2); BARRIER();
        DSREADS256(3, 0);
        if (s2) STG(&SB[0][HALF256], Bg, n0 + 128, kb);
        BARRIER(); WAITLGKM0(); MFMAS256(3);
        if (last) { WAITVM0(); } else { WAITVM4(); }
        BARRIER();
        DSREADS256(0, 1);
        if (s2) STG(&SA[0][0], Ag, m0, kb);
        WAITLGKM8();
        BARRIER(); WAITLGKM0(); MFMAS256(0); BARRIER();
        DSREADS256(1, 1);
        if (s2) STG(&SA[0][HALF256], Ag, m0 + 128, kb);
        BARRIER(); WAITLGKM0(); MFMAS256(1); BARRIER();
        DSREADS256(2, 1);
        if (s3) STG(&SB[1][0], Bg, n0, kc);
        BARRIER(); WAITLGKM0(); MFMAS256(2); BARRIER();
        DSREADS256(3, 1);
        if (s3) STG(&SB[1][HALF256], Bg, n0 + 128, kc);
        BARRIER(); WAITLGKM0(); MFMAS256(3);
        if (!last) WAITVM4();
        BARRIER();
    }

#pragma unroll
    for (int mi = 0; mi < 8; mi++) {
        const int gm = m0 + wm * 128 + mi * 16 + lrow;
#pragma unroll
        for (int ni = 0; ni < 4; ni++) {
            const int gn = n0 + wn * 64 + ni * 16 + lg * 4;
            size_t gi = (size_t)gm * N + gn;
            f32x4 a = acc[mi][ni];
            if constexpr (EPI == 0) {
                uint2 o; o.x = bf2(a[0], a[1]); o.y = bf2(a[2], a[3]);
                *(uint2*)&(((bf16*)Cout)[gi]) = o;
            } else if constexpr (EPI == 5) {
                float sc = (gn < C_) ? SCALE2 : 1.f;
                uint2 o; o.x = bf2(a[0] * sc, a[1] * sc); o.y = bf2(a[2] * sc, a[3] * sc);
                *(uint2*)&(((bf16*)Cout)[gi]) = o;
            } else {
                uint2 o;
                o.x = bf2(fgelu(a[0]), fgelu(a[1]));
                o.y = bf2(fgelu(a[2]), fgelu(a[3]));
                *(uint2*)&(((bf16*)Cout)[gi]) = o;
            }
        }
    }
}

// ---------------- 256x128 8-phase NT GEMM (N=1024-class shapes) ----------------
template <int EPI>
__global__ __launch_bounds__(512, 2) void gemm256x128(const bf16* __restrict__ Ag,
                                                      const bf16* __restrict__ Bg,
                                                      void* __restrict__ Cout,
                                                      const void* __restrict__ Res,
                                                      int M, int N, int K) {
    __shared__ short SA[2][256 * 64];
    __shared__ short SB[2][128 * 64];

    const int nbx = N >> 7;
    const int nwg = nbx * (M >> 8);
    const int bid = blockIdx.x;
    const int cpx = nwg >> 3;
    const int swzb = (bid & 7) * cpx + (bid >> 3);
    const int m0 = (swzb / nbx) * 256;
    const int n0 = (swzb % nbx) * 128;

    const int t = threadIdx.x;
    const int wid = t >> 6, lane = t & 63;
    const int wm = wid >> 1, wn = wid & 1;
    const int lrow = lane & 15, lg = lane >> 4;
    const int swzr = (lane & 7) * 8;
    const int sr = lane >> 3;
    const int ssc = ((lane & 7) ^ sr) * 8;

    f32x4 acc[4][4];
#pragma unroll
    for (int mi = 0; mi < 4; mi++)
#pragma unroll
        for (int ni = 0; ni < 4; ni++) acc[mi][ni] = (f32x4){0.f, 0.f, 0.f, 0.f};
    short8 bfr[4][2];

    const int T = K >> 6;
    const int niter = T >> 1;

#define DSRX(p, buf)                                                             \
    if ((p) == 0) {                                                              \
        _Pragma("unroll") for (int ni = 0; ni < 4; ni++)                         \
        _Pragma("unroll") for (int ks = 0; ks < 2; ks++)                         \
            bfr[ni][ks] = *(const short8*)(&SB[buf][(wn * 64 + ni * 16 + lrow) * 64 + \
                                                    ((ks * 32 + lg * 8) ^ swzr)]);    \
    }                                                                            \
    _Pragma("unroll") for (int mi2 = 0; mi2 < 2; mi2++)                          \
    _Pragma("unroll") for (int ks = 0; ks < 2; ks++)                             \
        af[mi2 * 2 + ks] = *(const short8*)(&SA[buf][(wm * 64 + (2 * (p) + mi2) * 16 + lrow) * 64 + \
                                                     ((ks * 32 + lg * 8) ^ swzr)]);

#define MFX(p)                                                                   \
    __builtin_amdgcn_s_setprio(1);                                               \
    _Pragma("unroll") for (int ks = 0; ks < 2; ks++)                             \
    _Pragma("unroll") for (int ni = 0; ni < 4; ni++)                             \
    _Pragma("unroll") for (int mi2 = 0; mi2 < 2; mi2++)                          \
        acc[2 * (p) + mi2][ni] = __builtin_amdgcn_mfma_f32_16x16x32_bf16(        \
            bfr[ni][ks], af[mi2 * 2 + ks], acc[2 * (p) + mi2][ni], 0, 0, 0);     \
    __builtin_amdgcn_s_setprio(0);

    STG(&SA[0][0], Ag, m0, 0);
    STG(&SA[0][HALF256], Ag, m0 + 128, 0);
    STG(&SB[0][0], Bg, n0, 0);
    STG(&SB[1][0], Bg, n0, 64);
    WAITVM2();
    BARRIER();

    for (int iter = 0; iter < niter; iter++) {
        const int tt = 2 * iter;
        const int ka = (tt + 1) * 64, kb = (tt + 2) * 64, kc = (tt + 3) * 64;
        const bool s2 = (tt + 2 < T), s3 = (tt + 3 < T);
        const bool last = (iter == niter - 1);
        short8 af[4];

        DSRX(0, 0);
        STG(&SA[1][0], Ag, m0, ka);
        STG(&SA[1][HALF256], Ag, m0 + 128, ka);
        WAITLGKM8();
        BARRIER(); WAITLGKM0(); MFX(0); BARRIER();
        DSRX(1, 0);
        if (s2) STG(&SB[0][0], Bg, n0, kb);
        BARRIER(); WAITLGKM0(); MFX(1);
        if (last) { WAITVM0(); } else { WAITVM2(); }
        BARRIER();
        DSRX(0, 1);
        if (s2) {
            STG(&SA[0][0], Ag, m0, kb);
            STG(&SA[0][HALF256], Ag, m0 + 128, kb);
        }
        WAITLGKM8();
        BARRIER(); WAITLGKM0(); MFX(0); BARRIER();
        DSRX(1, 1);
        if (s3) STG(&SB[1][0], Bg, n0, kc);
        BARRIER(); WAITLGKM0(); MFX(1);
        if (last) { WAITVM0(); } else { WAITVM2(); }
        BARRIER();
    }

#pragma unroll
    for (int mi = 0; mi < 4; mi++) {
        const int gm = m0 + wm * 64 + mi * 16 + lrow;
#pragma unroll
        for (int ni = 0; ni < 4; ni++) {
            const int gn = n0 + wn * 64 + ni * 16 + lg * 4;
            size_t gi = (size_t)gm * N + gn;
            f32x4 a = acc[mi][ni];
            if constexpr (EPI == 0) {
                uint2 o; o.x = bf2(a[0], a[1]); o.y = bf2(a[2], a[3]);
                *(uint2*)&(((bf16*)Cout)[gi]) = o;
            } else if constexpr (EPI == 3) {
                float4 rv = *(const float4*)&(((const float*)Res)[gi]);
                uint2 o; o.x = bf2(rv.x + a[0], rv.y + a[1]); o.y = bf2(rv.z + a[2], rv.w + a[3]);
                *(uint2*)&(((bf16*)Cout)[gi]) = o;
            } else {
                sh4 hv = *(const sh4*)&(((const bf16*)Res)[gi]);
                float4 o;
                o.x = bf16bits2f(hv[0]) + a[0];
                o.y = bf16bits2f(hv[1]) + a[1];
                o.z = bf16bits2f(hv[2]) + a[2];
                o.w = bf16bits2f(hv[3]) + a[3];
                *(float4*)&(((float*)Cout)[gi]) = o;
            }
        }
    }
}

// ---------------- MFMA flash attention: paired q-tiles share staged K/V ----------------
// grid (bh, pi): XCD = linear%8 = bh%8 -> all pi-blocks of a bh on one XCD (K/V L2-resident).
// Block processes q-tiles ql=pi and qh=31-pi in ONE kv loop; K/V staged once per kv tile.
__global__ __launch_bounds__(256, 4) void flash_attn(const bf16* __restrict__ qk,
                                                     const bf16* __restrict__ vt,
                                                     bf16* __restrict__ y) {
    const int bh = blockIdx.x;
    const int pi = blockIdx.y;
    const int b = bh >> 4, h = bh & 15;
    const int t = threadIdx.x;
    const int wave = t >> 6, lane = t & 63;
    const int lrow = lane & 15, lg = lane >> 4, lk = lg * 8;

    __shared__ alignas(16) short Ks[64 * 72];
    __shared__ alignas(16) short Vs[64 * 72];
    __shared__ alignas(16) short Ps[64 * 72];

    const size_t rs = 2 * C_;
    const bf16* Qg = qk + (size_t)b * T_ * rs + h * 64;
    const bf16* Kg = Qg + C_;
    const bf16* Vg = vt + (size_t)(h * 64) * M_TOK + b * T_;

    const int srow = t >> 3;
    const int sc8 = (t & 7) * 8;

    const int ql = pi, qh = 31 - pi;
    const int nkt = qh + 1;
    const int qgH = qh * 64 + wave * 16 + lrow;
    const int qgL = ql * 64 + wave * 16 + lrow;

    short8 qfH[2], qfL[2];
    {
        const bf16* qr = Qg + (size_t)qgH * rs;
        qfH[0] = *(const short8*)(qr + lk);
        qfH[1] = *(const short8*)(qr + 32 + lk);
        qr = Qg + (size_t)qgL * rs;
        qfL[0] = *(const short8*)(qr + lk);
        qfL[1] = *(const short8*)(qr + 32 + lk);
    }

    f32x4 oH[4], oL[4];
    float mH = -1e30f, lH = 0.f, mL = -1e30f, lL = 0.f;
#pragma unroll
    for (int ni = 0; ni < 4; ni++) {
        oH[ni] = (f32x4){0.f, 0.f, 0.f, 0.f};
        oL[ni] = (f32x4){0.f, 0.f, 0.f, 0.f};
    }

    short8 kr[2], vr[2];
#pragma unroll
    for (int p = 0; p < 2; p++) {
        int r = srow + p * 32;
        kr[p] = *(const short8*)(Kg + (size_t)r * rs + sc8);
        vr[p] = *(const short8*)(Vg + (size_t)r * M_TOK + sc8);
    }

    for (int kt = 0; kt < nkt; kt++) {
        const int s0 = kt * 64;
#pragma unroll
        for (int p = 0; p < 2; p++) {
            int r = srow + p * 32;
            *(short8*)(&Ks[r * 72 + sc8]) = kr[p];
            *(short8*)(&Vs[r * 72 + sc8]) = vr[p];
        }
        __syncthreads();
        if (kt + 1 < nkt) {
            const int s0n = (kt + 1) * 64;
#pragma unroll
            for (int p = 0; p < 2; p++) {
                int r = srow + p * 32;
                kr[p] = *(const short8*)(Kg + (size_t)(s0n + r) * rs + sc8);
                vr[p] = *(const short8*)(Vg + (size_t)r * M_TOK + s0n + sc8);
            }
        }

        // ======== HEAVY tile ========
        {
            f32x4 s[4];
#pragma unroll
            for (int ni = 0; ni < 4; ni++) s[ni] = (f32x4){0.f, 0.f, 0.f, 0.f};
            __builtin_amdgcn_s_setprio(1);
#pragma unroll
            for (int ks = 0; ks < 2; ks++)
#pragma unroll
                for (int ni = 0; ni < 4; ni++) {
                    short8 kf = *(const short8*)(&Ks[(ni * 16 + lrow) * 72 + ks * 32 + lk]);
                    s[ni] = __builtin_amdgcn_mfma_f32_16x16x32_bf16(kf, qfH[ks], s[ni], 0, 0, 0);
                }
            __builtin_amdgcn_s_setprio(0);

            if (kt == qh) {
#pragma unroll
                for (int ni = 0; ni < 4; ni++)
#pragma unroll
                    for (int r = 0; r < 4; r++) {
                        int kvg = s0 + ni * 16 + lg * 4 + r;
                        if (kvg > qgH) s[ni][r] = -1e30f;
                    }
            }

            float pm = s[0][0];
#pragma unroll
            for (int ni = 0; ni < 4; ni++)
#pragma unroll
                for (int r = 0; r < 4; r++) pm = fmaxf(pm, s[ni][r]);
            pm = fmaxf(pm, __shfl_xor(pm, 16));
            pm = fmaxf(pm, __shfl_xor(pm, 32));
            if (!__all(pm - mH <= 8.f)) {
                float mn = fmaxf(mH, pm);
                float alpha = fexp2(mH - mn);
                mH = mn;
                lH *= alpha;
#pragma unroll
                for (int ni = 0; ni < 4; ni++)
#pragma unroll
                    for (int r = 0; r < 4; r++) oH[ni][r] *= alpha;
            }
            float rsum = 0.f;
#pragma unroll
            for (int ni = 0; ni < 4; ni++) {
                float p0 = fexp2(s[ni][0] - mH);
                float p1 = fexp2(s[ni][1] - mH);
                float p2 = fexp2(s[ni][2] - mH);
                float p3 = fexp2(s[ni][3] - mH);
                rsum += (p0 + p1) + (p2 + p3);
                uint2 pk; pk.x = bf2(p0, p1); pk.y = bf2(p2, p3);
                *(uint2*)(&Ps[(wave * 16 + lrow) * 72 + ni * 16 + lg * 4]) = pk;
            }
            rsum += __shfl_xor(rsum, 16);
            rsum += __shfl_xor(rsum, 32);
            lH += rsum;

            __builtin_amdgcn_s_setprio(1);
#pragma unroll
            for (int ks2 = 0; ks2 < 2; ks2++) {
                short8 pf = *(const short8*)(&Ps[(wave * 16 + lrow) * 72 + ks2 * 32 + lk]);
#pragma unroll
                for (int ni = 0; ni < 4; ni++) {
                    short8 vf = *(const short8*)(&Vs[(ni * 16 + lrow) * 72 + ks2 * 32 + lk]);
                    oH[ni] = __builtin_amdgcn_mfma_f32_16x16x32_bf16(vf, pf, oH[ni], 0, 0, 0);
                }
            }
            __builtin_amdgcn_s_setprio(0);
        }

        // ======== LIGHT tile (shares staged K/V) ========
        if (kt <= ql) {
            f32x4 s[4];
#pragma unroll
            for (int ni = 0; ni < 4; ni++) s[ni] = (f32x4){0.f, 0.f, 0.f, 0.f};
            __builtin_amdgcn_s_setprio(1);
#pragma unroll
            for (int ks = 0; ks < 2; ks++)
#pragma unroll
                for (int ni = 0; ni < 4; ni++) {
                    short8 kf = *(const short8*)(&Ks[(ni * 16 + lrow) * 72 + ks * 32 + lk]);
                    s[ni] = __builtin_amdgcn_mfma_f32_16x16x32_bf16(kf, qfL[ks], s[ni], 0, 0, 0);
                }
            __builtin_amdgcn_s_setprio(0);

            if (kt == ql) {
#pragma unroll
                for (int ni = 0; ni < 4; ni++)
#pragma unroll
                    for (int r = 0; r < 4; r++) {
                        int kvg = s0 + ni * 16 + lg * 4 + r;
                        if (kvg > qgL) s[ni][r] = -1e30f;
                    }
            }

            float pm = s[0][0];
#pragma unroll
            for (int ni = 0; ni < 4; ni++)
#pragma unroll
                for (int r = 0; r < 4; r++) pm = fmaxf(pm, s[ni][r]);
            pm = fmaxf(pm, __shfl_xor(pm, 16));
            pm = fmaxf(pm, __shfl_xor(pm, 32));
            if (!__all(pm - mL <= 8.f)) {
                float mn = fmaxf(mL, pm);
                float alpha = fexp2(mL - mn);
                mL = mn;
                lL *= alpha;
#pragma unroll
                for (int ni = 0; ni < 4; ni++)
#pragma unroll
                    for (int r = 0; r < 4; r++) oL[ni][r] *= alpha;
            }
            float rsum = 0.f;
#pragma unroll
            for (int ni = 0; ni < 4; ni++) {
                float p0 = fexp2(s[ni][0] - mL);
                float p1 = fexp2(s[ni][1] - mL);
                float p2 = fexp2(s[ni][2] - mL);
                float p3 = fexp2(s[ni][3] - mL);
                rsum += (p0 + p1) + (p2 + p3);
                uint2 pk; pk.x = bf2(p0, p1); pk.y = bf2(p2, p3);
                *(uint2*)(&Ps[(wave * 16 + lrow) * 72 + ni * 16 + lg * 4]) = pk;
            }
            rsum += __shfl_xor(rsum, 16);
            rsum += __shfl_xor(rsum, 32);
            lL += rsum;

            __builtin_amdgcn_s_setprio(1);
#pragma unroll
            for (int ks2 = 0; ks2 < 2; ks2++) {
                short8 pf = *(const short8*)(&Ps[(wave * 16 + lrow) * 72 + ks2 * 32 + lk]);
#pragma unroll
                for (int ni = 0; ni < 4; ni++) {
                    short8 vf = *(const short8*)(&Vs[(ni * 16 + lrow) * 72 + ks2 * 32 + lk]);
                    oL[ni] = __builtin_amdgcn_mfma_f32_16x16x32_bf16(vf, pf, oL[ni], 0, 0, 0);
                }
            }
            __builtin_amdgcn_s_setprio(0);
        }
        __syncthreads();
    }

    // ---- write both outputs ----
    float invH = 1.f / lH, invL = 1.f / lL;
#pragma unroll
    for (int ni = 0; ni < 4; ni++) {
        uint2 pk;
        pk.x = bf2(oH[ni][0] * invH, oH[ni][1] * invH);
        pk.y = bf2(oH[ni][2] * invH, oH[ni][3] * invH);
        *(uint2*)(&y[((size_t)(b * T_ + qgH)) * C_ + h * 64 + ni * 16 + lg * 4]) = pk;
        pk.x = bf2(oL[ni][0] * invL, oL[ni][1] * invL);
        pk.y = bf2(oL[ni][2] * invL, oL[ni][3] * invL);
        *(uint2*)(&y[((size_t)(b * T_ + qgL)) * C_ + h * 64 + ni * 16 + lg * 4]) = pk;
    }
}

// ---------------- launch ----------------
extern "C" void kernel_launch(void* const* d_in, const int* in_sizes, int n_in,
                              void* d_out, int out_size, void* d_ws, size_t ws_size,
                              hipStream_t stream) {
    const float* x      = (const float*)d_in[0];
    const float* ln1w   = (const float*)d_in[1];
    const float* ln1b   = (const float*)d_in[2];
    const float* ln2w   = (const float*)d_in[3];
    const float* ln2b   = (const float*)d_in[4];
    const float* w_attn = (const float*)d_in[5];
    const float* w_proj = (const float*)d_in[6];
    const float* w_fc   = (const float*)d_in[7];
    const float* w_fcp  = (const float*)d_in[8];
    float* out = (float*)d_out;

    char* ws = (char*)d_ws;
    bf16* ln_buf  = (bf16*)(ws);                   // [0,16M)
    bf16* qk_buf  = (bf16*)(ws + (16u << 20));     // [16,48M)
    bf16* vt_buf  = (bf16*)(ws + (48u << 20));     // [48,64M)
    bf16* ybuf    = (bf16*)(ws + (64u << 20));     // [64,80M)
    bf16* ubuf    = (bf16*)(ws + (16u << 20));     // [16,80M) reuse after attn
    bf16* x2b     = (bf16*)(ws + (80u << 20));     // [80,96M)
    bf16* wattn_h = (bf16*)(ws + (112u << 20));
    bf16* wproj_h = (bf16*)(ws + (118u << 20));
    bf16* wfc_h   = (bf16*)(ws + (120u << 20));
    bf16* wfcp_h  = (bf16*)(ws + (128u << 20));

    // fused LN1 + all weight conversions (1 dispatch)
    prep_kernel<<<M_TOK + 12288, 256, 0, stream>>>(
        x, ln1w, ln1b, ln_buf,
        w_attn, w_proj, w_fc, w_fcp,
        wattn_h, wproj_h, wfc_h, wfcp_h);

    // qk = ln_buf @ w_attn[0:2C]^T  (256^2 8-phase; Q columns pre-scaled)
    gemm256<5><<<dim3((M_TOK / 256) * (2 * C_ / 256)), 512, 0, stream>>>(
        ln_buf, wattn_h, qk_buf, M_TOK, 2 * C_, C_);

    // vt = w_v @ ln_buf^T  [1024, 8192]  (256x128 8-phase)
    gemm256x128<0><<<dim3((C_ / 256) * (M_TOK / 128)), 512, 0, stream>>>(
        wattn_h + (size_t)2 * C_ * C_, ln_buf, vt_buf, nullptr, C_, M_TOK, C_);

    // attention: grid (bh, pi) for XCD K/V locality; paired tiles share staging
    flash_attn<<<dim3(B_ * H_, 16), 256, 0, stream>>>(qk_buf, vt_buf, ybuf);

    // x2b = bf16(x + ybuf @ w_proj^T)  (256x128 8-phase)
    gemm256x128<3><<<dim3((M_TOK / 256) * (C_ / 128)), 512, 0, stream>>>(
        ybuf, wproj_h, x2b, x, M_TOK, C_, C_);

    // LN2 (bf16 in)
    ln_kernel_b<<<M_TOK, 256, 0, stream>>>(x2b, ln2w, ln2b, ln_buf);

    // u = fgelu(ln_buf @ w_fc^T)  (256^2 8-phase)
    gemm256<2><<<dim3((M_TOK / 256) * (FF_ / 256)), 512, 0, stream>>>(
        ln_buf, wfc_h, ubuf, M_TOK, FF_, C_);

    // out = f32(x2b) + u @ w_fcp^T  (256x128 8-phase)
    gemm256x128<4><<<dim3((M_TOK / 256) * (C_ / 128)), 512, 0, stream>>>(
        ubuf, wfcp_h, out, x2b, M_TOK, C_, FF_);
}

// Round 13
// 333.367 us; speedup vs baseline: 28.1118x; 1.0483x over previous
//
#include <hip/hip_runtime.h>
#include <hip/hip_bf16.h>

using bf16 = __hip_bfloat16;
typedef __attribute__((ext_vector_type(8))) short short8;
typedef __attribute__((ext_vector_type(4))) short sh4;
typedef __attribute__((ext_vector_type(4))) float f32x4;

#define B_ 4
#define T_ 2048
#define C_ 1024
#define H_ 16
#define FF_ 4096
#define M_TOK (B_ * T_)   // 8192
#define SCALE2 0.1803368801111f   // 0.125 * log2(e)

#define BARRIER() asm volatile("s_barrier" ::: "memory")
#define WAITLGKM0() asm volatile("s_waitcnt lgkmcnt(0)" ::: "memory")
#define WAITLGKM8() asm volatile("s_waitcnt lgkmcnt(8)" ::: "memory")
#define WAITVM4() asm volatile("s_waitcnt vmcnt(4)" ::: "memory")
#define WAITVM2() asm volatile("s_waitcnt vmcnt(2)" ::: "memory")
#define WAITVM0() asm volatile("s_waitcnt vmcnt(0)" ::: "memory")

#define SAE (256 * 64)
#define SBE256 (256 * 64)
#define SBE128 (128 * 64)
#define HALF256 (128 * 64)

// ---------------- async global->LDS 16B ----------------
__device__ __forceinline__ void gload16(const void* g, void* l) {
    __builtin_amdgcn_global_load_lds(
        (const __attribute__((address_space(1))) void*)g,
        (__attribute__((address_space(3))) void*)l, 16, 0, 0);
}

// 2^x in one instruction
__device__ __forceinline__ float fexp2(float x) {
    float r;
    asm("v_exp_f32 %0, %1" : "=v"(r) : "v"(x));
    return r;
}

__device__ __forceinline__ float bf16bits2f(short s) {
    return __uint_as_float(((unsigned)(unsigned short)s) << 16);
}

// pack two f32 -> one dword of 2 bf16
__device__ __forceinline__ unsigned bf2(float a, float b) {
    bf16 x = __float2bfloat16(a), y = __float2bfloat16(b);
    unsigned short ux = *(unsigned short*)&x, uy = *(unsigned short*)&y;
    return (unsigned)ux | ((unsigned)uy << 16);
}

// fast gelu: x * t / (t + 1), t = exp(2 * 0.79788456(x + 0.044715 x^3))
__device__ __forceinline__ float fgelu(float x) {
    float y = 0.79788456f * (x + 0.044715f * x * x * x);
    float tv = fexp2(y * 2.885390082f);
    return x * tv * __builtin_amdgcn_rcpf(tv + 1.f);
}

// ---------------- fused prep: LN1 (blocks 0..8191) + weight cvt (rest) ----------------
__global__ __launch_bounds__(256) void prep_kernel(
    const float* __restrict__ x, const float* __restrict__ ln1w, const float* __restrict__ ln1b,
    bf16* __restrict__ ln_out,
    const float* __restrict__ w_attn, const float* __restrict__ w_proj,
    const float* __restrict__ w_fc, const float* __restrict__ w_fcp,
    bf16* __restrict__ wattn_h, bf16* __restrict__ wproj_h,
    bf16* __restrict__ wfc_h, bf16* __restrict__ wfcp_h) {
    const int bid = blockIdx.x;
    const int t = threadIdx.x;
    if (bid < M_TOK) {
        float4 v = ((const float4*)(x + (size_t)bid * C_))[t];
        float s = v.x + v.y + v.z + v.w;
        float s2 = v.x * v.x + v.y * v.y + v.z * v.z + v.w * v.w;
#pragma unroll
        for (int off = 32; off > 0; off >>= 1) {
            s += __shfl_down(s, off);
            s2 += __shfl_down(s2, off);
        }
        __shared__ float ss[4], ss2[4];
        int wave = t >> 6, lane = t & 63;
        if (lane == 0) { ss[wave] = s; ss2[wave] = s2; }
        __syncthreads();
        s = ss[0] + ss[1] + ss[2] + ss[3];
        s2 = ss2[0] + ss2[1] + ss2[2] + ss2[3];
        float mu = s * (1.f / C_);
        float var = s2 * (1.f / C_) - mu * mu;
        float rstd = rsqrtf(var + 1e-5f);
        float4 wv = ((const float4*)ln1w)[t];
        float4 bv = ((const float4*)ln1b)[t];
        uint2 o;
        o.x = bf2((v.x - mu) * rstd * wv.x + bv.x, (v.y - mu) * rstd * wv.y + bv.y);
        o.y = bf2((v.z - mu) * rstd * wv.z + bv.z, (v.w - mu) * rstd * wv.w + bv.w);
        ((uint2*)(ln_out + (size_t)bid * C_))[t] = o;
    } else {
        int i = (bid - M_TOK) * 256 + t;
        const float* src;
        bf16* dst;
        int base;
        if (i < 786432) {            // w_attn: 3C*C/4
            src = w_attn; dst = wattn_h; base = 0;
        } else if (i < 1048576) {    // w_proj
            src = w_proj; dst = wproj_h; base = 786432;
        } else if (i < 2097152) {    // w_fc
            src = w_fc; dst = wfc_h; base = 1048576;
        } else {                     // w_fcp
            src = w_fcp; dst = wfcp_h; base = 2097152;
        }
        int j = i - base;
        float4 v = ((const float4*)src)[j];
        uint2 o;
        o.x = bf2(v.x, v.y);
        o.y = bf2(v.z, v.w);
        ((uint2*)dst)[j] = o;
    }
}

// ---------------- LayerNorm (LN2): bf16 in -> bf16 out ----------------
__global__ __launch_bounds__(256) void ln_kernel_b(const bf16* __restrict__ x,
                                                   const float* __restrict__ w,
                                                   const float* __restrict__ b,
                                                   bf16* __restrict__ out) {
    int row = blockIdx.x;
    int t = threadIdx.x;
    sh4 h = ((const sh4*)(x + (size_t)row * C_))[t];
    float4 v;
    v.x = bf16bits2f(h[0]);
    v.y = bf16bits2f(h[1]);
    v.z = bf16bits2f(h[2]);
    v.w = bf16bits2f(h[3]);
    float s = v.x + v.y + v.z + v.w;
    float s2 = v.x * v.x + v.y * v.y + v.z * v.z + v.w * v.w;
#pragma unroll
    for (int off = 32; off > 0; off >>= 1) {
        s += __shfl_down(s, off);
        s2 += __shfl_down(s2, off);
    }
    __shared__ float ss[4], ss2[4];
    int wave = t >> 6, lane = t & 63;
    if (lane == 0) { ss[wave] = s; ss2[wave] = s2; }
    __syncthreads();
    s = ss[0] + ss[1] + ss[2] + ss[3];
    s2 = ss2[0] + ss2[1] + ss2[2] + ss2[3];
    float mu = s * (1.f / C_);
    float var = s2 * (1.f / C_) - mu * mu;
    float rstd = rsqrtf(var + 1e-5f);
    float4 wv = ((const float4*)w)[t];
    float4 bv = ((const float4*)b)[t];
    uint2 o;
    o.x = bf2((v.x - mu) * rstd * wv.x + bv.x, (v.y - mu) * rstd * wv.y + bv.y);
    o.y = bf2((v.z - mu) * rstd * wv.z + bv.z, (v.w - mu) * rstd * wv.w + bv.w);
    ((uint2*)(out + (size_t)row * C_))[t] = o;
}

// ======== shared staging macro ========
#define STG(ldsbase, g, grow0, k0)                                               \
    {                                                                            \
        _Pragma("unroll") for (int s_ = 0; s_ < 2; s_++) {                       \
            int row_ = s_ * 64 + wid * 8 + sr;                                   \
            gload16(g + (size_t)((grow0) + row_) * K + (k0) + ssc,               \
                    (ldsbase) + row_ * 64 + (lane & 7) * 8);                     \
        }                                                                        \
    }

// ---------------- 256x256 8-phase NT GEMM body ----------------
// EPI 0: bf16  EPI 2: bf16 fgelu  EPI 5: bf16, cols<C_ scaled by SCALE2
template <int EPI>
__device__ __forceinline__ void gemm256_dev(short* SAp, short* SBp, int bid,
                                            const bf16* __restrict__ Ag,
                                            const bf16* __restrict__ Bg,
                                            void* __restrict__ Cout,
                                            int M, int N, int K) {
    const int nbx = N >> 8;
    const int nwg = nbx * (M >> 8);
    const int cpx = nwg >> 3;
    const int swzb = (bid & 7) * cpx + (bid >> 3);
    const int m0 = (swzb / nbx) * 256;
    const int n0 = (swzb % nbx) * 256;

    const int t = threadIdx.x;
    const int wid = t >> 6, lane = t & 63;
    const int wm = wid >> 2, wn = wid & 3;
    const int lrow = lane & 15, lg = lane >> 4;
    const int swzr = (lane & 7) * 8;
    const int sr = lane >> 3;
    const int ssc = ((lane & 7) ^ sr) * 8;

    f32x4 acc[8][4];
#pragma unroll
    for (int mi = 0; mi < 8; mi++)
#pragma unroll
        for (int ni = 0; ni < 4; ni++) acc[mi][ni] = (f32x4){0.f, 0.f, 0.f, 0.f};
    short8 bfr[4][2];

    const int T = K >> 6;
    const int niter = T >> 1;

#define DSREADS256(q, buf)                                                       \
    if ((q) == 0) {                                                              \
        _Pragma("unroll") for (int ni = 0; ni < 4; ni++)                         \
        _Pragma("unroll") for (int ks = 0; ks < 2; ks++)                         \
            bfr[ni][ks] = *(const short8*)(&SBp[(buf) * SBE256 +                 \
                (wn * 64 + ni * 16 + lrow) * 64 + ((ks * 32 + lg * 8) ^ swzr)]); \
    }                                                                            \
    _Pragma("unroll") for (int mi2 = 0; mi2 < 2; mi2++)                          \
    _Pragma("unroll") for (int ks = 0; ks < 2; ks++)                             \
        af[mi2 * 2 + ks] = *(const short8*)(&SAp[(buf) * SAE +                   \
            (wm * 128 + (2 * (q) + mi2) * 16 + lrow) * 64 + ((ks * 32 + lg * 8) ^ swzr)]);

#define MFMAS256(q)                                                              \
    __builtin_amdgcn_s_setprio(1);                                               \
    _Pragma("unroll") for (int ks = 0; ks < 2; ks++)                             \
    _Pragma("unroll") for (int ni = 0; ni < 4; ni++)                             \
    _Pragma("unroll") for (int mi2 = 0; mi2 < 2; mi2++)                          \
        acc[2 * (q) + mi2][ni] = __builtin_amdgcn_mfma_f32_16x16x32_bf16(        \
            bfr[ni][ks], af[mi2 * 2 + ks], acc[2 * (q) + mi2][ni], 0, 0, 0);     \
    __builtin_amdgcn_s_setprio(0);

    STG(SAp, Ag, m0, 0);
    STG(SAp + HALF256, Ag, m0 + 128, 0);
    STG(SBp, Bg, n0, 0);
    STG(SBp + HALF256, Bg, n0 + 128, 0);
    STG(SBp + SBE256, Bg, n0, 64);
    STG(SBp + SBE256 + HALF256, Bg, n0 + 128, 64);
    WAITVM4();
    BARRIER();

    for (int iter = 0; iter < niter; iter++) {
        const int tt = 2 * iter;
        const int ka = (tt + 1) * 64, kb = (tt + 2) * 64, kc = (tt + 3) * 64;
        const bool s2 = (tt + 2 < T), s3 = (tt + 3 < T);
        const bool last = (iter == niter - 1);
        short8 af[4];

        DSREADS256(0, 0);
        STG(SAp + SAE, Ag, m0, ka);
        WAITLGKM8();
        BARRIER(); WAITLGKM0(); MFMAS256(0); BARRIER();
        DSREADS256(1, 0);
        STG(SAp + SAE + HALF256, Ag, m0 + 128, ka);
        BARRIER(); WAITLGKM0(); MFMAS256(1); BARRIER();
        DSREADS256(2, 0);
        if (s2) STG(SBp, Bg, n0, kb);
        BARRIER(); WAITLGKM0(); MFMAS256(2); BARRIER();
        DSREADS256(3, 0);
        if (s2) STG(SBp + HALF256, Bg, n0 + 128, kb);
        BARRIER(); WAITLGKM0(); MFMAS256(3);
        if (last) { WAITVM0(); } else { WAITVM4(); }
        BARRIER();
        DSREADS256(0, 1);
        if (s2) STG(SAp, Ag, m0, kb);
        WAITLGKM8();
        BARRIER(); WAITLGKM0(); MFMAS256(0); BARRIER();
        DSREADS256(1, 1);
        if (s2) STG(SAp + HALF256, Ag, m0 + 128, kb);
        BARRIER(); WAITLGKM0(); MFMAS256(1); BARRIER();
        DSREADS256(2, 1);
        if (s3) STG(SBp + SBE256, Bg, n0, kc);
        BARRIER(); WAITLGKM0(); MFMAS256(2); BARRIER();
        DSREADS256(3, 1);
        if (s3) STG(SBp + SBE256 + HALF256, Bg, n0 + 128, kc);
        BARRIER(); WAITLGKM0(); MFMAS256(3);
        if (!last) WAITVM4();
        BARRIER();
    }

#pragma unroll
    for (int mi = 0; mi < 8; mi++) {
        const int gm = m0 + wm * 128 + mi * 16 + lrow;
#pragma unroll
        for (int ni = 0; ni < 4; ni++) {
            const int gn = n0 + wn * 64 + ni * 16 + lg * 4;
            size_t gi = (size_t)gm * N + gn;
            f32x4 a = acc[mi][ni];
            if constexpr (EPI == 0) {
                uint2 o; o.x = bf2(a[0], a[1]); o.y = bf2(a[2], a[3]);
                *(uint2*)&(((bf16*)Cout)[gi]) = o;
            } else if constexpr (EPI == 5) {
                float sc = (gn < C_) ? SCALE2 : 1.f;
                uint2 o; o.x = bf2(a[0] * sc, a[1] * sc); o.y = bf2(a[2] * sc, a[3] * sc);
                *(uint2*)&(((bf16*)Cout)[gi]) = o;
            } else {
                uint2 o;
                o.x = bf2(fgelu(a[0]), fgelu(a[1]));
                o.y = bf2(fgelu(a[2]), fgelu(a[3]));
                *(uint2*)&(((bf16*)Cout)[gi]) = o;
            }
        }
    }
}

// ---------------- 256x128 8-phase NT GEMM body ----------------
// EPI 0: bf16  EPI 3: bf16 = f32 Res + acc  EPI 4: f32 = bf16 Res + acc
template <int EPI>
__device__ __forceinline__ void gemm256x128_dev(short* SAp, short* SBp, int bid,
                                                const bf16* __restrict__ Ag,
                                                const bf16* __restrict__ Bg,
                                                void* __restrict__ Cout,
                                                const void* __restrict__ Res,
                                                int M, int N, int K) {
    const int nbx = N >> 7;
    const int nwg = nbx * (M >> 8);
    const int cpx = nwg >> 3;
    const int swzb = (bid & 7) * cpx + (bid >> 3);
    const int m0 = (swzb / nbx) * 256;
    const int n0 = (swzb % nbx) * 128;

    const int t = threadIdx.x;
    const int wid = t >> 6, lane = t & 63;
    const int wm = wid >> 1, wn = wid & 1;
    const int lrow = lane & 15, lg = lane >> 4;
    const int swzr = (lane & 7) * 8;
    const int sr = lane >> 3;
    const int ssc = ((lane & 7) ^ sr) * 8;

    f32x4 acc[4][4];
#pragma unroll
    for (int mi = 0; mi < 4; mi++)
#pragma unroll
        for (int ni = 0; ni < 4; ni++) acc[mi][ni] = (f32x4){0.f, 0.f, 0.f, 0.f};
    short8 bfr[4][2];

    const int T = K >> 6;
    const int niter = T >> 1;

#define DSRX(p, buf)                                                             \
    if ((p) == 0) {                                                              \
        _Pragma("unroll") for (int ni = 0; ni < 4; ni++)                         \
        _Pragma("unroll") for (int ks = 0; ks < 2; ks++)                         \
            bfr[ni][ks] = *(const short8*)(&SBp[(buf) * SBE128 +                 \
                (wn * 64 + ni * 16 + lrow) * 64 + ((ks * 32 + lg * 8) ^ swzr)]); \
    }                                                                            \
    _Pragma("unroll") for (int mi2 = 0; mi2 < 2; mi2++)                          \
    _Pragma("unroll") for (int ks = 0; ks < 2; ks++)                             \
        af[mi2 * 2 + ks] = *(const short8*)(&SAp[(buf) * SAE +                   \
            (wm * 64 + (2 * (p) + mi2) * 16 + lrow) * 64 + ((ks * 32 + lg * 8) ^ swzr)]);

#define MFX(p)                                                                   \
    __builtin_amdgcn_s_setprio(1);                                               \
    _Pragma("unroll") for (int ks = 0; ks < 2; ks++)                             \
    _Pragma("unroll") for (int ni = 0; ni < 4; ni++)                             \
    _Pragma("unroll") for (int mi2 = 0; mi2 < 2; mi2++)                          \
        acc[2 * (p) + mi2][ni] = __builtin_amdgcn_mfma_f32_16x16x32_bf16(        \
            bfr[ni][ks], af[mi2 * 2 + ks], acc[2 * (p) + mi2][ni], 0, 0, 0);     \
    __builtin_amdgcn_s_setprio(0);

    STG(SAp, Ag, m0, 0);
    STG(SAp + HALF256, Ag, m0 + 128, 0);
    STG(SBp, Bg, n0, 0);
    STG(SBp + SBE128, Bg, n0, 64);
    WAITVM2();
    BARRIER();

    for (int iter = 0; iter < niter; iter++) {
        const int tt = 2 * iter;
        const int ka = (tt + 1) * 64, kb = (tt + 2) * 64, kc = (tt + 3) * 64;
        const bool s2 = (tt + 2 < T), s3 = (tt + 3 < T);
        const bool last = (iter == niter - 1);
        short8 af[4];

        DSRX(0, 0);
        STG(SAp + SAE, Ag, m0, ka);
        STG(SAp + SAE + HALF256, Ag, m0 + 128, ka);
        WAITLGKM8();
        BARRIER(); WAITLGKM0(); MFX(0); BARRIER();
        DSRX(1, 0);
        if (s2) STG(SBp, Bg, n0, kb);
        BARRIER(); WAITLGKM0(); MFX(1);
        if (last) { WAITVM0(); } else { WAITVM2(); }
        BARRIER();
        DSRX(0, 1);
        if (s2) {
            STG(SAp, Ag, m0, kb);
            STG(SAp + HALF256, Ag, m0 + 128, kb);
        }
        WAITLGKM8();
        BARRIER(); WAITLGKM0(); MFX(0); BARRIER();
        DSRX(1, 1);
        if (s3) STG(SBp + SBE128, Bg, n0, kc);
        BARRIER(); WAITLGKM0(); MFX(1);
        if (last) { WAITVM0(); } else { WAITVM2(); }
        BARRIER();
    }

#pragma unroll
    for (int mi = 0; mi < 4; mi++) {
        const int gm = m0 + wm * 64 + mi * 16 + lrow;
#pragma unroll
        for (int ni = 0; ni < 4; ni++) {
            const int gn = n0 + wn * 64 + ni * 16 + lg * 4;
            size_t gi = (size_t)gm * N + gn;
            f32x4 a = acc[mi][ni];
            if constexpr (EPI == 0) {
                uint2 o; o.x = bf2(a[0], a[1]); o.y = bf2(a[2], a[3]);
                *(uint2*)&(((bf16*)Cout)[gi]) = o;
            } else if constexpr (EPI == 3) {
                float4 rv = *(const float4*)&(((const float*)Res)[gi]);
                uint2 o; o.x = bf2(rv.x + a[0], rv.y + a[1]); o.y = bf2(rv.z + a[2], rv.w + a[3]);
                *(uint2*)&(((bf16*)Cout)[gi]) = o;
            } else {
                sh4 hv = *(const sh4*)&(((const bf16*)Res)[gi]);
                float4 o;
                o.x = bf16bits2f(hv[0]) + a[0];
                o.y = bf16bits2f(hv[1]) + a[1];
                o.z = bf16bits2f(hv[2]) + a[2];
                o.w = bf16bits2f(hv[3]) + a[3];
                *(float4*)&(((float*)Cout)[gi]) = o;
            }
        }
    }
}

// ---------------- kernel wrappers ----------------
template <int EPI>
__global__ __launch_bounds__(512, 2) void gemm256(const bf16* __restrict__ Ag,
                                                  const bf16* __restrict__ Bg,
                                                  void* __restrict__ Cout,
                                                  int M, int N, int K) {
    __shared__ short LDS[2 * SAE + 2 * SBE256];
    gemm256_dev<EPI>(LDS, LDS + 2 * SAE, blockIdx.x, Ag, Bg, Cout, M, N, K);
}

template <int EPI>
__global__ __launch_bounds__(512, 2) void gemm256x128(const bf16* __restrict__ Ag,
                                                      const bf16* __restrict__ Bg,
                                                      void* __restrict__ Cout,
                                                      const void* __restrict__ Res,
                                                      int M, int N, int K) {
    __shared__ short LDS[2 * SAE + 2 * SBE128];
    gemm256x128_dev<EPI>(LDS, LDS + 2 * SAE, blockIdx.x, Ag, Bg, Cout, Res, M, N, K);
}

// merged qk (blocks 0..255) + vt (blocks 256..511): independent, both read ln_buf
__global__ __launch_bounds__(512, 2) void gemm_qkvt(const bf16* __restrict__ ln_buf,
                                                    const bf16* __restrict__ wattn_h,
                                                    bf16* __restrict__ qk_buf,
                                                    bf16* __restrict__ vt_buf) {
    __shared__ short LDS[2 * SAE + 2 * SBE256];
    if (blockIdx.x < 256) {
        gemm256_dev<5>(LDS, LDS + 2 * SAE, blockIdx.x,
                       ln_buf, wattn_h, qk_buf, M_TOK, 2 * C_, C_);
    } else {
        gemm256x128_dev<0>(LDS, LDS + 2 * SAE, blockIdx.x - 256,
                           wattn_h + (size_t)2 * C_ * C_, ln_buf, vt_buf, nullptr,
                           C_, M_TOK, C_);
    }
}

// ---------------- MFMA flash attention: paired q-tiles share staged K/V ----------------
__global__ __launch_bounds__(256, 4) void flash_attn(const bf16* __restrict__ qk,
                                                     const bf16* __restrict__ vt,
                                                     bf16* __restrict__ y) {
    const int bh = blockIdx.x;
    const int pi = blockIdx.y;
    const int b = bh >> 4, h = bh & 15;
    const int t = threadIdx.x;
    const int wave = t >> 6, lane = t & 63;
    const int lrow = lane & 15, lg = lane >> 4, lk = lg * 8;

    __shared__ alignas(16) short Ks[64 * 72];
    __shared__ alignas(16) short Vs[64 * 72];
    __shared__ alignas(16) short Ps[64 * 72];

    const size_t rs = 2 * C_;
    const bf16* Qg = qk + (size_t)b * T_ * rs + h * 64;
    const bf16* Kg = Qg + C_;
    const bf16* Vg = vt + (size_t)(h * 64) * M_TOK + b * T_;

    const int srow = t >> 3;
    const int sc8 = (t & 7) * 8;

    const int ql = pi, qh = 31 - pi;
    const int nkt = qh + 1;
    const int qgH = qh * 64 + wave * 16 + lrow;
    const int qgL = ql * 64 + wave * 16 + lrow;

    short8 qfH[2], qfL[2];
    {
        const bf16* qr = Qg + (size_t)qgH * rs;
        qfH[0] = *(const short8*)(qr + lk);
        qfH[1] = *(const short8*)(qr + 32 + lk);
        qr = Qg + (size_t)qgL * rs;
        qfL[0] = *(const short8*)(qr + lk);
        qfL[1] = *(const short8*)(qr + 32 + lk);
    }

    f32x4 oH[4], oL[4];
    float mH = -1e30f, lH = 0.f, mL = -1e30f, lL = 0.f;
#pragma unroll
    for (int ni = 0; ni < 4; ni++) {
        oH[ni] = (f32x4){0.f, 0.f, 0.f, 0.f};
        oL[ni] = (f32x4){0.f, 0.f, 0.f, 0.f};
    }

    short8 kr[2], vr[2];
#pragma unroll
    for (int p = 0; p < 2; p++) {
        int r = srow + p * 32;
        kr[p] = *(const short8*)(Kg + (size_t)r * rs + sc8);
        vr[p] = *(const short8*)(Vg + (size_t)r * M_TOK + sc8);
    }

    for (int kt = 0; kt < nkt; kt++) {
        const int s0 = kt * 64;
#pragma unroll
        for (int p = 0; p < 2; p++) {
            int r = srow + p * 32;
            *(short8*)(&Ks[r * 72 + sc8]) = kr[p];
            *(short8*)(&Vs[r * 72 + sc8]) = vr[p];
        }
        __syncthreads();
        if (kt + 1 < nkt) {
            const int s0n = (kt + 1) * 64;
#pragma unroll
            for (int p = 0; p < 2; p++) {
                int r = srow + p * 32;
                kr[p] = *(const short8*)(Kg + (size_t)(s0n + r) * rs + sc8);
                vr[p] = *(const short8*)(Vg + (size_t)r * M_TOK + s0n + sc8);
            }
        }

        // ======== HEAVY tile ========
        {
            f32x4 s[4];
#pragma unroll
            for (int ni = 0; ni < 4; ni++) s[ni] = (f32x4){0.f, 0.f, 0.f, 0.f};
            __builtin_amdgcn_s_setprio(1);
#pragma unroll
            for (int ks = 0; ks < 2; ks++)
#pragma unroll
                for (int ni = 0; ni < 4; ni++) {
                    short8 kf = *(const short8*)(&Ks[(ni * 16 + lrow) * 72 + ks * 32 + lk]);
                    s[ni] = __builtin_amdgcn_mfma_f32_16x16x32_bf16(kf, qfH[ks], s[ni], 0, 0, 0);
                }
            __builtin_amdgcn_s_setprio(0);

            if (kt == qh) {
#pragma unroll
                for (int ni = 0; ni < 4; ni++)
#pragma unroll
                    for (int r = 0; r < 4; r++) {
                        int kvg = s0 + ni * 16 + lg * 4 + r;
                        if (kvg > qgH) s[ni][r] = -1e30f;
                    }
            }

            float pm = s[0][0];
#pragma unroll
            for (int ni = 0; ni < 4; ni++)
#pragma unroll
                for (int r = 0; r < 4; r++) pm = fmaxf(pm, s[ni][r]);
            pm = fmaxf(pm, __shfl_xor(pm, 16));
            pm = fmaxf(pm, __shfl_xor(pm, 32));
            if (!__all(pm - mH <= 8.f)) {
                float mn = fmaxf(mH, pm);
                float alpha = fexp2(mH - mn);
                mH = mn;
                lH *= alpha;
#pragma unroll
                for (int ni = 0; ni < 4; ni++)
#pragma unroll
                    for (int r = 0; r < 4; r++) oH[ni][r] *= alpha;
            }
            float rsum = 0.f;
#pragma unroll
            for (int ni = 0; ni < 4; ni++) {
                float p0 = fexp2(s[ni][0] - mH);
                float p1 = fexp2(s[ni][1] - mH);
                float p2 = fexp2(s[ni][2] - mH);
                float p3 = fexp2(s[ni][3] - mH);
                rsum += (p0 + p1) + (p2 + p3);
                uint2 pk; pk.x = bf2(p0, p1); pk.y = bf2(p2, p3);
                *(uint2*)(&Ps[(wave * 16 + lrow) * 72 + ni * 16 + lg * 4]) = pk;
            }
            rsum += __shfl_xor(rsum, 16);
            rsum += __shfl_xor(rsum, 32);
            lH += rsum;

            __builtin_amdgcn_s_setprio(1);
#pragma unroll
            for (int ks2 = 0; ks2 < 2; ks2++) {
                short8 pf = *(const short8*)(&Ps[(wave * 16 + lrow) * 72 + ks2 * 32 + lk]);
#pragma unroll
                for (int ni = 0; ni < 4; ni++) {
                    short8 vf = *(const short8*)(&Vs[(ni * 16 + lrow) * 72 + ks2 * 32 + lk]);
                    oH[ni] = __builtin_amdgcn_mfma_f32_16x16x32_bf16(vf, pf, oH[ni], 0, 0, 0);
                }
            }
            __builtin_amdgcn_s_setprio(0);
        }

        // ======== LIGHT tile (shares staged K/V) ========
        if (kt <= ql) {
            f32x4 s[4];
#pragma unroll
            for (int ni = 0; ni < 4; ni++) s[ni] = (f32x4){0.f, 0.f, 0.f, 0.f};
            __builtin_amdgcn_s_setprio(1);
#pragma unroll
            for (int ks = 0; ks < 2; ks++)
#pragma unroll
                for (int ni = 0; ni < 4; ni++) {
                    short8 kf = *(const short8*)(&Ks[(ni * 16 + lrow) * 72 + ks * 32 + lk]);
                    s[ni] = __builtin_amdgcn_mfma_f32_16x16x32_bf16(kf, qfL[ks], s[ni], 0, 0, 0);
                }
            __builtin_amdgcn_s_setprio(0);

            if (kt == ql) {
#pragma unroll
                for (int ni = 0; ni < 4; ni++)
#pragma unroll
                    for (int r = 0; r < 4; r++) {
                        int kvg = s0 + ni * 16 + lg * 4 + r;
                        if (kvg > qgL) s[ni][r] = -1e30f;
                    }
            }

            float pm = s[0][0];
#pragma unroll
            for (int ni = 0; ni < 4; ni++)
#pragma unroll
                for (int r = 0; r < 4; r++) pm = fmaxf(pm, s[ni][r]);
            pm = fmaxf(pm, __shfl_xor(pm, 16));
            pm = fmaxf(pm, __shfl_xor(pm, 32));
            if (!__all(pm - mL <= 8.f)) {
                float mn = fmaxf(mL, pm);
                float alpha = fexp2(mL - mn);
                mL = mn;
                lL *= alpha;
#pragma unroll
                for (int ni = 0; ni < 4; ni++)
#pragma unroll
                    for (int r = 0; r < 4; r++) oL[ni][r] *= alpha;
            }
            float rsum = 0.f;
#pragma unroll
            for (int ni = 0; ni < 4; ni++) {
                float p0 = fexp2(s[ni][0] - mL);
                float p1 = fexp2(s[ni][1] - mL);
                float p2 = fexp2(s[ni][2] - mL);
                float p3 = fexp2(s[ni][3] - mL);
                rsum += (p0 + p1) + (p2 + p3);
                uint2 pk; pk.x = bf2(p0, p1); pk.y = bf2(p2, p3);
                *(uint2*)(&Ps[(wave * 16 + lrow) * 72 + ni * 16 + lg * 4]) = pk;
            }
            rsum += __shfl_xor(rsum, 16);
            rsum += __shfl_xor(rsum, 32);
            lL += rsum;

            __builtin_amdgcn_s_setprio(1);
#pragma unroll
            for (int ks2 = 0; ks2 < 2; ks2++) {
                short8 pf = *(const short8*)(&Ps[(wave * 16 + lrow) * 72 + ks2 * 32 + lk]);
#pragma unroll
                for (int ni = 0; ni < 4; ni++) {
                    short8 vf = *(const short8*)(&Vs[(ni * 16 + lrow) * 72 + ks2 * 32 + lk]);
                    oL[ni] = __builtin_amdgcn_mfma_f32_16x16x32_bf16(vf, pf, oL[ni], 0, 0, 0);
                }
            }
            __builtin_amdgcn_s_setprio(0);
        }
        __syncthreads();
    }

    float invH = 1.f / lH, invL = 1.f / lL;
#pragma unroll
    for (int ni = 0; ni < 4; ni++) {
        uint2 pk;
        pk.x = bf2(oH[ni][0] * invH, oH[ni][1] * invH);
        pk.y = bf2(oH[ni][2] * invH, oH[ni][3] * invH);
        *(uint2*)(&y[((size_t)(b * T_ + qgH)) * C_ + h * 64 + ni * 16 + lg * 4]) = pk;
        pk.x = bf2(oL[ni][0] * invL, oL[ni][1] * invL);
        pk.y = bf2(oL[ni][2] * invL, oL[ni][3] * invL);
        *(uint2*)(&y[((size_t)(b * T_ + qgL)) * C_ + h * 64 + ni * 16 + lg * 4]) = pk;
    }
}

// ---------------- launch ----------------
extern "C" void kernel_launch(void* const* d_in, const int* in_sizes, int n_in,
                              void* d_out, int out_size, void* d_ws, size_t ws_size,
                              hipStream_t stream) {
    const float* x      = (const float*)d_in[0];
    const float* ln1w   = (const float*)d_in[1];
    const float* ln1b   = (const float*)d_in[2];
    const float* ln2w   = (const float*)d_in[3];
    const float* ln2b   = (const float*)d_in[4];
    const float* w_attn = (const float*)d_in[5];
    const float* w_proj = (const float*)d_in[6];
    const float* w_fc   = (const float*)d_in[7];
    const float* w_fcp  = (const float*)d_in[8];
    float* out = (float*)d_out;

    char* ws = (char*)d_ws;
    bf16* ln_buf  = (bf16*)(ws);                   // [0,16M)
    bf16* qk_buf  = (bf16*)(ws + (16u << 20));     // [16,48M)
    bf16* vt_buf  = (bf16*)(ws + (48u << 20));     // [48,64M)
    bf16* ybuf    = (bf16*)(ws + (64u << 20));     // [64,80M)
    bf16* ubuf    = (bf16*)(ws + (16u << 20));     // [16,80M) reuse after attn
    bf16* x2b     = (bf16*)(ws + (80u << 20));     // [80,96M)
    bf16* wattn_h = (bf16*)(ws + (112u << 20));
    bf16* wproj_h = (bf16*)(ws + (118u << 20));
    bf16* wfc_h   = (bf16*)(ws + (120u << 20));
    bf16* wfcp_h  = (bf16*)(ws + (128u << 20));

    // fused LN1 + all weight conversions (1 dispatch)
    prep_kernel<<<M_TOK + 12288, 256, 0, stream>>>(
        x, ln1w, ln1b, ln_buf,
        w_attn, w_proj, w_fc, w_fcp,
        wattn_h, wproj_h, wfc_h, wfcp_h);

    // merged qk + vt (independent GEMMs, one dispatch)
    gemm_qkvt<<<512, 512, 0, stream>>>(ln_buf, wattn_h, qk_buf, vt_buf);

    // attention: grid (bh, pi) for XCD K/V locality; paired tiles share staging
    flash_attn<<<dim3(B_ * H_, 16), 256, 0, stream>>>(qk_buf, vt_buf, ybuf);

    // x2b = bf16(x + ybuf @ w_proj^T)  (256x128 8-phase)
    gemm256x128<3><<<dim3((M_TOK / 256) * (C_ / 128)), 512, 0, stream>>>(
        ybuf, wproj_h, x2b, x, M_TOK, C_, C_);

    // LN2 (bf16 in)
    ln_kernel_b<<<M_TOK, 256, 0, stream>>>(x2b, ln2w, ln2b, ln_buf);

    // u = fgelu(ln_buf @ w_fc^T)  (256^2 8-phase)
    gemm256<2><<<dim3((M_TOK / 256) * (FF_ / 256)), 512, 0, stream>>>(
        ln_buf, wfc_h, ubuf, M_TOK, FF_, C_);

    // out = f32(x2b) + u @ w_fcp^T  (256x128 8-phase)
    gemm256x128<4><<<dim3((M_TOK / 256) * (C_ / 128)), 512, 0, stream>>>(
        ubuf, wfcp_h, out, x2b, M_TOK, C_, FF_);
}

// Round 14
// 326.041 us; speedup vs baseline: 28.7434x; 1.0225x over previous
//
#include <hip/hip_runtime.h>
#include <hip/hip_bf16.h>

using bf16 = __hip_bfloat16;
typedef __attribute__((ext_vector_type(8))) short short8;
typedef __attribute__((ext_vector_type(4))) short sh4;
typedef __attribute__((ext_vector_type(4))) float f32x4;

#define B_ 4
#define T_ 2048
#define C_ 1024
#define H_ 16
#define FF_ 4096
#define M_TOK (B_ * T_)   // 8192
#define SCALE2 0.1803368801111f   // 0.125 * log2(e)

#define BARRIER() asm volatile("s_barrier" ::: "memory")
#define WAITLGKM0() asm volatile("s_waitcnt lgkmcnt(0)" ::: "memory")
#define WAITLGKM8() asm volatile("s_waitcnt lgkmcnt(8)" ::: "memory")
#define WAITVM4() asm volatile("s_waitcnt vmcnt(4)" ::: "memory")
#define WAITVM2() asm volatile("s_waitcnt vmcnt(2)" ::: "memory")
#define WAITVM0() asm volatile("s_waitcnt vmcnt(0)" ::: "memory")

#define SAE (256 * 64)
#define SBE256 (256 * 64)
#define SBE128 (128 * 64)
#define HALF256 (128 * 64)

// ---------------- async global->LDS 16B ----------------
__device__ __forceinline__ void gload16(const void* g, void* l) {
    __builtin_amdgcn_global_load_lds(
        (const __attribute__((address_space(1))) void*)g,
        (__attribute__((address_space(3))) void*)l, 16, 0, 0);
}

// 2^x in one instruction
__device__ __forceinline__ float fexp2(float x) {
    float r;
    asm("v_exp_f32 %0, %1" : "=v"(r) : "v"(x));
    return r;
}

__device__ __forceinline__ float bf16bits2f(short s) {
    return __uint_as_float(((unsigned)(unsigned short)s) << 16);
}

// pack two f32 -> one dword of 2 bf16
__device__ __forceinline__ unsigned bf2(float a, float b) {
    bf16 x = __float2bfloat16(a), y = __float2bfloat16(b);
    unsigned short ux = *(unsigned short*)&x, uy = *(unsigned short*)&y;
    return (unsigned)ux | ((unsigned)uy << 16);
}

// fast gelu
__device__ __forceinline__ float fgelu(float x) {
    float y = 0.79788456f * (x + 0.044715f * x * x * x);
    float tv = fexp2(y * 2.885390082f);
    return x * tv * __builtin_amdgcn_rcpf(tv + 1.f);
}

// ---------------- prep: LN1 (blocks 0..8191) + w_attn cvt only ----------------
__global__ __launch_bounds__(256) void prep_kernel(
    const float* __restrict__ x, const float* __restrict__ ln1w, const float* __restrict__ ln1b,
    bf16* __restrict__ ln_out,
    const float* __restrict__ w_attn, bf16* __restrict__ wattn_h) {
    const int bid = blockIdx.x;
    const int t = threadIdx.x;
    if (bid < M_TOK) {
        float4 v = ((const float4*)(x + (size_t)bid * C_))[t];
        float s = v.x + v.y + v.z + v.w;
        float s2 = v.x * v.x + v.y * v.y + v.z * v.z + v.w * v.w;
#pragma unroll
        for (int off = 32; off > 0; off >>= 1) {
            s += __shfl_down(s, off);
            s2 += __shfl_down(s2, off);
        }
        __shared__ float ss[4], ss2[4];
        int wave = t >> 6, lane = t & 63;
        if (lane == 0) { ss[wave] = s; ss2[wave] = s2; }
        __syncthreads();
        s = ss[0] + ss[1] + ss[2] + ss[3];
        s2 = ss2[0] + ss2[1] + ss2[2] + ss2[3];
        float mu = s * (1.f / C_);
        float var = s2 * (1.f / C_) - mu * mu;
        float rstd = rsqrtf(var + 1e-5f);
        float4 wv = ((const float4*)ln1w)[t];
        float4 bv = ((const float4*)ln1b)[t];
        uint2 o;
        o.x = bf2((v.x - mu) * rstd * wv.x + bv.x, (v.y - mu) * rstd * wv.y + bv.y);
        o.y = bf2((v.z - mu) * rstd * wv.z + bv.z, (v.w - mu) * rstd * wv.w + bv.w);
        ((uint2*)(ln_out + (size_t)bid * C_))[t] = o;
    } else {
        int j = (bid - M_TOK) * 256 + t;   // float4 index into w_attn (3C*C/4 = 786432)
        float4 v = ((const float4*)w_attn)[j];
        uint2 o;
        o.x = bf2(v.x, v.y);
        o.y = bf2(v.z, v.w);
        ((uint2*)wattn_h)[j] = o;
    }
}

// ---------------- LayerNorm (LN2): bf16 in -> bf16 out ----------------
__global__ __launch_bounds__(256) void ln_kernel_b(const bf16* __restrict__ x,
                                                   const float* __restrict__ w,
                                                   const float* __restrict__ b,
                                                   bf16* __restrict__ out) {
    int row = blockIdx.x;
    int t = threadIdx.x;
    sh4 h = ((const sh4*)(x + (size_t)row * C_))[t];
    float4 v;
    v.x = bf16bits2f(h[0]);
    v.y = bf16bits2f(h[1]);
    v.z = bf16bits2f(h[2]);
    v.w = bf16bits2f(h[3]);
    float s = v.x + v.y + v.z + v.w;
    float s2 = v.x * v.x + v.y * v.y + v.z * v.z + v.w * v.w;
#pragma unroll
    for (int off = 32; off > 0; off >>= 1) {
        s += __shfl_down(s, off);
        s2 += __shfl_down(s2, off);
    }
    __shared__ float ss[4], ss2[4];
    int wave = t >> 6, lane = t & 63;
    if (lane == 0) { ss[wave] = s; ss2[wave] = s2; }
    __syncthreads();
    s = ss[0] + ss[1] + ss[2] + ss[3];
    s2 = ss2[0] + ss2[1] + ss2[2] + ss2[3];
    float mu = s * (1.f / C_);
    float var = s2 * (1.f / C_) - mu * mu;
    float rstd = rsqrtf(var + 1e-5f);
    float4 wv = ((const float4*)w)[t];
    float4 bv = ((const float4*)b)[t];
    uint2 o;
    o.x = bf2((v.x - mu) * rstd * wv.x + bv.x, (v.y - mu) * rstd * wv.y + bv.y);
    o.y = bf2((v.z - mu) * rstd * wv.z + bv.z, (v.w - mu) * rstd * wv.w + bv.w);
    ((uint2*)(out + (size_t)row * C_))[t] = o;
}

// ======== shared staging macro ========
#define STG(ldsbase, g, grow0, k0)                                               \
    {                                                                            \
        _Pragma("unroll") for (int s_ = 0; s_ < 2; s_++) {                       \
            int row_ = s_ * 64 + wid * 8 + sr;                                   \
            gload16(g + (size_t)((grow0) + row_) * K + (k0) + ssc,               \
                    (ldsbase) + row_ * 64 + (lane & 7) * 8);                     \
        }                                                                        \
    }

// ---------------- 256x256 8-phase NT GEMM body ----------------
template <int EPI>
__device__ __forceinline__ void gemm256_dev(short* SAp, short* SBp, int bid,
                                            const bf16* __restrict__ Ag,
                                            const bf16* __restrict__ Bg,
                                            void* __restrict__ Cout,
                                            int M, int N, int K) {
    const int nbx = N >> 8;
    const int nwg = nbx * (M >> 8);
    const int cpx = nwg >> 3;
    const int swzb = (bid & 7) * cpx + (bid >> 3);
    const int m0 = (swzb / nbx) * 256;
    const int n0 = (swzb % nbx) * 256;

    const int t = threadIdx.x;
    const int wid = t >> 6, lane = t & 63;
    const int wm = wid >> 2, wn = wid & 3;
    const int lrow = lane & 15, lg = lane >> 4;
    const int swzr = (lane & 7) * 8;
    const int sr = lane >> 3;
    const int ssc = ((lane & 7) ^ sr) * 8;

    f32x4 acc[8][4];
#pragma unroll
    for (int mi = 0; mi < 8; mi++)
#pragma unroll
        for (int ni = 0; ni < 4; ni++) acc[mi][ni] = (f32x4){0.f, 0.f, 0.f, 0.f};
    short8 bfr[4][2];

    const int T = K >> 6;
    const int niter = T >> 1;

#define DSREADS256(q, buf)                                                       \
    if ((q) == 0) {                                                              \
        _Pragma("unroll") for (int ni = 0; ni < 4; ni++)                         \
        _Pragma("unroll") for (int ks = 0; ks < 2; ks++)                         \
            bfr[ni][ks] = *(const short8*)(&SBp[(buf) * SBE256 +                 \
                (wn * 64 + ni * 16 + lrow) * 64 + ((ks * 32 + lg * 8) ^ swzr)]); \
    }                                                                            \
    _Pragma("unroll") for (int mi2 = 0; mi2 < 2; mi2++)                          \
    _Pragma("unroll") for (int ks = 0; ks < 2; ks++)                             \
        af[mi2 * 2 + ks] = *(const short8*)(&SAp[(buf) * SAE +                   \
            (wm * 128 + (2 * (q) + mi2) * 16 + lrow) * 64 + ((ks * 32 + lg * 8) ^ swzr)]);

#define MFMAS256(q)                                                              \
    __builtin_amdgcn_s_setprio(1);                                               \
    _Pragma("unroll") for (int ks = 0; ks < 2; ks++)                             \
    _Pragma("unroll") for (int ni = 0; ni < 4; ni++)                             \
    _Pragma("unroll") for (int mi2 = 0; mi2 < 2; mi2++)                          \
        acc[2 * (q) + mi2][ni] = __builtin_amdgcn_mfma_f32_16x16x32_bf16(        \
            bfr[ni][ks], af[mi2 * 2 + ks], acc[2 * (q) + mi2][ni], 0, 0, 0);     \
    __builtin_amdgcn_s_setprio(0);

    STG(SAp, Ag, m0, 0);
    STG(SAp + HALF256, Ag, m0 + 128, 0);
    STG(SBp, Bg, n0, 0);
    STG(SBp + HALF256, Bg, n0 + 128, 0);
    STG(SBp + SBE256, Bg, n0, 64);
    STG(SBp + SBE256 + HALF256, Bg, n0 + 128, 64);
    WAITVM4();
    BARRIER();

    for (int iter = 0; iter < niter; iter++) {
        const int tt = 2 * iter;
        const int ka = (tt + 1) * 64, kb = (tt + 2) * 64, kc = (tt + 3) * 64;
        const bool s2 = (tt + 2 < T), s3 = (tt + 3 < T);
        const bool last = (iter == niter - 1);
        short8 af[4];

        DSREADS256(0, 0);
        STG(SAp + SAE, Ag, m0, ka);
        WAITLGKM8();
        BARRIER(); WAITLGKM0(); MFMAS256(0); BARRIER();
        DSREADS256(1, 0);
        STG(SAp + SAE + HALF256, Ag, m0 + 128, ka);
        BARRIER(); WAITLGKM0(); MFMAS256(1); BARRIER();
        DSREADS256(2, 0);
        if (s2) STG(SBp, Bg, n0, kb);
        BARRIER(); WAITLGKM0(); MFMAS256(2); BARRIER();
        DSREADS256(3, 0);
        if (s2) STG(SBp + HALF256, Bg, n0 + 128, kb);
        BARRIER(); WAITLGKM0(); MFMAS256(3);
        if (last) { WAITVM0(); } else { WAITVM4(); }
        BARRIER();
        DSREADS256(0, 1);
        if (s2) STG(SAp, Ag, m0, kb);
        WAITLGKM8();
        BARRIER(); WAITLGKM0(); MFMAS256(0); BARRIER();
        DSREADS256(1, 1);
        if (s2) STG(SAp + HALF256, Ag, m0 + 128, kb);
        BARRIER(); WAITLGKM0(); MFMAS256(1); BARRIER();
        DSREADS256(2, 1);
        if (s3) STG(SBp + SBE256, Bg, n0, kc);
        BARRIER(); WAITLGKM0(); MFMAS256(2); BARRIER();
        DSREADS256(3, 1);
        if (s3) STG(SBp + SBE256 + HALF256, Bg, n0 + 128, kc);
        BARRIER(); WAITLGKM0(); MFMAS256(3);
        if (!last) WAITVM4();
        BARRIER();
    }

#pragma unroll
    for (int mi = 0; mi < 8; mi++) {
        const int gm = m0 + wm * 128 + mi * 16 + lrow;
#pragma unroll
        for (int ni = 0; ni < 4; ni++) {
            const int gn = n0 + wn * 64 + ni * 16 + lg * 4;
            size_t gi = (size_t)gm * N + gn;
            f32x4 a = acc[mi][ni];
            if constexpr (EPI == 0) {
                uint2 o; o.x = bf2(a[0], a[1]); o.y = bf2(a[2], a[3]);
                *(uint2*)&(((bf16*)Cout)[gi]) = o;
            } else if constexpr (EPI == 5) {
                float sc = (gn < C_) ? SCALE2 : 1.f;
                uint2 o; o.x = bf2(a[0] * sc, a[1] * sc); o.y = bf2(a[2] * sc, a[3] * sc);
                *(uint2*)&(((bf16*)Cout)[gi]) = o;
            } else {
                uint2 o;
                o.x = bf2(fgelu(a[0]), fgelu(a[1]));
                o.y = bf2(fgelu(a[2]), fgelu(a[3]));
                *(uint2*)&(((bf16*)Cout)[gi]) = o;
            }
        }
    }
}

// ---------------- 256x128 8-phase NT GEMM body ----------------
template <int EPI>
__device__ __forceinline__ void gemm256x128_dev(short* SAp, short* SBp, int bid,
                                                const bf16* __restrict__ Ag,
                                                const bf16* __restrict__ Bg,
                                                void* __restrict__ Cout,
                                                const void* __restrict__ Res,
                                                int M, int N, int K) {
    const int nbx = N >> 7;
    const int nwg = nbx * (M >> 8);
    const int cpx = nwg >> 3;
    const int swzb = (bid & 7) * cpx + (bid >> 3);
    const int m0 = (swzb / nbx) * 256;
    const int n0 = (swzb % nbx) * 128;

    const int t = threadIdx.x;
    const int wid = t >> 6, lane = t & 63;
    const int wm = wid >> 1, wn = wid & 1;
    const int lrow = lane & 15, lg = lane >> 4;
    const int swzr = (lane & 7) * 8;
    const int sr = lane >> 3;
    const int ssc = ((lane & 7) ^ sr) * 8;

    f32x4 acc[4][4];
#pragma unroll
    for (int mi = 0; mi < 4; mi++)
#pragma unroll
        for (int ni = 0; ni < 4; ni++) acc[mi][ni] = (f32x4){0.f, 0.f, 0.f, 0.f};
    short8 bfr[4][2];

    const int T = K >> 6;
    const int niter = T >> 1;

#define DSRX(p, buf)                                                             \
    if ((p) == 0) {                                                              \
        _Pragma("unroll") for (int ni = 0; ni < 4; ni++)                         \
        _Pragma("unroll") for (int ks = 0; ks < 2; ks++)                         \
            bfr[ni][ks] = *(const short8*)(&SBp[(buf) * SBE128 +                 \
                (wn * 64 + ni * 16 + lrow) * 64 + ((ks * 32 + lg * 8) ^ swzr)]); \
    }                                                                            \
    _Pragma("unroll") for (int mi2 = 0; mi2 < 2; mi2++)                          \
    _Pragma("unroll") for (int ks = 0; ks < 2; ks++)                             \
        af[mi2 * 2 + ks] = *(const short8*)(&SAp[(buf) * SAE +                   \
            (wm * 64 + (2 * (p) + mi2) * 16 + lrow) * 64 + ((ks * 32 + lg * 8) ^ swzr)]);

#define MFX(p)                                                                   \
    __builtin_amdgcn_s_setprio(1);                                               \
    _Pragma("unroll") for (int ks = 0; ks < 2; ks++)                             \
    _Pragma("unroll") for (int ni = 0; ni < 4; ni++)                             \
    _Pragma("unroll") for (int mi2 = 0; mi2 < 2; mi2++)                          \
        acc[2 * (p) + mi2][ni] = __builtin_amdgcn_mfma_f32_16x16x32_bf16(        \
            bfr[ni][ks], af[mi2 * 2 + ks], acc[2 * (p) + mi2][ni], 0, 0, 0);     \
    __builtin_amdgcn_s_setprio(0);

    STG(SAp, Ag, m0, 0);
    STG(SAp + HALF256, Ag, m0 + 128, 0);
    STG(SBp, Bg, n0, 0);
    STG(SBp + SBE128, Bg, n0, 64);
    WAITVM2();
    BARRIER();

    for (int iter = 0; iter < niter; iter++) {
        const int tt = 2 * iter;
        const int ka = (tt + 1) * 64, kb = (tt + 2) * 64, kc = (tt + 3) * 64;
        const bool s2 = (tt + 2 < T), s3 = (tt + 3 < T);
        const bool last = (iter == niter - 1);
        short8 af[4];

        DSRX(0, 0);
        STG(SAp + SAE, Ag, m0, ka);
        STG(SAp + SAE + HALF256, Ag, m0 + 128, ka);
        WAITLGKM8();
        BARRIER(); WAITLGKM0(); MFX(0); BARRIER();
        DSRX(1, 0);
        if (s2) STG(SBp, Bg, n0, kb);
        BARRIER(); WAITLGKM0(); MFX(1);
        if (last) { WAITVM0(); } else { WAITVM2(); }
        BARRIER();
        DSRX(0, 1);
        if (s2) {
            STG(SAp, Ag, m0, kb);
            STG(SAp + HALF256, Ag, m0 + 128, kb);
        }
        WAITLGKM8();
        BARRIER(); WAITLGKM0(); MFX(0); BARRIER();
        DSRX(1, 1);
        if (s3) STG(SBp + SBE128, Bg, n0, kc);
        BARRIER(); WAITLGKM0(); MFX(1);
        if (last) { WAITVM0(); } else { WAITVM2(); }
        BARRIER();
    }

#pragma unroll
    for (int mi = 0; mi < 4; mi++) {
        const int gm = m0 + wm * 64 + mi * 16 + lrow;
#pragma unroll
        for (int ni = 0; ni < 4; ni++) {
            const int gn = n0 + wn * 64 + ni * 16 + lg * 4;
            size_t gi = (size_t)gm * N + gn;
            f32x4 a = acc[mi][ni];
            if constexpr (EPI == 0) {
                uint2 o; o.x = bf2(a[0], a[1]); o.y = bf2(a[2], a[3]);
                *(uint2*)&(((bf16*)Cout)[gi]) = o;
            } else if constexpr (EPI == 3) {
                float4 rv = *(const float4*)&(((const float*)Res)[gi]);
                uint2 o; o.x = bf2(rv.x + a[0], rv.y + a[1]); o.y = bf2(rv.z + a[2], rv.w + a[3]);
                *(uint2*)&(((bf16*)Cout)[gi]) = o;
            } else {
                sh4 hv = *(const sh4*)&(((const bf16*)Res)[gi]);
                float4 o;
                o.x = bf16bits2f(hv[0]) + a[0];
                o.y = bf16bits2f(hv[1]) + a[1];
                o.z = bf16bits2f(hv[2]) + a[2];
                o.w = bf16bits2f(hv[3]) + a[3];
                *(float4*)&(((float*)Cout)[gi]) = o;
            }
        }
    }
}

// ---------------- kernel wrappers ----------------
template <int EPI>
__global__ __launch_bounds__(512, 2) void gemm256(const bf16* __restrict__ Ag,
                                                  const bf16* __restrict__ Bg,
                                                  void* __restrict__ Cout,
                                                  int M, int N, int K) {
    __shared__ short LDS[2 * SAE + 2 * SBE256];
    gemm256_dev<EPI>(LDS, LDS + 2 * SAE, blockIdx.x, Ag, Bg, Cout, M, N, K);
}

template <int EPI>
__global__ __launch_bounds__(512, 2) void gemm256x128(const bf16* __restrict__ Ag,
                                                      const bf16* __restrict__ Bg,
                                                      void* __restrict__ Cout,
                                                      const void* __restrict__ Res,
                                                      int M, int N, int K) {
    __shared__ short LDS[2 * SAE + 2 * SBE128];
    gemm256x128_dev<EPI>(LDS, LDS + 2 * SAE, blockIdx.x, Ag, Bg, Cout, Res, M, N, K);
}

// merged qk (blocks 0..255) + vt (blocks 256..511)
__global__ __launch_bounds__(512, 2) void gemm_qkvt(const bf16* __restrict__ ln_buf,
                                                    const bf16* __restrict__ wattn_h,
                                                    bf16* __restrict__ qk_buf,
                                                    bf16* __restrict__ vt_buf) {
    __shared__ short LDS[2 * SAE + 2 * SBE256];
    if (blockIdx.x < 256) {
        gemm256_dev<5>(LDS, LDS + 2 * SAE, blockIdx.x,
                       ln_buf, wattn_h, qk_buf, M_TOK, 2 * C_, C_);
    } else {
        gemm256x128_dev<0>(LDS, LDS + 2 * SAE, blockIdx.x - 256,
                           wattn_h + (size_t)2 * C_ * C_, ln_buf, vt_buf, nullptr,
                           C_, M_TOK, C_);
    }
}

// ---------------- flash attention (blocks 0..1023) + deferred weight cvt (blocks 1024+) ----------------
// flash: bh = bid&63, pi = bid>>6 -> XCD = bid%8 = bh%8 (K/V L2 locality preserved).
// cvt: w_proj (262144 f4) | w_fc (1048576 f4) | w_fcp (1048576 f4) -> 9216 blocks.
__global__ __launch_bounds__(256, 4) void flash_cvt(const bf16* __restrict__ qk,
                                                    const bf16* __restrict__ vt,
                                                    bf16* __restrict__ y,
                                                    const float* __restrict__ w_proj,
                                                    const float* __restrict__ w_fc,
                                                    const float* __restrict__ w_fcp,
                                                    bf16* __restrict__ wproj_h,
                                                    bf16* __restrict__ wfc_h,
                                                    bf16* __restrict__ wfcp_h) {
    const int bid = blockIdx.x;
    const int t = threadIdx.x;

    if (bid >= 1024) {
        // ---- deferred weight conversion ----
        int i = (bid - 1024) * 256 + t;
        const float* src;
        bf16* dst;
        int base;
        if (i < 262144) {            // w_proj: C*C/4
            src = w_proj; dst = wproj_h; base = 0;
        } else if (i < 1310720) {    // w_fc: FF*C/4
            src = w_fc; dst = wfc_h; base = 262144;
        } else {                     // w_fcp: C*FF/4
            src = w_fcp; dst = wfcp_h; base = 1310720;
        }
        int j = i - base;
        float4 v = ((const float4*)src)[j];
        uint2 o;
        o.x = bf2(v.x, v.y);
        o.y = bf2(v.z, v.w);
        ((uint2*)dst)[j] = o;
        return;
    }

    const int bh = bid & 63;
    const int pi = bid >> 6;
    const int b = bh >> 4, h = bh & 15;
    const int wave = t >> 6, lane = t & 63;
    const int lrow = lane & 15, lg = lane >> 4, lk = lg * 8;

    __shared__ alignas(16) short Ks[64 * 72];
    __shared__ alignas(16) short Vs[64 * 72];
    __shared__ alignas(16) short Ps[64 * 72];

    const size_t rs = 2 * C_;
    const bf16* Qg = qk + (size_t)b * T_ * rs + h * 64;
    const bf16* Kg = Qg + C_;
    const bf16* Vg = vt + (size_t)(h * 64) * M_TOK + b * T_;

    const int srow = t >> 3;
    const int sc8 = (t & 7) * 8;

    const int ql = pi, qh = 31 - pi;
    const int nkt = qh + 1;
    const int qgH = qh * 64 + wave * 16 + lrow;
    const int qgL = ql * 64 + wave * 16 + lrow;

    short8 qfH[2], qfL[2];
    {
        const bf16* qr = Qg + (size_t)qgH * rs;
        qfH[0] = *(const short8*)(qr + lk);
        qfH[1] = *(const short8*)(qr + 32 + lk);
        qr = Qg + (size_t)qgL * rs;
        qfL[0] = *(const short8*)(qr + lk);
        qfL[1] = *(const short8*)(qr + 32 + lk);
    }

    f32x4 oH[4], oL[4];
    float mH = -1e30f, lH = 0.f, mL = -1e30f, lL = 0.f;
#pragma unroll
    for (int ni = 0; ni < 4; ni++) {
        oH[ni] = (f32x4){0.f, 0.f, 0.f, 0.f};
        oL[ni] = (f32x4){0.f, 0.f, 0.f, 0.f};
    }

    short8 kr[2], vr[2];
#pragma unroll
    for (int p = 0; p < 2; p++) {
        int r = srow + p * 32;
        kr[p] = *(const short8*)(Kg + (size_t)r * rs + sc8);
        vr[p] = *(const short8*)(Vg + (size_t)r * M_TOK + sc8);
    }

    for (int kt = 0; kt < nkt; kt++) {
        const int s0 = kt * 64;
#pragma unroll
        for (int p = 0; p < 2; p++) {
            int r = srow + p * 32;
            *(short8*)(&Ks[r * 72 + sc8]) = kr[p];
            *(short8*)(&Vs[r * 72 + sc8]) = vr[p];
        }
        __syncthreads();
        if (kt + 1 < nkt) {
            const int s0n = (kt + 1) * 64;
#pragma unroll
            for (int p = 0; p < 2; p++) {
                int r = srow + p * 32;
                kr[p] = *(const short8*)(Kg + (size_t)(s0n + r) * rs + sc8);
                vr[p] = *(const short8*)(Vg + (size_t)r * M_TOK + s0n + sc8);
            }
        }

        // ======== HEAVY tile ========
        {
            f32x4 s[4];
#pragma unroll
            for (int ni = 0; ni < 4; ni++) s[ni] = (f32x4){0.f, 0.f, 0.f, 0.f};
            __builtin_amdgcn_s_setprio(1);
#pragma unroll
            for (int ks = 0; ks < 2; ks++)
#pragma unroll
                for (int ni = 0; ni < 4; ni++) {
                    short8 kf = *(const short8*)(&Ks[(ni * 16 + lrow) * 72 + ks * 32 + lk]);
                    s[ni] = __builtin_amdgcn_mfma_f32_16x16x32_bf16(kf, qfH[ks], s[ni], 0, 0, 0);
                }
            __builtin_amdgcn_s_setprio(0);

            if (kt == qh) {
#pragma unroll
                for (int ni = 0; ni < 4; ni++)
#pragma unroll
                    for (int r = 0; r < 4; r++) {
                        int kvg = s0 + ni * 16 + lg * 4 + r;
                        if (kvg > qgH) s[ni][r] = -1e30f;
                    }
            }

            float pm = s[0][0];
#pragma unroll
            for (int ni = 0; ni < 4; ni++)
#pragma unroll
                for (int r = 0; r < 4; r++) pm = fmaxf(pm, s[ni][r]);
            pm = fmaxf(pm, __shfl_xor(pm, 16));
            pm = fmaxf(pm, __shfl_xor(pm, 32));
            if (!__all(pm - mH <= 8.f)) {
                float mn = fmaxf(mH, pm);
                float alpha = fexp2(mH - mn);
                mH = mn;
                lH *= alpha;
#pragma unroll
                for (int ni = 0; ni < 4; ni++)
#pragma unroll
                    for (int r = 0; r < 4; r++) oH[ni][r] *= alpha;
            }
            float rsum = 0.f;
#pragma unroll
            for (int ni = 0; ni < 4; ni++) {
                float p0 = fexp2(s[ni][0] - mH);
                float p1 = fexp2(s[ni][1] - mH);
                float p2 = fexp2(s[ni][2] - mH);
                float p3 = fexp2(s[ni][3] - mH);
                rsum += (p0 + p1) + (p2 + p3);
                uint2 pk; pk.x = bf2(p0, p1); pk.y = bf2(p2, p3);
                *(uint2*)(&Ps[(wave * 16 + lrow) * 72 + ni * 16 + lg * 4]) = pk;
            }
            rsum += __shfl_xor(rsum, 16);
            rsum += __shfl_xor(rsum, 32);
            lH += rsum;

            __builtin_amdgcn_s_setprio(1);
#pragma unroll
            for (int ks2 = 0; ks2 < 2; ks2++) {
                short8 pf = *(const short8*)(&Ps[(wave * 16 + lrow) * 72 + ks2 * 32 + lk]);
#pragma unroll
                for (int ni = 0; ni < 4; ni++) {
                    short8 vf = *(const short8*)(&Vs[(ni * 16 + lrow) * 72 + ks2 * 32 + lk]);
                    oH[ni] = __builtin_amdgcn_mfma_f32_16x16x32_bf16(vf, pf, oH[ni], 0, 0, 0);
                }
            }
            __builtin_amdgcn_s_setprio(0);
        }

        // ======== LIGHT tile (shares staged K/V) ========
        if (kt <= ql) {
            f32x4 s[4];
#pragma unroll
            for (int ni = 0; ni < 4; ni++) s[ni] = (f32x4){0.f, 0.f, 0.f, 0.f};
            __builtin_amdgcn_s_setprio(1);
#pragma unroll
            for (int ks = 0; ks < 2; ks++)
#pragma unroll
                for (int ni = 0; ni < 4; ni++) {
                    short8 kf = *(const short8*)(&Ks[(ni * 16 + lrow) * 72 + ks * 32 + lk]);
                    s[ni] = __builtin_amdgcn_mfma_f32_16x16x32_bf16(kf, qfL[ks], s[ni], 0, 0, 0);
                }
            __builtin_amdgcn_s_setprio(0);

            if (kt == ql) {
#pragma unroll
                for (int ni = 0; ni < 4; ni++)
#pragma unroll
                    for (int r = 0; r < 4; r++) {
                        int kvg = s0 + ni * 16 + lg * 4 + r;
                        if (kvg > qgL) s[ni][r] = -1e30f;
                    }
            }

            float pm = s[0][0];
#pragma unroll
            for (int ni = 0; ni < 4; ni++)
#pragma unroll
                for (int r = 0; r < 4; r++) pm = fmaxf(pm, s[ni][r]);
            pm = fmaxf(pm, __shfl_xor(pm, 16));
            pm = fmaxf(pm, __shfl_xor(pm, 32));
            if (!__all(pm - mL <= 8.f)) {
                float mn = fmaxf(mL, pm);
                float alpha = fexp2(mL - mn);
                mL = mn;
                lL *= alpha;
#pragma unroll
                for (int ni = 0; ni < 4; ni++)
#pragma unroll
                    for (int r = 0; r < 4; r++) oL[ni][r] *= alpha;
            }
            float rsum = 0.f;
#pragma unroll
            for (int ni = 0; ni < 4; ni++) {
                float p0 = fexp2(s[ni][0] - mL);
                float p1 = fexp2(s[ni][1] - mL);
                float p2 = fexp2(s[ni][2] - mL);
                float p3 = fexp2(s[ni][3] - mL);
                rsum += (p0 + p1) + (p2 + p3);
                uint2 pk; pk.x = bf2(p0, p1); pk.y = bf2(p2, p3);
                *(uint2*)(&Ps[(wave * 16 + lrow) * 72 + ni * 16 + lg * 4]) = pk;
            }
            rsum += __shfl_xor(rsum, 16);
            rsum += __shfl_xor(rsum, 32);
            lL += rsum;

            __builtin_amdgcn_s_setprio(1);
#pragma unroll
            for (int ks2 = 0; ks2 < 2; ks2++) {
                short8 pf = *(const short8*)(&Ps[(wave * 16 + lrow) * 72 + ks2 * 32 + lk]);
#pragma unroll
                for (int ni = 0; ni < 4; ni++) {
                    short8 vf = *(const short8*)(&Vs[(ni * 16 + lrow) * 72 + ks2 * 32 + lk]);
                    oL[ni] = __builtin_amdgcn_mfma_f32_16x16x32_bf16(vf, pf, oL[ni], 0, 0, 0);
                }
            }
            __builtin_amdgcn_s_setprio(0);
        }
        __syncthreads();
    }

    float invH = 1.f / lH, invL = 1.f / lL;
#pragma unroll
    for (int ni = 0; ni < 4; ni++) {
        uint2 pk;
        pk.x = bf2(oH[ni][0] * invH, oH[ni][1] * invH);
        pk.y = bf2(oH[ni][2] * invH, oH[ni][3] * invH);
        *(uint2*)(&y[((size_t)(b * T_ + qgH)) * C_ + h * 64 + ni * 16 + lg * 4]) = pk;
        pk.x = bf2(oL[ni][0] * invL, oL[ni][1] * invL);
        pk.y = bf2(oL[ni][2] * invL, oL[ni][3] * invL);
        *(uint2*)(&y[((size_t)(b * T_ + qgL)) * C_ + h * 64 + ni * 16 + lg * 4]) = pk;
    }
}

// ---------------- launch ----------------
extern "C" void kernel_launch(void* const* d_in, const int* in_sizes, int n_in,
                              void* d_out, int out_size, void* d_ws, size_t ws_size,
                              hipStream_t stream) {
    const float* x      = (const float*)d_in[0];
    const float* ln1w   = (const float*)d_in[1];
    const float* ln1b   = (const float*)d_in[2];
    const float* ln2w   = (const float*)d_in[3];
    const float* ln2b   = (const float*)d_in[4];
    const float* w_attn = (const float*)d_in[5];
    const float* w_proj = (const float*)d_in[6];
    const float* w_fc   = (const float*)d_in[7];
    const float* w_fcp  = (const float*)d_in[8];
    float* out = (float*)d_out;

    char* ws = (char*)d_ws;
    bf16* ln_buf  = (bf16*)(ws);                   // [0,16M)
    bf16* qk_buf  = (bf16*)(ws + (16u << 20));     // [16,48M)
    bf16* vt_buf  = (bf16*)(ws + (48u << 20));     // [48,64M)
    bf16* ybuf    = (bf16*)(ws + (64u << 20));     // [64,80M)
    bf16* ubuf    = (bf16*)(ws + (16u << 20));     // [16,80M) reuse after attn
    bf16* x2b     = (bf16*)(ws + (80u << 20));     // [80,96M)
    bf16* wattn_h = (bf16*)(ws + (112u << 20));
    bf16* wproj_h = (bf16*)(ws + (118u << 20));
    bf16* wfc_h   = (bf16*)(ws + (120u << 20));
    bf16* wfcp_h  = (bf16*)(ws + (128u << 20));

    // prep: LN1 + w_attn cvt only (3072 cvt blocks)
    prep_kernel<<<M_TOK + 3072, 256, 0, stream>>>(
        x, ln1w, ln1b, ln_buf, w_attn, wattn_h);

    // merged qk + vt
    gemm_qkvt<<<512, 512, 0, stream>>>(ln_buf, wattn_h, qk_buf, vt_buf);

    // flash attention + deferred weight conversions (w_proj/w_fc/w_fcp) in tail
    flash_cvt<<<1024 + 9216, 256, 0, stream>>>(
        qk_buf, vt_buf, ybuf, w_proj, w_fc, w_fcp, wproj_h, wfc_h, wfcp_h);

    // x2b = bf16(x + ybuf @ w_proj^T)
    gemm256x128<3><<<dim3((M_TOK / 256) * (C_ / 128)), 512, 0, stream>>>(
        ybuf, wproj_h, x2b, x, M_TOK, C_, C_);

    // LN2
    ln_kernel_b<<<M_TOK, 256, 0, stream>>>(x2b, ln2w, ln2b, ln_buf);

    // u = fgelu(ln_buf @ w_fc^T)
    gemm256<2><<<dim3((M_TOK / 256) * (FF_ / 256)), 512, 0, stream>>>(
        ln_buf, wfc_h, ubuf, M_TOK, FF_, C_);

    // out = f32(x2b) + u @ w_fcp^T
    gemm256x128<4><<<dim3((M_TOK / 256) * (C_ / 128)), 512, 0, stream>>>(
        ubuf, wfcp_h, out, x2b, M_TOK, C_, FF_);
}

// Round 15
// 313.653 us; speedup vs baseline: 29.8787x; 1.0395x over previous
//
#include <hip/hip_runtime.h>
#include <hip/hip_bf16.h>

using bf16 = __hip_bfloat16;
typedef __attribute__((ext_vector_type(8))) short short8;
typedef __attribute__((ext_vector_type(4))) short sh4;
typedef __attribute__((ext_vector_type(4))) float f32x4;

#define B_ 4
#define T_ 2048
#define C_ 1024
#define H_ 16
#define FF_ 4096
#define M_TOK (B_ * T_)   // 8192
#define SCALE2 0.1803368801111f   // 0.125 * log2(e)

#define BARRIER() asm volatile("s_barrier" ::: "memory")
#define WAITLGKM0() asm volatile("s_waitcnt lgkmcnt(0)" ::: "memory")
#define WAITLGKM8() asm volatile("s_waitcnt lgkmcnt(8)" ::: "memory")
#define WAITVM4() asm volatile("s_waitcnt vmcnt(4)" ::: "memory")
#define WAITVM2() asm volatile("s_waitcnt vmcnt(2)" ::: "memory")
#define WAITVM0() asm volatile("s_waitcnt vmcnt(0)" ::: "memory")

#define SAE (256 * 64)
#define SBE256 (256 * 64)
#define SBE128 (128 * 64)
#define HALF256 (128 * 64)

// ---------------- async global->LDS 16B ----------------
__device__ __forceinline__ void gload16(const void* g, void* l) {
    __builtin_amdgcn_global_load_lds(
        (const __attribute__((address_space(1))) void*)g,
        (__attribute__((address_space(3))) void*)l, 16, 0, 0);
}

// 2^x in one instruction
__device__ __forceinline__ float fexp2(float x) {
    float r;
    asm("v_exp_f32 %0, %1" : "=v"(r) : "v"(x));
    return r;
}

__device__ __forceinline__ float bf16bits2f(short s) {
    return __uint_as_float(((unsigned)(unsigned short)s) << 16);
}

// pack two f32 -> one dword of 2 bf16
__device__ __forceinline__ unsigned bf2(float a, float b) {
    bf16 x = __float2bfloat16(a), y = __float2bfloat16(b);
    unsigned short ux = *(unsigned short*)&x, uy = *(unsigned short*)&y;
    return (unsigned)ux | ((unsigned)uy << 16);
}

// fast gelu
__device__ __forceinline__ float fgelu(float x) {
    float y = 0.79788456f * (x + 0.044715f * x * x * x);
    float tv = fexp2(y * 2.885390082f);
    return x * tv * __builtin_amdgcn_rcpf(tv + 1.f);
}

// ---------------- prep: LN1 (blocks 0..8191) + w_attn cvt only ----------------
__global__ __launch_bounds__(256) void prep_kernel(
    const float* __restrict__ x, const float* __restrict__ ln1w, const float* __restrict__ ln1b,
    bf16* __restrict__ ln_out,
    const float* __restrict__ w_attn, bf16* __restrict__ wattn_h) {
    const int bid = blockIdx.x;
    const int t = threadIdx.x;
    if (bid < M_TOK) {
        float4 v = ((const float4*)(x + (size_t)bid * C_))[t];
        float s = v.x + v.y + v.z + v.w;
        float s2 = v.x * v.x + v.y * v.y + v.z * v.z + v.w * v.w;
#pragma unroll
        for (int off = 32; off > 0; off >>= 1) {
            s += __shfl_down(s, off);
            s2 += __shfl_down(s2, off);
        }
        __shared__ float ss[4], ss2[4];
        int wave = t >> 6, lane = t & 63;
        if (lane == 0) { ss[wave] = s; ss2[wave] = s2; }
        __syncthreads();
        s = ss[0] + ss[1] + ss[2] + ss[3];
        s2 = ss2[0] + ss2[1] + ss2[2] + ss2[3];
        float mu = s * (1.f / C_);
        float var = s2 * (1.f / C_) - mu * mu;
        float rstd = rsqrtf(var + 1e-5f);
        float4 wv = ((const float4*)ln1w)[t];
        float4 bv = ((const float4*)ln1b)[t];
        uint2 o;
        o.x = bf2((v.x - mu) * rstd * wv.x + bv.x, (v.y - mu) * rstd * wv.y + bv.y);
        o.y = bf2((v.z - mu) * rstd * wv.z + bv.z, (v.w - mu) * rstd * wv.w + bv.w);
        ((uint2*)(ln_out + (size_t)bid * C_))[t] = o;
    } else {
        int j = (bid - M_TOK) * 256 + t;
        float4 v = ((const float4*)w_attn)[j];
        uint2 o;
        o.x = bf2(v.x, v.y);
        o.y = bf2(v.z, v.w);
        ((uint2*)wattn_h)[j] = o;
    }
}

// ---------------- LayerNorm (LN2): bf16 in -> bf16 out ----------------
__global__ __launch_bounds__(256) void ln_kernel_b(const bf16* __restrict__ x,
                                                   const float* __restrict__ w,
                                                   const float* __restrict__ b,
                                                   bf16* __restrict__ out) {
    int row = blockIdx.x;
    int t = threadIdx.x;
    sh4 h = ((const sh4*)(x + (size_t)row * C_))[t];
    float4 v;
    v.x = bf16bits2f(h[0]);
    v.y = bf16bits2f(h[1]);
    v.z = bf16bits2f(h[2]);
    v.w = bf16bits2f(h[3]);
    float s = v.x + v.y + v.z + v.w;
    float s2 = v.x * v.x + v.y * v.y + v.z * v.z + v.w * v.w;
#pragma unroll
    for (int off = 32; off > 0; off >>= 1) {
        s += __shfl_down(s, off);
        s2 += __shfl_down(s2, off);
    }
    __shared__ float ss[4], ss2[4];
    int wave = t >> 6, lane = t & 63;
    if (lane == 0) { ss[wave] = s; ss2[wave] = s2; }
    __syncthreads();
    s = ss[0] + ss[1] + ss[2] + ss[3];
    s2 = ss2[0] + ss2[1] + ss2[2] + ss2[3];
    float mu = s * (1.f / C_);
    float var = s2 * (1.f / C_) - mu * mu;
    float rstd = rsqrtf(var + 1e-5f);
    float4 wv = ((const float4*)w)[t];
    float4 bv = ((const float4*)b)[t];
    uint2 o;
    o.x = bf2((v.x - mu) * rstd * wv.x + bv.x, (v.y - mu) * rstd * wv.y + bv.y);
    o.y = bf2((v.z - mu) * rstd * wv.z + bv.z, (v.w - mu) * rstd * wv.w + bv.w);
    ((uint2*)(out + (size_t)row * C_))[t] = o;
}

// ======== shared staging macro ========
#define STG(ldsbase, g, grow0, k0)                                               \
    {                                                                            \
        _Pragma("unroll") for (int s_ = 0; s_ < 2; s_++) {                       \
            int row_ = s_ * 64 + wid * 8 + sr;                                   \
            gload16(g + (size_t)((grow0) + row_) * K + (k0) + ssc,               \
                    (ldsbase) + row_ * 64 + (lane & 7) * 8);                     \
        }                                                                        \
    }

// ---------------- 256x256 8-phase NT GEMM body ----------------
template <int EPI>
__device__ __forceinline__ void gemm256_dev(short* SAp, short* SBp, int bid,
                                            const bf16* __restrict__ Ag,
                                            const bf16* __restrict__ Bg,
                                            void* __restrict__ Cout,
                                            int M, int N, int K) {
    const int nbx = N >> 8;
    const int nwg = nbx * (M >> 8);
    const int cpx = nwg >> 3;
    const int swzb = (bid & 7) * cpx + (bid >> 3);
    const int m0 = (swzb / nbx) * 256;
    const int n0 = (swzb % nbx) * 256;

    const int t = threadIdx.x;
    const int wid = t >> 6, lane = t & 63;
    const int wm = wid >> 2, wn = wid & 3;
    const int lrow = lane & 15, lg = lane >> 4;
    const int swzr = (lane & 7) * 8;
    const int sr = lane >> 3;
    const int ssc = ((lane & 7) ^ sr) * 8;

    f32x4 acc[8][4];
#pragma unroll
    for (int mi = 0; mi < 8; mi++)
#pragma unroll
        for (int ni = 0; ni < 4; ni++) acc[mi][ni] = (f32x4){0.f, 0.f, 0.f, 0.f};
    short8 bfr[4][2];

    const int T = K >> 6;
    const int niter = T >> 1;

#define DSREADS256(q, buf)                                                       \
    if ((q) == 0) {                                                              \
        _Pragma("unroll") for (int ni = 0; ni < 4; ni++)                         \
        _Pragma("unroll") for (int ks = 0; ks < 2; ks++)                         \
            bfr[ni][ks] = *(const short8*)(&SBp[(buf) * SBE256 +                 \
                (wn * 64 + ni * 16 + lrow) * 64 + ((ks * 32 + lg * 8) ^ swzr)]); \
    }                                                                            \
    _Pragma("unroll") for (int mi2 = 0; mi2 < 2; mi2++)                          \
    _Pragma("unroll") for (int ks = 0; ks < 2; ks++)                             \
        af[mi2 * 2 + ks] = *(const short8*)(&SAp[(buf) * SAE +                   \
            (wm * 128 + (2 * (q) + mi2) * 16 + lrow) * 64 + ((ks * 32 + lg * 8) ^ swzr)]);

#define MFMAS256(q)                                                              \
    __builtin_amdgcn_s_setprio(1);                                               \
    _Pragma("unroll") for (int ks = 0; ks < 2; ks++)                             \
    _Pragma("unroll") for (int ni = 0; ni < 4; ni++)                             \
    _Pragma("unroll") for (int mi2 = 0; mi2 < 2; mi2++)                          \
        acc[2 * (q) + mi2][ni] = __builtin_amdgcn_mfma_f32_16x16x32_bf16(        \
            bfr[ni][ks], af[mi2 * 2 + ks], acc[2 * (q) + mi2][ni], 0, 0, 0);     \
    __builtin_amdgcn_s_setprio(0);

    STG(SAp, Ag, m0, 0);
    STG(SAp + HALF256, Ag, m0 + 128, 0);
    STG(SBp, Bg, n0, 0);
    STG(SBp + HALF256, Bg, n0 + 128, 0);
    STG(SBp + SBE256, Bg, n0, 64);
    STG(SBp + SBE256 + HALF256, Bg, n0 + 128, 64);
    WAITVM4();
    BARRIER();

    for (int iter = 0; iter < niter; iter++) {
        const int tt = 2 * iter;
        const int ka = (tt + 1) * 64, kb = (tt + 2) * 64, kc = (tt + 3) * 64;
        const bool s2 = (tt + 2 < T), s3 = (tt + 3 < T);
        const bool last = (iter == niter - 1);
        short8 af[4];

        DSREADS256(0, 0);
        STG(SAp + SAE, Ag, m0, ka);
        WAITLGKM8();
        BARRIER(); WAITLGKM0(); MFMAS256(0); BARRIER();
        DSREADS256(1, 0);
        STG(SAp + SAE + HALF256, Ag, m0 + 128, ka);
        BARRIER(); WAITLGKM0(); MFMAS256(1); BARRIER();
        DSREADS256(2, 0);
        if (s2) STG(SBp, Bg, n0, kb);
        BARRIER(); WAITLGKM0(); MFMAS256(2); BARRIER();
        DSREADS256(3, 0);
        if (s2) STG(SBp + HALF256, Bg, n0 + 128, kb);
        BARRIER(); WAITLGKM0(); MFMAS256(3);
        if (last) { WAITVM0(); } else { WAITVM4(); }
        BARRIER();
        DSREADS256(0, 1);
        if (s2) STG(SAp, Ag, m0, kb);
        WAITLGKM8();
        BARRIER(); WAITLGKM0(); MFMAS256(0); BARRIER();
        DSREADS256(1, 1);
        if (s2) STG(SAp + HALF256, Ag, m0 + 128, kb);
        BARRIER(); WAITLGKM0(); MFMAS256(1); BARRIER();
        DSREADS256(2, 1);
        if (s3) STG(SBp + SBE256, Bg, n0, kc);
        BARRIER(); WAITLGKM0(); MFMAS256(2); BARRIER();
        DSREADS256(3, 1);
        if (s3) STG(SBp + SBE256 + HALF256, Bg, n0 + 128, kc);
        BARRIER(); WAITLGKM0(); MFMAS256(3);
        if (!last) WAITVM4();
        BARRIER();
    }

#pragma unroll
    for (int mi = 0; mi < 8; mi++) {
        const int gm = m0 + wm * 128 + mi * 16 + lrow;
#pragma unroll
        for (int ni = 0; ni < 4; ni++) {
            const int gn = n0 + wn * 64 + ni * 16 + lg * 4;
            size_t gi = (size_t)gm * N + gn;
            f32x4 a = acc[mi][ni];
            if constexpr (EPI == 0) {
                uint2 o; o.x = bf2(a[0], a[1]); o.y = bf2(a[2], a[3]);
                *(uint2*)&(((bf16*)Cout)[gi]) = o;
            } else if constexpr (EPI == 5) {
                float sc = (gn < C_) ? SCALE2 : 1.f;
                uint2 o; o.x = bf2(a[0] * sc, a[1] * sc); o.y = bf2(a[2] * sc, a[3] * sc);
                *(uint2*)&(((bf16*)Cout)[gi]) = o;
            } else {
                uint2 o;
                o.x = bf2(fgelu(a[0]), fgelu(a[1]));
                o.y = bf2(fgelu(a[2]), fgelu(a[3]));
                *(uint2*)&(((bf16*)Cout)[gi]) = o;
            }
        }
    }
}

// ---------------- 256x128 8-phase NT GEMM body ----------------
template <int EPI>
__device__ __forceinline__ void gemm256x128_dev(short* SAp, short* SBp, int bid,
                                                const bf16* __restrict__ Ag,
                                                const bf16* __restrict__ Bg,
                                                void* __restrict__ Cout,
                                                const void* __restrict__ Res,
                                                int M, int N, int K) {
    const int nbx = N >> 7;
    const int nwg = nbx * (M >> 8);
    const int cpx = nwg >> 3;
    const int swzb = (bid & 7) * cpx + (bid >> 3);
    const int m0 = (swzb / nbx) * 256;
    const int n0 = (swzb % nbx) * 128;

    const int t = threadIdx.x;
    const int wid = t >> 6, lane = t & 63;
    const int wm = wid >> 1, wn = wid & 1;
    const int lrow = lane & 15, lg = lane >> 4;
    const int swzr = (lane & 7) * 8;
    const int sr = lane >> 3;
    const int ssc = ((lane & 7) ^ sr) * 8;

    f32x4 acc[4][4];
#pragma unroll
    for (int mi = 0; mi < 4; mi++)
#pragma unroll
        for (int ni = 0; ni < 4; ni++) acc[mi][ni] = (f32x4){0.f, 0.f, 0.f, 0.f};
    short8 bfr[4][2];

    const int T = K >> 6;
    const int niter = T >> 1;

#define DSRX(p, buf)                                                             \
    if ((p) == 0) {                                                              \
        _Pragma("unroll") for (int ni = 0; ni < 4; ni++)                         \
        _Pragma("unroll") for (int ks = 0; ks < 2; ks++)                         \
            bfr[ni][ks] = *(const short8*)(&SBp[(buf) * SBE128 +                 \
                (wn * 64 + ni * 16 + lrow) * 64 + ((ks * 32 + lg * 8) ^ swzr)]); \
    }                                                                            \
    _Pragma("unroll") for (int mi2 = 0; mi2 < 2; mi2++)                          \
    _Pragma("unroll") for (int ks = 0; ks < 2; ks++)                             \
        af[mi2 * 2 + ks] = *(const short8*)(&SAp[(buf) * SAE +                   \
            (wm * 64 + (2 * (p) + mi2) * 16 + lrow) * 64 + ((ks * 32 + lg * 8) ^ swzr)]);

#define MFX(p)                                                                   \
    __builtin_amdgcn_s_setprio(1);                                               \
    _Pragma("unroll") for (int ks = 0; ks < 2; ks++)                             \
    _Pragma("unroll") for (int ni = 0; ni < 4; ni++)                             \
    _Pragma("unroll") for (int mi2 = 0; mi2 < 2; mi2++)                          \
        acc[2 * (p) + mi2][ni] = __builtin_amdgcn_mfma_f32_16x16x32_bf16(        \
            bfr[ni][ks], af[mi2 * 2 + ks], acc[2 * (p) + mi2][ni], 0, 0, 0);     \
    __builtin_amdgcn_s_setprio(0);

    STG(SAp, Ag, m0, 0);
    STG(SAp + HALF256, Ag, m0 + 128, 0);
    STG(SBp, Bg, n0, 0);
    STG(SBp + SBE128, Bg, n0, 64);
    WAITVM2();
    BARRIER();

    for (int iter = 0; iter < niter; iter++) {
        const int tt = 2 * iter;
        const int ka = (tt + 1) * 64, kb = (tt + 2) * 64, kc = (tt + 3) * 64;
        const bool s2 = (tt + 2 < T), s3 = (tt + 3 < T);
        const bool last = (iter == niter - 1);
        short8 af[4];

        DSRX(0, 0);
        STG(SAp + SAE, Ag, m0, ka);
        STG(SAp + SAE + HALF256, Ag, m0 + 128, ka);
        WAITLGKM8();
        BARRIER(); WAITLGKM0(); MFX(0); BARRIER();
        DSRX(1, 0);
        if (s2) STG(SBp, Bg, n0, kb);
        BARRIER(); WAITLGKM0(); MFX(1);
        if (last) { WAITVM0(); } else { WAITVM2(); }
        BARRIER();
        DSRX(0, 1);
        if (s2) {
            STG(SAp, Ag, m0, kb);
            STG(SAp + HALF256, Ag, m0 + 128, kb);
        }
        WAITLGKM8();
        BARRIER(); WAITLGKM0(); MFX(0); BARRIER();
        DSRX(1, 1);
        if (s3) STG(SBp + SBE128, Bg, n0, kc);
        BARRIER(); WAITLGKM0(); MFX(1);
        if (last) { WAITVM0(); } else { WAITVM2(); }
        BARRIER();
    }

#pragma unroll
    for (int mi = 0; mi < 4; mi++) {
        const int gm = m0 + wm * 64 + mi * 16 + lrow;
#pragma unroll
        for (int ni = 0; ni < 4; ni++) {
            const int gn = n0 + wn * 64 + ni * 16 + lg * 4;
            size_t gi = (size_t)gm * N + gn;
            f32x4 a = acc[mi][ni];
            if constexpr (EPI == 0) {
                uint2 o; o.x = bf2(a[0], a[1]); o.y = bf2(a[2], a[3]);
                *(uint2*)&(((bf16*)Cout)[gi]) = o;
            } else if constexpr (EPI == 3) {
                float4 rv = *(const float4*)&(((const float*)Res)[gi]);
                uint2 o; o.x = bf2(rv.x + a[0], rv.y + a[1]); o.y = bf2(rv.z + a[2], rv.w + a[3]);
                *(uint2*)&(((bf16*)Cout)[gi]) = o;
            } else {
                sh4 hv = *(const sh4*)&(((const bf16*)Res)[gi]);
                float4 o;
                o.x = bf16bits2f(hv[0]) + a[0];
                o.y = bf16bits2f(hv[1]) + a[1];
                o.z = bf16bits2f(hv[2]) + a[2];
                o.w = bf16bits2f(hv[3]) + a[3];
                *(float4*)&(((float*)Cout)[gi]) = o;
            }
        }
    }
}

// ---------------- kernel wrappers ----------------
template <int EPI>
__global__ __launch_bounds__(512, 2) void gemm256(const bf16* __restrict__ Ag,
                                                  const bf16* __restrict__ Bg,
                                                  void* __restrict__ Cout,
                                                  int M, int N, int K) {
    __shared__ short LDS[2 * SAE + 2 * SBE256];
    gemm256_dev<EPI>(LDS, LDS + 2 * SAE, blockIdx.x, Ag, Bg, Cout, M, N, K);
}

template <int EPI>
__global__ __launch_bounds__(512, 2) void gemm256x128(const bf16* __restrict__ Ag,
                                                      const bf16* __restrict__ Bg,
                                                      void* __restrict__ Cout,
                                                      const void* __restrict__ Res,
                                                      int M, int N, int K) {
    __shared__ short LDS[2 * SAE + 2 * SBE128];
    gemm256x128_dev<EPI>(LDS, LDS + 2 * SAE, blockIdx.x, Ag, Bg, Cout, Res, M, N, K);
}

// merged qk (blocks 0..255) + vt (blocks 256..511)
__global__ __launch_bounds__(512, 2) void gemm_qkvt(const bf16* __restrict__ ln_buf,
                                                    const bf16* __restrict__ wattn_h,
                                                    bf16* __restrict__ qk_buf,
                                                    bf16* __restrict__ vt_buf) {
    __shared__ short LDS[2 * SAE + 2 * SBE256];
    if (blockIdx.x < 256) {
        gemm256_dev<5>(LDS, LDS + 2 * SAE, blockIdx.x,
                       ln_buf, wattn_h, qk_buf, M_TOK, 2 * C_, C_);
    } else {
        gemm256x128_dev<0>(LDS, LDS + 2 * SAE, blockIdx.x - 256,
                           wattn_h + (size_t)2 * C_ * C_, ln_buf, vt_buf, nullptr,
                           C_, M_TOK, C_);
    }
}

// ---------------- flash attention (blocks 0..1023) + deferred weight cvt (blocks 1024+) ----------------
// LDS layout: [64][64] shorts, XOR-swizzled: phys_col = logical_col ^ ((row&7)*8)
__global__ __launch_bounds__(256, 4) void flash_cvt(const bf16* __restrict__ qk,
                                                    const bf16* __restrict__ vt,
                                                    bf16* __restrict__ y,
                                                    const float* __restrict__ w_proj,
                                                    const float* __restrict__ w_fc,
                                                    const float* __restrict__ w_fcp,
                                                    bf16* __restrict__ wproj_h,
                                                    bf16* __restrict__ wfc_h,
                                                    bf16* __restrict__ wfcp_h) {
    const int bid = blockIdx.x;
    const int t = threadIdx.x;

    if (bid >= 1024) {
        int i = (bid - 1024) * 256 + t;
        const float* src;
        bf16* dst;
        int base;
        if (i < 262144) {            // w_proj: C*C/4
            src = w_proj; dst = wproj_h; base = 0;
        } else if (i < 1310720) {    // w_fc: FF*C/4
            src = w_fc; dst = wfc_h; base = 262144;
        } else {                     // w_fcp: C*FF/4
            src = w_fcp; dst = wfcp_h; base = 1310720;
        }
        int j = i - base;
        float4 v = ((const float4*)src)[j];
        uint2 o;
        o.x = bf2(v.x, v.y);
        o.y = bf2(v.z, v.w);
        ((uint2*)dst)[j] = o;
        return;
    }

    const int bh = bid & 63;
    const int pi = bid >> 6;
    const int b = bh >> 4, h = bh & 15;
    const int wave = t >> 6, lane = t & 63;
    const int lrow = lane & 15, lg = lane >> 4, lk = lg * 8;
    const int swz = (lrow & 7) * 8;           // read/compute-side XOR (row&7 == lrow&7)

    __shared__ alignas(16) short Ks[64 * 64];
    __shared__ alignas(16) short Vs[64 * 64];
    __shared__ alignas(16) short Ps[64 * 64];

    const size_t rs = 2 * C_;
    const bf16* Qg = qk + (size_t)b * T_ * rs + h * 64;
    const bf16* Kg = Qg + C_;
    const bf16* Vg = vt + (size_t)(h * 64) * M_TOK + b * T_;

    const int srow = t >> 3;                  // 0..31
    const int sc8 = (t & 7) * 8;              // logical col
    const int ssw = sc8 ^ ((srow & 7) * 8);   // swizzled store col (row&7 == srow&7)

    const int ql = pi, qh = 31 - pi;
    const int nkt = qh + 1;
    const int qgH = qh * 64 + wave * 16 + lrow;
    const int qgL = ql * 64 + wave * 16 + lrow;

    short8 qfH[2], qfL[2];
    {
        const bf16* qr = Qg + (size_t)qgH * rs;
        qfH[0] = *(const short8*)(qr + lk);
        qfH[1] = *(const short8*)(qr + 32 + lk);
        qr = Qg + (size_t)qgL * rs;
        qfL[0] = *(const short8*)(qr + lk);
        qfL[1] = *(const short8*)(qr + 32 + lk);
    }

    f32x4 oH[4], oL[4];
    float mH = -1e30f, lH = 0.f, mL = -1e30f, lL = 0.f;
#pragma unroll
    for (int ni = 0; ni < 4; ni++) {
        oH[ni] = (f32x4){0.f, 0.f, 0.f, 0.f};
        oL[ni] = (f32x4){0.f, 0.f, 0.f, 0.f};
    }

    short8 kr[2], vr[2];
#pragma unroll
    for (int p = 0; p < 2; p++) {
        int r = srow + p * 32;
        kr[p] = *(const short8*)(Kg + (size_t)r * rs + sc8);
        vr[p] = *(const short8*)(Vg + (size_t)r * M_TOK + sc8);
    }

    for (int kt = 0; kt < nkt; kt++) {
        const int s0 = kt * 64;
#pragma unroll
        for (int p = 0; p < 2; p++) {
            int r = srow + p * 32;
            *(short8*)(&Ks[r * 64 + ssw]) = kr[p];
            *(short8*)(&Vs[r * 64 + ssw]) = vr[p];
        }
        __syncthreads();
        if (kt + 1 < nkt) {
            const int s0n = (kt + 1) * 64;
#pragma unroll
            for (int p = 0; p < 2; p++) {
                int r = srow + p * 32;
                kr[p] = *(const short8*)(Kg + (size_t)(s0n + r) * rs + sc8);
                vr[p] = *(const short8*)(Vg + (size_t)r * M_TOK + s0n + sc8);
            }
        }

        // ======== HEAVY tile ========
        {
            f32x4 s[4];
#pragma unroll
            for (int ni = 0; ni < 4; ni++) s[ni] = (f32x4){0.f, 0.f, 0.f, 0.f};
            __builtin_amdgcn_s_setprio(1);
#pragma unroll
            for (int ks = 0; ks < 2; ks++)
#pragma unroll
                for (int ni = 0; ni < 4; ni++) {
                    short8 kf = *(const short8*)(&Ks[(ni * 16 + lrow) * 64 + ((ks * 32 + lk) ^ swz)]);
                    s[ni] = __builtin_amdgcn_mfma_f32_16x16x32_bf16(kf, qfH[ks], s[ni], 0, 0, 0);
                }
            __builtin_amdgcn_s_setprio(0);

            if (kt == qh) {
#pragma unroll
                for (int ni = 0; ni < 4; ni++)
#pragma unroll
                    for (int r = 0; r < 4; r++) {
                        int kvg = s0 + ni * 16 + lg * 4 + r;
                        if (kvg > qgH) s[ni][r] = -1e30f;
                    }
            }

            float pm = s[0][0];
#pragma unroll
            for (int ni = 0; ni < 4; ni++)
#pragma unroll
                for (int r = 0; r < 4; r++) pm = fmaxf(pm, s[ni][r]);
            pm = fmaxf(pm, __shfl_xor(pm, 16));
            pm = fmaxf(pm, __shfl_xor(pm, 32));
            if (!__all(pm - mH <= 8.f)) {
                float mn = fmaxf(mH, pm);
                float alpha = fexp2(mH - mn);
                mH = mn;
                lH *= alpha;
#pragma unroll
                for (int ni = 0; ni < 4; ni++)
#pragma unroll
                    for (int r = 0; r < 4; r++) oH[ni][r] *= alpha;
            }
            float rsum = 0.f;
#pragma unroll
            for (int ni = 0; ni < 4; ni++) {
                float p0 = fexp2(s[ni][0] - mH);
                float p1 = fexp2(s[ni][1] - mH);
                float p2 = fexp2(s[ni][2] - mH);
                float p3 = fexp2(s[ni][3] - mH);
                rsum += (p0 + p1) + (p2 + p3);
                uint2 pk; pk.x = bf2(p0, p1); pk.y = bf2(p2, p3);
                *(uint2*)(&Ps[(wave * 16 + lrow) * 64 + ((ni * 16 + lg * 4) ^ swz)]) = pk;
            }
            rsum += __shfl_xor(rsum, 16);
            rsum += __shfl_xor(rsum, 32);
            lH += rsum;

            __builtin_amdgcn_s_setprio(1);
#pragma unroll
            for (int ks2 = 0; ks2 < 2; ks2++) {
                short8 pf = *(const short8*)(&Ps[(wave * 16 + lrow) * 64 + ((ks2 * 32 + lk) ^ swz)]);
#pragma unroll
                for (int ni = 0; ni < 4; ni++) {
                    short8 vf = *(const short8*)(&Vs[(ni * 16 + lrow) * 64 + ((ks2 * 32 + lk) ^ swz)]);
                    oH[ni] = __builtin_amdgcn_mfma_f32_16x16x32_bf16(vf, pf, oH[ni], 0, 0, 0);
                }
            }
            __builtin_amdgcn_s_setprio(0);
        }

        // ======== LIGHT tile (shares staged K/V) ========
        if (kt <= ql) {
            f32x4 s[4];
#pragma unroll
            for (int ni = 0; ni < 4; ni++) s[ni] = (f32x4){0.f, 0.f, 0.f, 0.f};
            __builtin_amdgcn_s_setprio(1);
#pragma unroll
            for (int ks = 0; ks < 2; ks++)
#pragma unroll
                for (int ni = 0; ni < 4; ni++) {
                    short8 kf = *(const short8*)(&Ks[(ni * 16 + lrow) * 64 + ((ks * 32 + lk) ^ swz)]);
                    s[ni] = __builtin_amdgcn_mfma_f32_16x16x32_bf16(kf, qfL[ks], s[ni], 0, 0, 0);
                }
            __builtin_amdgcn_s_setprio(0);

            if (kt == ql) {
#pragma unroll
                for (int ni = 0; ni < 4; ni++)
#pragma unroll
                    for (int r = 0; r < 4; r++) {
                        int kvg = s0 + ni * 16 + lg * 4 + r;
                        if (kvg > qgL) s[ni][r] = -1e30f;
                    }
            }

            float pm = s[0][0];
#pragma unroll
            for (int ni = 0; ni < 4; ni++)
#pragma unroll
                for (int r = 0; r < 4; r++) pm = fmaxf(pm, s[ni][r]);
            pm = fmaxf(pm, __shfl_xor(pm, 16));
            pm = fmaxf(pm, __shfl_xor(pm, 32));
            if (!__all(pm - mL <= 8.f)) {
                float mn = fmaxf(mL, pm);
                float alpha = fexp2(mL - mn);
                mL = mn;
                lL *= alpha;
#pragma unroll
                for (int ni = 0; ni < 4; ni++)
#pragma unroll
                    for (int r = 0; r < 4; r++) oL[ni][r] *= alpha;
            }
            float rsum = 0.f;
#pragma unroll
            for (int ni = 0; ni < 4; ni++) {
                float p0 = fexp2(s[ni][0] - mL);
                float p1 = fexp2(s[ni][1] - mL);
                float p2 = fexp2(s[ni][2] - mL);
                float p3 = fexp2(s[ni][3] - mL);
                rsum += (p0 + p1) + (p2 + p3);
                uint2 pk; pk.x = bf2(p0, p1); pk.y = bf2(p2, p3);
                *(uint2*)(&Ps[(wave * 16 + lrow) * 64 + ((ni * 16 + lg * 4) ^ swz)]) = pk;
            }
            rsum += __shfl_xor(rsum, 16);
            rsum += __shfl_xor(rsum, 32);
            lL += rsum;

            __builtin_amdgcn_s_setprio(1);
#pragma unroll
            for (int ks2 = 0; ks2 < 2; ks2++) {
                short8 pf = *(const short8*)(&Ps[(wave * 16 + lrow) * 64 + ((ks2 * 32 + lk) ^ swz)]);
#pragma unroll
                for (int ni = 0; ni < 4; ni++) {
                    short8 vf = *(const short8*)(&Vs[(ni * 16 + lrow) * 64 + ((ks2 * 32 + lk) ^ swz)]);
                    oL[ni] = __builtin_amdgcn_mfma_f32_16x16x32_bf16(vf, pf, oL[ni], 0, 0, 0);
                }
            }
            __builtin_amdgcn_s_setprio(0);
        }
        __syncthreads();
    }

    float invH = 1.f / lH, invL = 1.f / lL;
#pragma unroll
    for (int ni = 0; ni < 4; ni++) {
        uint2 pk;
        pk.x = bf2(oH[ni][0] * invH, oH[ni][1] * invH);
        pk.y = bf2(oH[ni][2] * invH, oH[ni][3] * invH);
        *(uint2*)(&y[((size_t)(b * T_ + qgH)) * C_ + h * 64 + ni * 16 + lg * 4]) = pk;
        pk.x = bf2(oL[ni][0] * invL, oL[ni][1] * invL);
        pk.y = bf2(oL[ni][2] * invL, oL[ni][3] * invL);
        *(uint2*)(&y[((size_t)(b * T_ + qgL)) * C_ + h * 64 + ni * 16 + lg * 4]) = pk;
    }
}

// ---------------- launch ----------------
extern "C" void kernel_launch(void* const* d_in, const int* in_sizes, int n_in,
                              void* d_out, int out_size, void* d_ws, size_t ws_size,
                              hipStream_t stream) {
    const float* x      = (const float*)d_in[0];
    const float* ln1w   = (const float*)d_in[1];
    const float* ln1b   = (const float*)d_in[2];
    const float* ln2w   = (const float*)d_in[3];
    const float* ln2b   = (const float*)d_in[4];
    const float* w_attn = (const float*)d_in[5];
    const float* w_proj = (const float*)d_in[6];
    const float* w_fc   = (const float*)d_in[7];
    const float* w_fcp  = (const float*)d_in[8];
    float* out = (float*)d_out;

    char* ws = (char*)d_ws;
    bf16* ln_buf  = (bf16*)(ws);                   // [0,16M)
    bf16* qk_buf  = (bf16*)(ws + (16u << 20));     // [16,48M)
    bf16* vt_buf  = (bf16*)(ws + (48u << 20));     // [48,64M)
    bf16* ybuf    = (bf16*)(ws + (64u << 20));     // [64,80M)
    bf16* ubuf    = (bf16*)(ws + (16u << 20));     // [16,80M) reuse after attn
    bf16* x2b     = (bf16*)(ws + (80u << 20));     // [80,96M)
    bf16* wattn_h = (bf16*)(ws + (112u << 20));
    bf16* wproj_h = (bf16*)(ws + (118u << 20));
    bf16* wfc_h   = (bf16*)(ws + (120u << 20));
    bf16* wfcp_h  = (bf16*)(ws + (128u << 20));

    // prep: LN1 + w_attn cvt only
    prep_kernel<<<M_TOK + 3072, 256, 0, stream>>>(
        x, ln1w, ln1b, ln_buf, w_attn, wattn_h);

    // merged qk + vt
    gemm_qkvt<<<512, 512, 0, stream>>>(ln_buf, wattn_h, qk_buf, vt_buf);

    // flash attention + deferred weight conversions in tail
    flash_cvt<<<1024 + 9216, 256, 0, stream>>>(
        qk_buf, vt_buf, ybuf, w_proj, w_fc, w_fcp, wproj_h, wfc_h, wfcp_h);

    // x2b = bf16(x + ybuf @ w_proj^T)
    gemm256x128<3><<<dim3((M_TOK / 256) * (C_ / 128)), 512, 0, stream>>>(
        ybuf, wproj_h, x2b, x, M_TOK, C_, C_);

    // LN2
    ln_kernel_b<<<M_TOK, 256, 0, stream>>>(x2b, ln2w, ln2b, ln_buf);

    // u = fgelu(ln_buf @ w_fc^T)
    gemm256<2><<<dim3((M_TOK / 256) * (FF_ / 256)), 512, 0, stream>>>(
        ln_buf, wfc_h, ubuf, M_TOK, FF_, C_);

    // out = f32(x2b) + u @ w_fcp^T
    gemm256x128<4><<<dim3((M_TOK / 256) * (C_ / 128)), 512, 0, stream>>>(
        ubuf, wfcp_h, out, x2b, M_TOK, C_, FF_);
}